// Round 6
// baseline (924.192 us; speedup 1.0000x reference)
//
#include <hip/hip_runtime.h>

#define NN 50000
#define PM 4
#define EE 500000
#define INF_ 128
#define NH 8
#define FF 32
#define HF 256
#define HS 128
#define BG 128
#define OUTC 2

#define NB2 98        // buckets per path: dst>>9 (512 nodes/bucket)
#define BCAP 6144     // bucket capacity (mean 5102, sd ~71 -> 14 sigma slack)
#define BCH 4096      // edges per workgroup in bucket pass
#define PCH 16        // pooling chunks (partial-sum stage)

typedef __attribute__((ext_vector_type(8))) short bf16x8;
typedef __attribute__((ext_vector_type(4))) float f32x4;

__device__ __forceinline__ float b2f(unsigned short x) {
  unsigned u = ((unsigned)x) << 16;
  return __builtin_bit_cast(float, u);
}
__device__ __forceinline__ unsigned short f2b(float f) {
  unsigned u = __builtin_bit_cast(unsigned, f);
  u += 0x7fff + ((u >> 16) & 1);   // RNE
  return (unsigned short)(u >> 16);
}

// ---------------------------------------------------------------------------
// prep: zero gcnt/wsum + h->bf16 + Wg transpose->bf16 + W1 transpose->bf16
//       + fold attn into per-k weights. One dispatch, sections by blockIdx.x.
// ---------------------------------------------------------------------------
__global__ __launch_bounds__(256) void prep_kernel(
    const float* __restrict__ h, const float* __restrict__ Wg,
    const float* __restrict__ W1, const float* __restrict__ al,
    const float* __restrict__ ar,
    unsigned short* __restrict__ h_b, unsigned short* __restrict__ Wb_t,
    unsigned short* __restrict__ W1_t, float* __restrict__ wl,
    float* __restrict__ wr, int* __restrict__ gcnt, float* __restrict__ wsum) {
  int b = blockIdx.x;
  int tid = threadIdx.x;
  if (b < 1) {                 // zero gcnt + wsum
    for (int i = tid; i < PM * NB2; i += 256) gcnt[i] = 0;
    if (tid < PM) wsum[tid] = 0.f;
    return;
  }
  b -= 1;
  if (b < 6250) {              // h -> bf16 (float4 granular)
    int t = b * 256 + tid;     // t < 1.6M exactly
    float4 v = *(const float4*)(h + (size_t)t * 4);
    ushort4 o;
    o.x = f2b(v.x); o.y = f2b(v.y); o.z = f2b(v.z); o.w = f2b(v.w);
    *(ushort4*)(h_b + (size_t)t * 4) = o;
    return;
  }
  b -= 6250;
  if (b < 512) {               // Wg [P][128k][256n] -> [P][256n][128k] bf16
    int t = b * 256 + tid;
    int p = t >> 15, rem = t & 32767;
    int n = rem >> 7, k = rem & 127;
    Wb_t[(size_t)p * 32768 + n * 128 + k] = f2b(Wg[(size_t)p * 32768 + k * 256 + n]);
    return;
  }
  b -= 512;
  if (b < 128) {               // W1 [256k][128n] -> [128n][256k] bf16
    int t = b * 256 + tid;
    int n = t >> 8, k = t & 255;
    W1_t[n * 256 + k] = f2b(W1[k * 128 + n]);
    return;
  }
  b -= 128;
  {                            // fold: wl/wr[p][k][h]
    int t = b * 256 + tid;     // t < 4096
    int p = t >> 10, rem = t & 1023;
    int k = rem >> 3, hh = rem & 7;
    const float* wrow = Wg + (size_t)p * 32768 + k * 256 + hh * 32;
    const float* alp = al + p * 256 + hh * 32;
    const float* arp = ar + p * 256 + hh * 32;
    float sl = 0.f, sr = 0.f;
    #pragma unroll
    for (int f = 0; f < 32; f++) { sl += wrow[f] * alp[f]; sr += wrow[f] * arp[f]; }
    wl[t] = sl; wr[t] = sr;
  }
}

// ---------------------------------------------------------------------------
// bucket: per-block histogram -> one global atomic per (block,bucket) to
// reserve a contiguous segment -> LDS-cursor scatter.
// ---------------------------------------------------------------------------
__global__ __launch_bounds__(256) void bucket_kernel(
    const int* __restrict__ src, const int* __restrict__ dst,
    unsigned* __restrict__ bdata, int* __restrict__ gcnt) {
  __shared__ unsigned ed[BCH];
  __shared__ int hist[NB2], gbase[NB2], cur[NB2];
  int p = blockIdx.y;
  int e0 = blockIdx.x * BCH;
  int n = min(BCH, EE - e0);
  int tid = threadIdx.x;
  if (tid < NB2) hist[tid] = 0;
  __syncthreads();
  const int* sp = src + (size_t)p * EE + e0;
  const int* dp = dst + (size_t)p * EE + e0;
  for (int i = tid; i < n; i += 256) {
    int s = sp[i], d = dp[i];
    ed[i] = ((unsigned)d << 16) | (unsigned)s;
    atomicAdd(&hist[d >> 9], 1);
  }
  __syncthreads();
  if (tid < NB2) {
    gbase[tid] = atomicAdd(&gcnt[p * NB2 + tid], hist[tid]);
    cur[tid] = 0;
  }
  __syncthreads();
  for (int i = tid; i < n; i += 256) {
    unsigned pk = ed[i];
    int bk = pk >> 25;           // (dst>>9)
    int slot = gbase[bk] + atomicAdd(&cur[bk], 1);
    if (slot < BCAP)
      bdata[((size_t)(p * NB2 + bk)) * BCAP + slot] = pk;
  }
}

// ---------------------------------------------------------------------------
// csrify: per (bucket,path): 512-node local CSR in LDS, write global off[]
// + csr[] (ushort src).
// ---------------------------------------------------------------------------
__global__ __launch_bounds__(256) void csrify_kernel(
    const unsigned* __restrict__ bdata, const int* __restrict__ gcnt,
    int* __restrict__ off, unsigned short* __restrict__ csr) {
  __shared__ unsigned ebuf[BCAP];
  __shared__ int gc[NB2];
  __shared__ int degc[512];
  __shared__ int loff[513];
  __shared__ int tmp[256];
  __shared__ int base_s;
  int b = blockIdx.x, p = blockIdx.y;
  int tid = threadIdx.x;
  if (tid < NB2) gc[tid] = min(gcnt[p * NB2 + tid], BCAP);
  __syncthreads();
  if (tid == 0) {
    int s = 0;
    for (int i = 0; i < b; i++) s += gc[i];
    base_s = s;
  }
  int cnt = gc[b];
  const unsigned* bp = bdata + ((size_t)(p * NB2 + b)) * BCAP;
  for (int i = tid; i < cnt; i += 256) ebuf[i] = bp[i];
  degc[tid] = 0; degc[256 + tid] = 0;
  __syncthreads();
  for (int i = tid; i < cnt; i += 256)
    atomicAdd(&degc[(ebuf[i] >> 16) & 511], 1);
  __syncthreads();
  int d0 = degc[2 * tid], d1 = degc[2 * tid + 1];
  tmp[tid] = d0 + d1;
  __syncthreads();
  for (int o = 1; o < 256; o <<= 1) {
    int v = (tid >= o) ? tmp[tid - o] : 0;
    __syncthreads();
    tmp[tid] += v;
    __syncthreads();
  }
  int bse = tmp[tid] - d0 - d1;
  loff[2 * tid] = bse; loff[2 * tid + 1] = bse + d0;
  if (tid == 255) loff[512] = tmp[255];
  __syncthreads();
  int base = base_s;
  for (int dl = tid; dl < 512; dl += 256) {
    int n = b * 512 + dl;
    if (n <= NN) off[(size_t)p * (NN + 1) + n] = base + loff[dl];
  }
  degc[tid] = 0; degc[256 + tid] = 0;   // reuse as cursors
  __syncthreads();
  for (int i = tid; i < cnt; i += 256) {
    unsigned pk = ebuf[i];
    int dl = (pk >> 16) & 511;
    int slot = loff[dl] + atomicAdd(&degc[dl], 1);
    csr[(size_t)p * EE + base + slot] = (unsigned short)(pk & 0xffff);
  }
}

// ---------------------------------------------------------------------------
// GEMM1: hp_b[p][M,256] = h_b[M,128] @ W[p], MFMA bf16. p = p0 + blockIdx.z.
// ---------------------------------------------------------------------------
__global__ __launch_bounds__(256) void gemm1_kernel(
    const unsigned short* __restrict__ hA, const unsigned short* __restrict__ Bt,
    unsigned short* __restrict__ Cb, int M, int p0, size_t cstride) {
  __shared__ unsigned short As[64 * 128];
  __shared__ unsigned short Bs[128 * 128];
  int tid = threadIdx.x;
  int pl = blockIdx.z;
  const unsigned short* Bp = Bt + (size_t)(p0 + pl) * 32768;
  unsigned short* Cp = Cb + (size_t)pl * cstride;
  int row0 = blockIdx.x * 64, col0 = blockIdx.y * 128;
  #pragma unroll
  for (int i = 0; i < 4; i++) {
    int c = i * 256 + tid;
    int row = c >> 4, g = c & 15;
    int grow = row0 + row;
    uint4 v = make_uint4(0, 0, 0, 0);
    if (grow < M) v = *(const uint4*)(hA + (size_t)grow * 128 + g * 8);
    *(uint4*)&As[row * 128 + ((g ^ (row & 15)) << 3)] = v;
  }
  #pragma unroll
  for (int i = 0; i < 8; i++) {
    int c = i * 256 + tid;
    int row = c >> 4, g = c & 15;
    uint4 v = *(const uint4*)(Bp + (size_t)(col0 + row) * 128 + g * 8);
    *(uint4*)&Bs[row * 128 + ((g ^ (row & 15)) << 3)] = v;
  }
  __syncthreads();
  int wave = tid >> 6, lane = tid & 63;
  int ln = lane & 15, quad = lane >> 4;
  int mbase = (wave >> 1) * 32, nbase = (wave & 1) * 64;
  f32x4 acc[2][4] = {};
  #pragma unroll
  for (int ks = 0; ks < 4; ks++) {
    int g = ks * 4 + quad;
    bf16x8 a[2], bb[4];
    #pragma unroll
    for (int mi = 0; mi < 2; mi++) {
      int r = mbase + mi * 16 + ln;
      a[mi] = *(const bf16x8*)&As[r * 128 + ((g ^ ln) << 3)];
    }
    #pragma unroll
    for (int ni = 0; ni < 4; ni++) {
      int r = nbase + ni * 16 + ln;
      bb[ni] = *(const bf16x8*)&Bs[r * 128 + ((g ^ ln) << 3)];
    }
    #pragma unroll
    for (int mi = 0; mi < 2; mi++)
      #pragma unroll
      for (int ni = 0; ni < 4; ni++)
        acc[mi][ni] = __builtin_amdgcn_mfma_f32_16x16x32_bf16(a[mi], bb[ni], acc[mi][ni], 0, 0, 0);
  }
  #pragma unroll
  for (int mi = 0; mi < 2; mi++) {
    int gm0 = row0 + mbase + mi * 16 + quad * 4;
    #pragma unroll
    for (int ni = 0; ni < 4; ni++) {
      int gn = col0 + nbase + ni * 16 + ln;
      #pragma unroll
      for (int r = 0; r < 4; r++) {
        int gm = gm0 + r;
        if (gm < M) Cp[(size_t)gm * 256 + gn] = f2b(acc[mi][ni][r]);
      }
    }
  }
}

// ---------------------------------------------------------------------------
// elr: el/er = h @ folded weights (fp32 exact). p = p0 + blockIdx.y.
// ---------------------------------------------------------------------------
__global__ __launch_bounds__(256) void elr_kernel(
    const float* __restrict__ h, const float* __restrict__ wl,
    const float* __restrict__ wr, float* __restrict__ el,
    float* __restrict__ er, int N, int p0, size_t estride) {
  __shared__ float wls[128 * 8], wrs[128 * 8];
  int pl = blockIdx.y;
  const float* wlp = wl + (size_t)(p0 + pl) * 1024;
  const float* wrp = wr + (size_t)(p0 + pl) * 1024;
  float* elp = el + (size_t)pl * estride;
  float* erp = er + (size_t)pl * estride;
  for (int i = threadIdx.x; i < 1024; i += 256) { wls[i] = wlp[i]; wrs[i] = wrp[i]; }
  __syncthreads();
  int n = blockIdx.x * 256 + threadIdx.x;
  if (n >= N) return;
  float accl[8] = {}, accr[8] = {};
  for (int k4 = 0; k4 < 32; k4++) {
    float4 hv = *(const float4*)(h + (size_t)n * 128 + k4 * 4);
    float vv[4] = {hv.x, hv.y, hv.z, hv.w};
    #pragma unroll
    for (int j = 0; j < 4; j++) {
      float v = vv[j];
      int k = k4 * 4 + j;
      #pragma unroll
      for (int hh = 0; hh < 8; hh++) {
        accl[hh] += v * wls[k * 8 + hh];
        accr[hh] += v * wrs[k * 8 + hh];
      }
    }
  }
  *(float4*)(elp + (size_t)n * 8)     = make_float4(accl[0], accl[1], accl[2], accl[3]);
  *(float4*)(elp + (size_t)n * 8 + 4) = make_float4(accl[4], accl[5], accl[6], accl[7]);
  *(float4*)(erp + (size_t)n * 8)     = make_float4(accr[0], accr[1], accr[2], accr[3]);
  *(float4*)(erp + (size_t)n * 8 + 4) = make_float4(accr[4], accr[5], accr[6], accr[7]);
}

// ---------------------------------------------------------------------------
// agg: one wave per dst node: out = (sum w*hp)/(sum w), +bias, ELU -> bf16.
// ---------------------------------------------------------------------------
__global__ __launch_bounds__(256) void agg_kernel(
    const unsigned short* __restrict__ hp_b, const float* __restrict__ el,
    const float* __restrict__ er, const unsigned short* __restrict__ csr,
    const int* __restrict__ off, const float* __restrict__ bias,
    unsigned short* __restrict__ emb_b, int N, int p0,
    size_t hstride, size_t estride, size_t embstride) {
  int pl = blockIdx.y;
  int p = p0 + pl;
  const unsigned short* hp = hp_b + (size_t)pl * hstride;
  const float* elp = el + (size_t)pl * estride;
  const float* erp = er + (size_t)pl * estride;
  const unsigned short* csrp = csr + (size_t)p * EE;
  const int* offp = off + (size_t)p * (NN + 1);
  const float* bp = bias + (size_t)p * HF;
  unsigned short* embp = emb_b + (size_t)pl * embstride;
  int n = blockIdx.x * 4 + (threadIdx.x >> 6);
  if (n >= N) return;
  int lane = threadIdx.x & 63;
  int h = lane >> 3;
  int e0 = offp[n], e1 = offp[n + 1];
  float erh = erp[n * NH + h];
  float den = 0.f, a0 = 0.f, a1 = 0.f, a2 = 0.f, a3 = 0.f;
  for (int e = e0; e < e1; e++) {
    int s = csrp[e];
    float x = elp[s * NH + h] + erh;
    x = (x > 0.f) ? x : 0.2f * x;
    float w = expf(x);
    den += w;
    ushort4 hv = *(const ushort4*)(hp + (size_t)s * HF + lane * 4);
    a0 += w * b2f(hv.x); a1 += w * b2f(hv.y);
    a2 += w * b2f(hv.z); a3 += w * b2f(hv.w);
  }
  float inv = (den > 0.f) ? 1.f / den : 0.f;
  float4 bv = *(const float4*)(bp + lane * 4);
  float o0 = a0 * inv + bv.x, o1 = a1 * inv + bv.y;
  float o2 = a2 * inv + bv.z, o3 = a3 * inv + bv.w;
  o0 = (o0 > 0.f) ? o0 : expf(o0) - 1.f;
  o1 = (o1 > 0.f) ? o1 : expf(o1) - 1.f;
  o2 = (o2 > 0.f) ? o2 : expf(o2) - 1.f;
  o3 = (o3 > 0.f) ? o3 : expf(o3) - 1.f;
  ushort4 ov;
  ov.x = f2b(o0); ov.y = f2b(o1); ov.z = f2b(o2); ov.w = f2b(o3);
  *(ushort4*)(embp + (size_t)n * HF + lane * 4) = ov;
}

// ---------------------------------------------------------------------------
// GEMM2 + semantic epilogue: wsum[p] += sum tanh(emb@W1+b1).W2
// ---------------------------------------------------------------------------
__global__ __launch_bounds__(256) void gemm2_kernel(
    const unsigned short* __restrict__ A, const unsigned short* __restrict__ Bt,
    const float* __restrict__ b1, const float* __restrict__ W2,
    float* __restrict__ wsum, int M, int p0, size_t astride) {
  __shared__ unsigned short As[64 * 128];
  __shared__ unsigned short Bs[128 * 128];
  int tid = threadIdx.x;
  int pl = blockIdx.y;
  const unsigned short* Ap = A + (size_t)pl * astride;
  int row0 = blockIdx.x * 64;
  int wave = tid >> 6, lane = tid & 63;
  int ln = lane & 15, quad = lane >> 4;
  int mbase = (wave >> 1) * 32, nbase = (wave & 1) * 64;
  f32x4 acc[2][4] = {};
  for (int kc = 0; kc < 2; kc++) {
    #pragma unroll
    for (int i = 0; i < 4; i++) {
      int c = i * 256 + tid;
      int row = c >> 4, g = c & 15;
      int grow = row0 + row;
      uint4 v = make_uint4(0, 0, 0, 0);
      if (grow < M) v = *(const uint4*)(Ap + (size_t)grow * 256 + kc * 128 + g * 8);
      *(uint4*)&As[row * 128 + ((g ^ (row & 15)) << 3)] = v;
    }
    #pragma unroll
    for (int i = 0; i < 8; i++) {
      int c = i * 256 + tid;
      int row = c >> 4, g = c & 15;
      uint4 v = *(const uint4*)(Bt + (size_t)row * 256 + kc * 128 + g * 8);
      *(uint4*)&Bs[row * 128 + ((g ^ (row & 15)) << 3)] = v;
    }
    __syncthreads();
    #pragma unroll
    for (int ks = 0; ks < 4; ks++) {
      int g = ks * 4 + quad;
      bf16x8 a[2], bb[4];
      #pragma unroll
      for (int mi = 0; mi < 2; mi++) {
        int r = mbase + mi * 16 + ln;
        a[mi] = *(const bf16x8*)&As[r * 128 + ((g ^ ln) << 3)];
      }
      #pragma unroll
      for (int ni = 0; ni < 4; ni++) {
        int r = nbase + ni * 16 + ln;
        bb[ni] = *(const bf16x8*)&Bs[r * 128 + ((g ^ ln) << 3)];
      }
      #pragma unroll
      for (int mi = 0; mi < 2; mi++)
        #pragma unroll
        for (int ni = 0; ni < 4; ni++)
          acc[mi][ni] = __builtin_amdgcn_mfma_f32_16x16x32_bf16(a[mi], bb[ni], acc[mi][ni], 0, 0, 0);
    }
    __syncthreads();
  }
  float b1v[4], w2v[4];
  #pragma unroll
  for (int ni = 0; ni < 4; ni++) {
    int col = nbase + ni * 16 + ln;
    b1v[ni] = b1[col]; w2v[ni] = W2[col];
  }
  float s = 0.f;
  #pragma unroll
  for (int mi = 0; mi < 2; mi++) {
    int gm0 = row0 + mbase + mi * 16 + quad * 4;
    #pragma unroll
    for (int r = 0; r < 4; r++) {
      if (gm0 + r < M) {
        #pragma unroll
        for (int ni = 0; ni < 4; ni++)
          s += tanhf(acc[mi][ni][r] + b1v[ni]) * w2v[ni];
      }
    }
  }
  #pragma unroll
  for (int o = 32; o > 0; o >>= 1) s += __shfl_down(s, o);
  if (lane == 0) atomicAdd(&wsum[p0 + pl], s);
}

// ---------------------------------------------------------------------------
// pool: LDS accumulate per (feat-slice, chunk, path), then PLAIN coalesced
// stores of the 8192-entry partial (no global atomics).
// ---------------------------------------------------------------------------
__global__ __launch_bounds__(256) void pool_kernel(
    const unsigned short* __restrict__ emb, const int* __restrict__ gid,
    float* __restrict__ partial, int N, int p0, size_t embstride) {
  __shared__ float acc[BG * 64];
  int pl = blockIdx.z;
  const unsigned short* embp = emb + (size_t)pl * embstride;
  int f0 = blockIdx.x * 64;
  int lane = threadIdx.x & 63, grp = threadIdx.x >> 6;
  for (int i = threadIdx.x; i < BG * 64; i += 256) acc[i] = 0.f;
  __syncthreads();
  int chunk = (N + PCH - 1) / PCH;
  int start = blockIdx.y * chunk;
  int end = min(start + chunk, N);
  int glen = (end - start + 3) >> 2;
  int gstart = start + grp * glen;
  int gend = min(gstart + glen, end);
  for (int n = gstart; n < gend; n++) {
    int g = gid[n];
    float v = b2f(embp[(size_t)n * HF + f0 + lane]);
    atomicAdd(&acc[g * 64 + lane], v);
  }
  __syncthreads();
  float* dst = partial + ((((size_t)(p0 + pl) * PCH + blockIdx.y) * 4 + blockIdx.x) << 13);
  for (int i = threadIdx.x; i < BG * 64; i += 256) dst[i] = acc[i];
}

// ---------------------------------------------------------------------------
// final: per-graph count, chunk-partial reduce, beta softmax, logits + pooled
// ---------------------------------------------------------------------------
__global__ __launch_bounds__(256) void final_kernel(
    const float* __restrict__ partial, const float* __restrict__ wsum,
    const int* __restrict__ gid, const float* __restrict__ clsW,
    const float* __restrict__ clsb, float* __restrict__ out, int N) {
  int b = blockIdx.x;
  int f = threadIdx.x;
  __shared__ int ci[256];
  int cl = 0;
  for (int i = f; i < N; i += 256) cl += (gid[i] == b) ? 1 : 0;
  ci[f] = cl;
  __syncthreads();
  for (int st = 128; st > 0; st >>= 1) {
    if (f < st) ci[f] += ci[f + st];
    __syncthreads();
  }
  float c = fmaxf((float)ci[0], 1.f);
  float wm[PM];
  float mx = -1e30f;
  #pragma unroll
  for (int p = 0; p < PM; p++) { wm[p] = wsum[p] / (float)N; mx = fmaxf(mx, wm[p]); }
  float es = 0.f, e[PM];
  #pragma unroll
  for (int p = 0; p < PM; p++) { e[p] = expf(wm[p] - mx); es += e[p]; }
  int xs = f >> 6, fl = f & 63;
  float v = 0.f;
  #pragma unroll
  for (int p = 0; p < PM; p++) {
    float s = 0.f;
    for (int y = 0; y < PCH; y++)
      s += partial[((((size_t)p * PCH + y) * 4 + xs) << 13) + b * 64 + fl];
    v += (e[p] / es) * s;
  }
  v /= c;
  out[256 + (size_t)b * HF + f] = v;
  __shared__ float sm[256];
  sm[f] = v * clsW[f * 2 + 0];
  __syncthreads();
  for (int st = 128; st > 0; st >>= 1) {
    if (f < st) sm[f] += sm[f + st];
    __syncthreads();
  }
  float l0 = sm[0];
  __syncthreads();
  sm[f] = v * clsW[f * 2 + 1];
  __syncthreads();
  for (int st = 128; st > 0; st >>= 1) {
    if (f < st) sm[f] += sm[f + st];
    __syncthreads();
  }
  if (f == 0) {
    out[b * 2 + 0] = l0 + clsb[0];
    out[b * 2 + 1] = sm[0] + clsb[1];
  }
}

// ---------------------------------------------------------------------------
extern "C" void kernel_launch(void* const* d_in, const int* in_sizes, int n_in,
                              void* d_out, int out_size, void* d_ws, size_t ws_size,
                              hipStream_t stream) {
  const float* h      = (const float*)d_in[0];
  const float* Wg     = (const float*)d_in[1];
  const float* attn_l = (const float*)d_in[2];
  const float* attn_r = (const float*)d_in[3];
  const float* gatb   = (const float*)d_in[4];
  const float* semW1  = (const float*)d_in[5];
  const float* semb1  = (const float*)d_in[6];
  const float* semW2  = (const float*)d_in[7];
  const float* clsW   = (const float*)d_in[8];
  const float* clsb   = (const float*)d_in[9];
  const int*   src    = (const int*)d_in[10];
  const int*   dst    = (const int*)d_in[11];
  const int*   gid    = (const int*)d_in[12];
  float* out = (float*)d_out;

  auto layout_size = [](int PMg) -> size_t {
    size_t o = 0;
    auto alloc = [&](size_t bytes) { o += (bytes + 255) & ~(size_t)255; };
    alloc((size_t)NN * INF_ * 2);              // h_b
    alloc((size_t)PMg * NN * HF * 2);          // hp_b
    alloc((size_t)PMg * NN * HF * 2);          // emb_b
    alloc((size_t)PM * HF * INF_ * 2);         // Wb_t
    alloc((size_t)HS * HF * 2);                // W1_t
    alloc((size_t)PM * INF_ * NH * 4);         // wl
    alloc((size_t)PM * INF_ * NH * 4);         // wr
    alloc((size_t)PMg * NN * NH * 4);          // el
    alloc((size_t)PMg * NN * NH * 4);          // er
    alloc((size_t)PM * NB2 * BCAP * 4);        // bdata
    alloc((size_t)PM * NB2 * 4);               // gcnt
    alloc((size_t)PM * (NN + 1) * 4);          // off
    alloc((size_t)PM * EE * 2);                // csr
    alloc((size_t)PM * PCH * 4 * BG * 64 * 4); // partial
    alloc(PM * 4);                             // wsum
    return o;
  };
  int PMg = (layout_size(4) <= ws_size) ? 4 : 1;

  char* ws = (char*)d_ws;
  size_t o = 0;
  auto alloc = [&](size_t bytes) { size_t r = o; o += (bytes + 255) & ~(size_t)255; return r; };
  unsigned short* h_b   = (unsigned short*)(ws + alloc((size_t)NN * INF_ * 2));
  unsigned short* hp_b  = (unsigned short*)(ws + alloc((size_t)PMg * NN * HF * 2));
  unsigned short* emb_b = (unsigned short*)(ws + alloc((size_t)PMg * NN * HF * 2));
  unsigned short* Wb_t  = (unsigned short*)(ws + alloc((size_t)PM * HF * INF_ * 2));
  unsigned short* W1_t  = (unsigned short*)(ws + alloc((size_t)HS * HF * 2));
  float* wl    = (float*)(ws + alloc((size_t)PM * INF_ * NH * 4));
  float* wr    = (float*)(ws + alloc((size_t)PM * INF_ * NH * 4));
  float* el    = (float*)(ws + alloc((size_t)PMg * NN * NH * 4));
  float* er    = (float*)(ws + alloc((size_t)PMg * NN * NH * 4));
  unsigned* bdata = (unsigned*)(ws + alloc((size_t)PM * NB2 * BCAP * 4));
  int*   gcnt  = (int*)(ws + alloc((size_t)PM * NB2 * 4));
  int*   off   = (int*)(ws + alloc((size_t)PM * (NN + 1) * 4));
  unsigned short* csr = (unsigned short*)(ws + alloc((size_t)PM * EE * 2));
  float* partial = (float*)(ws + alloc((size_t)PM * PCH * 4 * BG * 64 * 4));
  float* wsum  = (float*)(ws + alloc(PM * 4));

  const size_t hpS  = (PMg == 4) ? (size_t)NN * HF : 0;
  const size_t embS = hpS;
  const size_t elS  = (PMg == 4) ? (size_t)NN * NH : 0;

  prep_kernel<<<1 + 6250 + 512 + 128 + 16, 256, 0, stream>>>(
      h, Wg, semW1, attn_l, attn_r, h_b, Wb_t, W1_t, wl, wr, gcnt, wsum);
  bucket_kernel<<<dim3((EE + BCH - 1) / BCH, PM), 256, 0, stream>>>(src, dst, bdata, gcnt);
  csrify_kernel<<<dim3(NB2, PM), 256, 0, stream>>>(bdata, gcnt, off, csr);

  if (PMg == 4) {
    gemm1_kernel<<<dim3((NN + 63) / 64, 2, 4), 256, 0, stream>>>(h_b, Wb_t, hp_b, NN, 0, hpS);
    elr_kernel<<<dim3((NN + 255) / 256, 4), 256, 0, stream>>>(h, wl, wr, el, er, NN, 0, elS);
    agg_kernel<<<dim3((NN + 3) / 4, 4), 256, 0, stream>>>(
        hp_b, el, er, csr, off, gatb, emb_b, NN, 0, hpS, elS, embS);
    gemm2_kernel<<<dim3((NN + 63) / 64, 4), 256, 0, stream>>>(
        emb_b, W1_t, semb1, semW2, wsum, NN, 0, embS);
    pool_kernel<<<dim3(4, PCH, 4), 256, 0, stream>>>(emb_b, gid, partial, NN, 0, embS);
  } else {
    for (int p = 0; p < PM; p++) {
      gemm1_kernel<<<dim3((NN + 63) / 64, 2, 1), 256, 0, stream>>>(h_b, Wb_t, hp_b, NN, p, 0);
      elr_kernel<<<dim3((NN + 255) / 256, 1), 256, 0, stream>>>(h, wl, wr, el, er, NN, p, 0);
      agg_kernel<<<dim3((NN + 3) / 4, 1), 256, 0, stream>>>(
          hp_b, el, er, csr, off, gatb, emb_b, NN, p, 0, 0, 0);
      gemm2_kernel<<<dim3((NN + 63) / 64, 1), 256, 0, stream>>>(
          emb_b, W1_t, semb1, semW2, wsum, NN, p, 0);
      pool_kernel<<<dim3(4, PCH, 1), 256, 0, stream>>>(emb_b, gid, partial, NN, p, 0);
    }
  }

  final_kernel<<<BG, 256, 0, stream>>>(partial, wsum, gid, clsW, clsb, out, NN);
}

// Round 7
// 687.928 us; speedup vs baseline: 1.3434x; 1.3434x over previous
//
#include <hip/hip_runtime.h>

#define NN 50000
#define PM 4
#define EE 500000
#define INF_ 128
#define NH 8
#define FF 32
#define HF 256
#define HS 128
#define BG 128
#define OUTC 2

#define NB2 98        // buckets per path: dst>>9 (512 nodes/bucket)
#define BCAP 6144     // bucket capacity (mean 5102, sd ~71 -> 14 sigma slack)
#define BCH 4096      // edges per workgroup in bucket pass
#define GCAP 576      // nodes per graph capacity (mean 390, sd ~20 -> 9 sigma)

typedef __attribute__((ext_vector_type(8))) short bf16x8;
typedef __attribute__((ext_vector_type(4))) float f32x4;

__device__ __forceinline__ float b2f(unsigned short x) {
  unsigned u = ((unsigned)x) << 16;
  return __builtin_bit_cast(float, u);
}
__device__ __forceinline__ unsigned short f2b(float f) {
  unsigned u = __builtin_bit_cast(unsigned, f);
  u += 0x7fff + ((u >> 16) & 1);   // RNE
  return (unsigned short)(u >> 16);
}

// ---------------------------------------------------------------------------
// prep: zero gcnt/gcnt2/wsum + h->bf16 + Wg transpose + W1 transpose + fold
// ---------------------------------------------------------------------------
__global__ __launch_bounds__(256) void prep_kernel(
    const float* __restrict__ h, const float* __restrict__ Wg,
    const float* __restrict__ W1, const float* __restrict__ al,
    const float* __restrict__ ar,
    unsigned short* __restrict__ h_b, unsigned short* __restrict__ Wb_t,
    unsigned short* __restrict__ W1_t, float* __restrict__ wl,
    float* __restrict__ wr, int* __restrict__ gcnt, int* __restrict__ gcnt2,
    float* __restrict__ wsum) {
  int b = blockIdx.x;
  int tid = threadIdx.x;
  if (b < 1) {                 // zero gcnt + gcnt2 + wsum
    for (int i = tid; i < PM * NB2; i += 256) gcnt[i] = 0;
    if (tid < BG) gcnt2[tid] = 0;
    if (tid < PM) wsum[tid] = 0.f;
    return;
  }
  b -= 1;
  if (b < 6250) {              // h -> bf16 (float4 granular)
    int t = b * 256 + tid;
    float4 v = *(const float4*)(h + (size_t)t * 4);
    ushort4 o;
    o.x = f2b(v.x); o.y = f2b(v.y); o.z = f2b(v.z); o.w = f2b(v.w);
    *(ushort4*)(h_b + (size_t)t * 4) = o;
    return;
  }
  b -= 6250;
  if (b < 512) {               // Wg [P][128k][256n] -> [P][256n][128k] bf16
    int t = b * 256 + tid;
    int p = t >> 15, rem = t & 32767;
    int n = rem >> 7, k = rem & 127;
    Wb_t[(size_t)p * 32768 + n * 128 + k] = f2b(Wg[(size_t)p * 32768 + k * 256 + n]);
    return;
  }
  b -= 512;
  if (b < 128) {               // W1 [256k][128n] -> [128n][256k] bf16
    int t = b * 256 + tid;
    int n = t >> 8, k = t & 255;
    W1_t[n * 256 + k] = f2b(W1[k * 128 + n]);
    return;
  }
  b -= 128;
  {                            // fold: wl/wr[p][k][h]
    int t = b * 256 + tid;
    int p = t >> 10, rem = t & 1023;
    int k = rem >> 3, hh = rem & 7;
    const float* wrow = Wg + (size_t)p * 32768 + k * 256 + hh * 32;
    const float* alp = al + p * 256 + hh * 32;
    const float* arp = ar + p * 256 + hh * 32;
    float sl = 0.f, sr = 0.f;
    #pragma unroll
    for (int f = 0; f < 32; f++) { sl += wrow[f] * alp[f]; sr += wrow[f] * arp[f]; }
    wl[t] = sl; wr[t] = sr;
  }
}

// ---------------------------------------------------------------------------
// bucket: per-block histogram -> global segment reserve -> LDS-cursor scatter
// ---------------------------------------------------------------------------
__global__ __launch_bounds__(256) void bucket_kernel(
    const int* __restrict__ src, const int* __restrict__ dst,
    unsigned* __restrict__ bdata, int* __restrict__ gcnt) {
  __shared__ unsigned ed[BCH];
  __shared__ int hist[NB2], gbase[NB2], cur[NB2];
  int p = blockIdx.y;
  int e0 = blockIdx.x * BCH;
  int n = min(BCH, EE - e0);
  int tid = threadIdx.x;
  if (tid < NB2) hist[tid] = 0;
  __syncthreads();
  const int* sp = src + (size_t)p * EE + e0;
  const int* dp = dst + (size_t)p * EE + e0;
  for (int i = tid; i < n; i += 256) {
    int s = sp[i], d = dp[i];
    ed[i] = ((unsigned)d << 16) | (unsigned)s;
    atomicAdd(&hist[d >> 9], 1);
  }
  __syncthreads();
  if (tid < NB2) {
    gbase[tid] = atomicAdd(&gcnt[p * NB2 + tid], hist[tid]);
    cur[tid] = 0;
  }
  __syncthreads();
  for (int i = tid; i < n; i += 256) {
    unsigned pk = ed[i];
    int bk = pk >> 25;           // (dst>>9)
    int slot = gbase[bk] + atomicAdd(&cur[bk], 1);
    if (slot < BCAP)
      bdata[((size_t)(p * NB2 + bk)) * BCAP + slot] = pk;
  }
}

// ---------------------------------------------------------------------------
// gbucket: bin node ids by graph id -> glist[BG][GCAP] + per-graph counts
// ---------------------------------------------------------------------------
__global__ __launch_bounds__(256) void gbucket_kernel(
    const int* __restrict__ gid, int* __restrict__ glist, int* __restrict__ gcnt2) {
  __shared__ int gl[BCH];
  __shared__ int hist[BG], gbase[BG], cur[BG];
  int e0 = blockIdx.x * BCH;
  int n = min(BCH, NN - e0);
  int tid = threadIdx.x;
  if (tid < BG) hist[tid] = 0;
  __syncthreads();
  for (int i = tid; i < n; i += 256) {
    int g = gid[e0 + i];
    gl[i] = g;
    atomicAdd(&hist[g], 1);
  }
  __syncthreads();
  if (tid < BG) {
    gbase[tid] = atomicAdd(&gcnt2[tid], hist[tid]);
    cur[tid] = 0;
  }
  __syncthreads();
  for (int i = tid; i < n; i += 256) {
    int g = gl[i];
    int slot = gbase[g] + atomicAdd(&cur[g], 1);
    if (slot < GCAP) glist[g * GCAP + slot] = e0 + i;
  }
}

// ---------------------------------------------------------------------------
// csrify: per (bucket,path): 512-node local CSR in LDS -> global off/csr
// ---------------------------------------------------------------------------
__global__ __launch_bounds__(256) void csrify_kernel(
    const unsigned* __restrict__ bdata, const int* __restrict__ gcnt,
    int* __restrict__ off, unsigned short* __restrict__ csr) {
  __shared__ unsigned ebuf[BCAP];
  __shared__ int gc[NB2];
  __shared__ int degc[512];
  __shared__ int loff[513];
  __shared__ int tmp[256];
  __shared__ int base_s;
  int b = blockIdx.x, p = blockIdx.y;
  int tid = threadIdx.x;
  if (tid < NB2) gc[tid] = min(gcnt[p * NB2 + tid], BCAP);
  __syncthreads();
  if (tid == 0) {
    int s = 0;
    for (int i = 0; i < b; i++) s += gc[i];
    base_s = s;
  }
  int cnt = gc[b];
  const unsigned* bp = bdata + ((size_t)(p * NB2 + b)) * BCAP;
  for (int i = tid; i < cnt; i += 256) ebuf[i] = bp[i];
  degc[tid] = 0; degc[256 + tid] = 0;
  __syncthreads();
  for (int i = tid; i < cnt; i += 256)
    atomicAdd(&degc[(ebuf[i] >> 16) & 511], 1);
  __syncthreads();
  int d0 = degc[2 * tid], d1 = degc[2 * tid + 1];
  tmp[tid] = d0 + d1;
  __syncthreads();
  for (int o = 1; o < 256; o <<= 1) {
    int v = (tid >= o) ? tmp[tid - o] : 0;
    __syncthreads();
    tmp[tid] += v;
    __syncthreads();
  }
  int bse = tmp[tid] - d0 - d1;
  loff[2 * tid] = bse; loff[2 * tid + 1] = bse + d0;
  if (tid == 255) loff[512] = tmp[255];
  __syncthreads();
  int base = base_s;
  for (int dl = tid; dl < 512; dl += 256) {
    int n = b * 512 + dl;
    if (n <= NN) off[(size_t)p * (NN + 1) + n] = base + loff[dl];
  }
  degc[tid] = 0; degc[256 + tid] = 0;   // reuse as cursors
  __syncthreads();
  for (int i = tid; i < cnt; i += 256) {
    unsigned pk = ebuf[i];
    int dl = (pk >> 16) & 511;
    int slot = loff[dl] + atomicAdd(&degc[dl], 1);
    csr[(size_t)p * EE + base + slot] = (unsigned short)(pk & 0xffff);
  }
}

// ---------------------------------------------------------------------------
// GEMM1: hp_b[p][M,256] = h_b[M,128] @ W[p], MFMA bf16. p = p0 + blockIdx.z.
// ---------------------------------------------------------------------------
__global__ __launch_bounds__(256) void gemm1_kernel(
    const unsigned short* __restrict__ hA, const unsigned short* __restrict__ Bt,
    unsigned short* __restrict__ Cb, int M, int p0, size_t cstride) {
  __shared__ unsigned short As[64 * 128];
  __shared__ unsigned short Bs[128 * 128];
  int tid = threadIdx.x;
  int pl = blockIdx.z;
  const unsigned short* Bp = Bt + (size_t)(p0 + pl) * 32768;
  unsigned short* Cp = Cb + (size_t)pl * cstride;
  int row0 = blockIdx.x * 64, col0 = blockIdx.y * 128;
  #pragma unroll
  for (int i = 0; i < 4; i++) {
    int c = i * 256 + tid;
    int row = c >> 4, g = c & 15;
    int grow = row0 + row;
    uint4 v = make_uint4(0, 0, 0, 0);
    if (grow < M) v = *(const uint4*)(hA + (size_t)grow * 128 + g * 8);
    *(uint4*)&As[row * 128 + ((g ^ (row & 15)) << 3)] = v;
  }
  #pragma unroll
  for (int i = 0; i < 8; i++) {
    int c = i * 256 + tid;
    int row = c >> 4, g = c & 15;
    uint4 v = *(const uint4*)(Bp + (size_t)(col0 + row) * 128 + g * 8);
    *(uint4*)&Bs[row * 128 + ((g ^ (row & 15)) << 3)] = v;
  }
  __syncthreads();
  int wave = tid >> 6, lane = tid & 63;
  int ln = lane & 15, quad = lane >> 4;
  int mbase = (wave >> 1) * 32, nbase = (wave & 1) * 64;
  f32x4 acc[2][4] = {};
  #pragma unroll
  for (int ks = 0; ks < 4; ks++) {
    int g = ks * 4 + quad;
    bf16x8 a[2], bb[4];
    #pragma unroll
    for (int mi = 0; mi < 2; mi++) {
      int r = mbase + mi * 16 + ln;
      a[mi] = *(const bf16x8*)&As[r * 128 + ((g ^ ln) << 3)];
    }
    #pragma unroll
    for (int ni = 0; ni < 4; ni++) {
      int r = nbase + ni * 16 + ln;
      bb[ni] = *(const bf16x8*)&Bs[r * 128 + ((g ^ ln) << 3)];
    }
    #pragma unroll
    for (int mi = 0; mi < 2; mi++)
      #pragma unroll
      for (int ni = 0; ni < 4; ni++)
        acc[mi][ni] = __builtin_amdgcn_mfma_f32_16x16x32_bf16(a[mi], bb[ni], acc[mi][ni], 0, 0, 0);
  }
  #pragma unroll
  for (int mi = 0; mi < 2; mi++) {
    int gm0 = row0 + mbase + mi * 16 + quad * 4;
    #pragma unroll
    for (int ni = 0; ni < 4; ni++) {
      int gn = col0 + nbase + ni * 16 + ln;
      #pragma unroll
      for (int r = 0; r < 4; r++) {
        int gm = gm0 + r;
        if (gm < M) Cp[(size_t)gm * 256 + gn] = f2b(acc[mi][ni][r]);
      }
    }
  }
}

// ---------------------------------------------------------------------------
// elr: el/er = h @ folded weights (fp32 exact). p = p0 + blockIdx.y.
// ---------------------------------------------------------------------------
__global__ __launch_bounds__(256) void elr_kernel(
    const float* __restrict__ h, const float* __restrict__ wl,
    const float* __restrict__ wr, float* __restrict__ el,
    float* __restrict__ er, int N, int p0, size_t estride) {
  __shared__ float wls[128 * 8], wrs[128 * 8];
  int pl = blockIdx.y;
  const float* wlp = wl + (size_t)(p0 + pl) * 1024;
  const float* wrp = wr + (size_t)(p0 + pl) * 1024;
  float* elp = el + (size_t)pl * estride;
  float* erp = er + (size_t)pl * estride;
  for (int i = threadIdx.x; i < 1024; i += 256) { wls[i] = wlp[i]; wrs[i] = wrp[i]; }
  __syncthreads();
  int n = blockIdx.x * 256 + threadIdx.x;
  if (n >= N) return;
  float accl[8] = {}, accr[8] = {};
  for (int k4 = 0; k4 < 32; k4++) {
    float4 hv = *(const float4*)(h + (size_t)n * 128 + k4 * 4);
    float vv[4] = {hv.x, hv.y, hv.z, hv.w};
    #pragma unroll
    for (int j = 0; j < 4; j++) {
      float v = vv[j];
      int k = k4 * 4 + j;
      #pragma unroll
      for (int hh = 0; hh < 8; hh++) {
        accl[hh] += v * wls[k * 8 + hh];
        accr[hh] += v * wrs[k * 8 + hh];
      }
    }
  }
  *(float4*)(elp + (size_t)n * 8)     = make_float4(accl[0], accl[1], accl[2], accl[3]);
  *(float4*)(elp + (size_t)n * 8 + 4) = make_float4(accl[4], accl[5], accl[6], accl[7]);
  *(float4*)(erp + (size_t)n * 8)     = make_float4(accr[0], accr[1], accr[2], accr[3]);
  *(float4*)(erp + (size_t)n * 8 + 4) = make_float4(accr[4], accr[5], accr[6], accr[7]);
}

// ---------------------------------------------------------------------------
// agg: one wave per dst node: out = (sum w*hp)/(sum w), +bias, ELU -> bf16.
// ---------------------------------------------------------------------------
__global__ __launch_bounds__(256) void agg_kernel(
    const unsigned short* __restrict__ hp_b, const float* __restrict__ el,
    const float* __restrict__ er, const unsigned short* __restrict__ csr,
    const int* __restrict__ off, const float* __restrict__ bias,
    unsigned short* __restrict__ emb_b, int N, int p0,
    size_t hstride, size_t estride, size_t embstride) {
  int pl = blockIdx.y;
  int p = p0 + pl;
  const unsigned short* hp = hp_b + (size_t)pl * hstride;
  const float* elp = el + (size_t)pl * estride;
  const float* erp = er + (size_t)pl * estride;
  const unsigned short* csrp = csr + (size_t)p * EE;
  const int* offp = off + (size_t)p * (NN + 1);
  const float* bp = bias + (size_t)p * HF;
  unsigned short* embp = emb_b + (size_t)pl * embstride;
  int n = blockIdx.x * 4 + (threadIdx.x >> 6);
  if (n >= N) return;
  int lane = threadIdx.x & 63;
  int h = lane >> 3;
  int e0 = offp[n], e1 = offp[n + 1];
  float erh = erp[n * NH + h];
  float den = 0.f, a0 = 0.f, a1 = 0.f, a2 = 0.f, a3 = 0.f;
  for (int e = e0; e < e1; e++) {
    int s = csrp[e];
    float x = elp[s * NH + h] + erh;
    x = (x > 0.f) ? x : 0.2f * x;
    float w = expf(x);
    den += w;
    ushort4 hv = *(const ushort4*)(hp + (size_t)s * HF + lane * 4);
    a0 += w * b2f(hv.x); a1 += w * b2f(hv.y);
    a2 += w * b2f(hv.z); a3 += w * b2f(hv.w);
  }
  float inv = (den > 0.f) ? 1.f / den : 0.f;
  float4 bv = *(const float4*)(bp + lane * 4);
  float o0 = a0 * inv + bv.x, o1 = a1 * inv + bv.y;
  float o2 = a2 * inv + bv.z, o3 = a3 * inv + bv.w;
  o0 = (o0 > 0.f) ? o0 : expf(o0) - 1.f;
  o1 = (o1 > 0.f) ? o1 : expf(o1) - 1.f;
  o2 = (o2 > 0.f) ? o2 : expf(o2) - 1.f;
  o3 = (o3 > 0.f) ? o3 : expf(o3) - 1.f;
  ushort4 ov;
  ov.x = f2b(o0); ov.y = f2b(o1); ov.z = f2b(o2); ov.w = f2b(o3);
  *(ushort4*)(embp + (size_t)n * HF + lane * 4) = ov;
}

// ---------------------------------------------------------------------------
// GEMM2 + semantic epilogue: wsum[p] += sum tanh(emb@W1+b1).W2
// ---------------------------------------------------------------------------
__global__ __launch_bounds__(256) void gemm2_kernel(
    const unsigned short* __restrict__ A, const unsigned short* __restrict__ Bt,
    const float* __restrict__ b1, const float* __restrict__ W2,
    float* __restrict__ wsum, int M, int p0, size_t astride) {
  __shared__ unsigned short As[64 * 128];
  __shared__ unsigned short Bs[128 * 128];
  int tid = threadIdx.x;
  int pl = blockIdx.y;
  const unsigned short* Ap = A + (size_t)pl * astride;
  int row0 = blockIdx.x * 64;
  int wave = tid >> 6, lane = tid & 63;
  int ln = lane & 15, quad = lane >> 4;
  int mbase = (wave >> 1) * 32, nbase = (wave & 1) * 64;
  f32x4 acc[2][4] = {};
  for (int kc = 0; kc < 2; kc++) {
    #pragma unroll
    for (int i = 0; i < 4; i++) {
      int c = i * 256 + tid;
      int row = c >> 4, g = c & 15;
      int grow = row0 + row;
      uint4 v = make_uint4(0, 0, 0, 0);
      if (grow < M) v = *(const uint4*)(Ap + (size_t)grow * 256 + kc * 128 + g * 8);
      *(uint4*)&As[row * 128 + ((g ^ (row & 15)) << 3)] = v;
    }
    #pragma unroll
    for (int i = 0; i < 8; i++) {
      int c = i * 256 + tid;
      int row = c >> 4, g = c & 15;
      uint4 v = *(const uint4*)(Bt + (size_t)row * 256 + kc * 128 + g * 8);
      *(uint4*)&Bs[row * 128 + ((g ^ (row & 15)) << 3)] = v;
    }
    __syncthreads();
    #pragma unroll
    for (int ks = 0; ks < 4; ks++) {
      int g = ks * 4 + quad;
      bf16x8 a[2], bb[4];
      #pragma unroll
      for (int mi = 0; mi < 2; mi++) {
        int r = mbase + mi * 16 + ln;
        a[mi] = *(const bf16x8*)&As[r * 128 + ((g ^ ln) << 3)];
      }
      #pragma unroll
      for (int ni = 0; ni < 4; ni++) {
        int r = nbase + ni * 16 + ln;
        bb[ni] = *(const bf16x8*)&Bs[r * 128 + ((g ^ ln) << 3)];
      }
      #pragma unroll
      for (int mi = 0; mi < 2; mi++)
        #pragma unroll
        for (int ni = 0; ni < 4; ni++)
          acc[mi][ni] = __builtin_amdgcn_mfma_f32_16x16x32_bf16(a[mi], bb[ni], acc[mi][ni], 0, 0, 0);
    }
    __syncthreads();
  }
  float b1v[4], w2v[4];
  #pragma unroll
  for (int ni = 0; ni < 4; ni++) {
    int col = nbase + ni * 16 + ln;
    b1v[ni] = b1[col]; w2v[ni] = W2[col];
  }
  float s = 0.f;
  #pragma unroll
  for (int mi = 0; mi < 2; mi++) {
    int gm0 = row0 + mbase + mi * 16 + quad * 4;
    #pragma unroll
    for (int r = 0; r < 4; r++) {
      if (gm0 + r < M) {
        #pragma unroll
        for (int ni = 0; ni < 4; ni++)
          s += tanhf(acc[mi][ni][r] + b1v[ni]) * w2v[ni];
      }
    }
  }
  #pragma unroll
  for (int o = 32; o > 0; o >>= 1) s += __shfl_down(s, o);
  if (lane == 0) atomicAdd(&wsum[p0 + pl], s);
}

// ---------------------------------------------------------------------------
// pool v3: one block per (graph, path). Node list from glist; register
// accumulation (4 nodes/iter, ushort4/thread), no atomics anywhere.
// ---------------------------------------------------------------------------
__global__ __launch_bounds__(256) void pool_kernel(
    const unsigned short* __restrict__ emb, const int* __restrict__ glist,
    const int* __restrict__ gcnt2, float* __restrict__ pool,
    int p0, size_t embstride) {
  __shared__ int nl[GCAP];
  __shared__ float sm[4][64][4];
  int b = blockIdx.x, pl = blockIdx.y;
  const unsigned short* embp = emb + (size_t)pl * embstride;
  int tid = threadIdx.x;
  int cnt = min(gcnt2[b], GCAP);
  for (int i = tid; i < cnt; i += 256) nl[i] = glist[b * GCAP + i];
  __syncthreads();
  int sub = tid >> 6, lane = tid & 63;
  float a0 = 0.f, a1 = 0.f, a2 = 0.f, a3 = 0.f;
  for (int i = sub; i < cnt; i += 4) {
    ushort4 v = *(const ushort4*)(embp + (size_t)nl[i] * HF + lane * 4);
    a0 += b2f(v.x); a1 += b2f(v.y); a2 += b2f(v.z); a3 += b2f(v.w);
  }
  sm[sub][lane][0] = a0; sm[sub][lane][1] = a1;
  sm[sub][lane][2] = a2; sm[sub][lane][3] = a3;
  __syncthreads();
  // feat f = tid: lane=f>>2, j=f&3; sum 4 subgroups
  int fl = tid >> 2, j = tid & 3;
  float s = sm[0][fl][j] + sm[1][fl][j] + sm[2][fl][j] + sm[3][fl][j];
  pool[((size_t)(p0 + pl) * BG + b) * HF + tid] = s;
}

// ---------------------------------------------------------------------------
// final: counts from gcnt2, beta softmax, fuse, logits + pooled out
// ---------------------------------------------------------------------------
__global__ __launch_bounds__(256) void final_kernel(
    const float* __restrict__ pool, const float* __restrict__ wsum,
    const int* __restrict__ gcnt2, const float* __restrict__ clsW,
    const float* __restrict__ clsb, float* __restrict__ out, int N) {
  int b = blockIdx.x;
  int f = threadIdx.x;
  float c = fmaxf((float)gcnt2[b], 1.f);
  float wm[PM];
  float mx = -1e30f;
  #pragma unroll
  for (int p = 0; p < PM; p++) { wm[p] = wsum[p] / (float)N; mx = fmaxf(mx, wm[p]); }
  float es = 0.f, e[PM];
  #pragma unroll
  for (int p = 0; p < PM; p++) { e[p] = expf(wm[p] - mx); es += e[p]; }
  float v = 0.f;
  #pragma unroll
  for (int p = 0; p < PM; p++)
    v += (e[p] / es) * pool[((size_t)p * BG + b) * HF + f];
  v /= c;
  out[256 + (size_t)b * HF + f] = v;
  __shared__ float sm[256];
  sm[f] = v * clsW[f * 2 + 0];
  __syncthreads();
  for (int st = 128; st > 0; st >>= 1) {
    if (f < st) sm[f] += sm[f + st];
    __syncthreads();
  }
  float l0 = sm[0];
  __syncthreads();
  sm[f] = v * clsW[f * 2 + 1];
  __syncthreads();
  for (int st = 128; st > 0; st >>= 1) {
    if (f < st) sm[f] += sm[f + st];
    __syncthreads();
  }
  if (f == 0) {
    out[b * 2 + 0] = l0 + clsb[0];
    out[b * 2 + 1] = sm[0] + clsb[1];
  }
}

// ---------------------------------------------------------------------------
extern "C" void kernel_launch(void* const* d_in, const int* in_sizes, int n_in,
                              void* d_out, int out_size, void* d_ws, size_t ws_size,
                              hipStream_t stream) {
  const float* h      = (const float*)d_in[0];
  const float* Wg     = (const float*)d_in[1];
  const float* attn_l = (const float*)d_in[2];
  const float* attn_r = (const float*)d_in[3];
  const float* gatb   = (const float*)d_in[4];
  const float* semW1  = (const float*)d_in[5];
  const float* semb1  = (const float*)d_in[6];
  const float* semW2  = (const float*)d_in[7];
  const float* clsW   = (const float*)d_in[8];
  const float* clsb   = (const float*)d_in[9];
  const int*   src    = (const int*)d_in[10];
  const int*   dst    = (const int*)d_in[11];
  const int*   gid    = (const int*)d_in[12];
  float* out = (float*)d_out;

  auto layout_size = [](int PMg) -> size_t {
    size_t o = 0;
    auto alloc = [&](size_t bytes) { o += (bytes + 255) & ~(size_t)255; };
    alloc((size_t)NN * INF_ * 2);              // h_b
    alloc((size_t)PMg * NN * HF * 2);          // hp_b
    alloc((size_t)PMg * NN * HF * 2);          // emb_b
    alloc((size_t)PM * HF * INF_ * 2);         // Wb_t
    alloc((size_t)HS * HF * 2);                // W1_t
    alloc((size_t)PM * INF_ * NH * 4);         // wl
    alloc((size_t)PM * INF_ * NH * 4);         // wr
    alloc((size_t)PMg * NN * NH * 4);          // el
    alloc((size_t)PMg * NN * NH * 4);          // er
    alloc((size_t)PM * NB2 * BCAP * 4);        // bdata
    alloc((size_t)PM * NB2 * 4);               // gcnt
    alloc((size_t)BG * GCAP * 4);              // glist
    alloc((size_t)BG * 4);                     // gcnt2
    alloc((size_t)PM * (NN + 1) * 4);          // off
    alloc((size_t)PM * EE * 2);                // csr
    alloc((size_t)PM * BG * HF * 4);           // pool
    alloc(PM * 4);                             // wsum
    return o;
  };
  int PMg = (layout_size(4) <= ws_size) ? 4 : 1;

  char* ws = (char*)d_ws;
  size_t o = 0;
  auto alloc = [&](size_t bytes) { size_t r = o; o += (bytes + 255) & ~(size_t)255; return r; };
  unsigned short* h_b   = (unsigned short*)(ws + alloc((size_t)NN * INF_ * 2));
  unsigned short* hp_b  = (unsigned short*)(ws + alloc((size_t)PMg * NN * HF * 2));
  unsigned short* emb_b = (unsigned short*)(ws + alloc((size_t)PMg * NN * HF * 2));
  unsigned short* Wb_t  = (unsigned short*)(ws + alloc((size_t)PM * HF * INF_ * 2));
  unsigned short* W1_t  = (unsigned short*)(ws + alloc((size_t)HS * HF * 2));
  float* wl    = (float*)(ws + alloc((size_t)PM * INF_ * NH * 4));
  float* wr    = (float*)(ws + alloc((size_t)PM * INF_ * NH * 4));
  float* el    = (float*)(ws + alloc((size_t)PMg * NN * NH * 4));
  float* er    = (float*)(ws + alloc((size_t)PMg * NN * NH * 4));
  unsigned* bdata = (unsigned*)(ws + alloc((size_t)PM * NB2 * BCAP * 4));
  int*   gcnt  = (int*)(ws + alloc((size_t)PM * NB2 * 4));
  int*   glist = (int*)(ws + alloc((size_t)BG * GCAP * 4));
  int*   gcnt2 = (int*)(ws + alloc((size_t)BG * 4));
  int*   off   = (int*)(ws + alloc((size_t)PM * (NN + 1) * 4));
  unsigned short* csr = (unsigned short*)(ws + alloc((size_t)PM * EE * 2));
  float* pool  = (float*)(ws + alloc((size_t)PM * BG * HF * 4));
  float* wsum  = (float*)(ws + alloc(PM * 4));

  const size_t hpS  = (PMg == 4) ? (size_t)NN * HF : 0;
  const size_t embS = hpS;
  const size_t elS  = (PMg == 4) ? (size_t)NN * NH : 0;

  prep_kernel<<<1 + 6250 + 512 + 128 + 16, 256, 0, stream>>>(
      h, Wg, semW1, attn_l, attn_r, h_b, Wb_t, W1_t, wl, wr, gcnt, gcnt2, wsum);
  bucket_kernel<<<dim3((EE + BCH - 1) / BCH, PM), 256, 0, stream>>>(src, dst, bdata, gcnt);
  gbucket_kernel<<<(NN + BCH - 1) / BCH, 256, 0, stream>>>(gid, glist, gcnt2);
  csrify_kernel<<<dim3(NB2, PM), 256, 0, stream>>>(bdata, gcnt, off, csr);

  if (PMg == 4) {
    gemm1_kernel<<<dim3((NN + 63) / 64, 2, 4), 256, 0, stream>>>(h_b, Wb_t, hp_b, NN, 0, hpS);
    elr_kernel<<<dim3((NN + 255) / 256, 4), 256, 0, stream>>>(h, wl, wr, el, er, NN, 0, elS);
    agg_kernel<<<dim3((NN + 3) / 4, 4), 256, 0, stream>>>(
        hp_b, el, er, csr, off, gatb, emb_b, NN, 0, hpS, elS, embS);
    gemm2_kernel<<<dim3((NN + 63) / 64, 4), 256, 0, stream>>>(
        emb_b, W1_t, semb1, semW2, wsum, NN, 0, embS);
    pool_kernel<<<dim3(BG, 4), 256, 0, stream>>>(emb_b, glist, gcnt2, pool, 0, embS);
  } else {
    for (int p = 0; p < PM; p++) {
      gemm1_kernel<<<dim3((NN + 63) / 64, 2, 1), 256, 0, stream>>>(h_b, Wb_t, hp_b, NN, p, 0);
      elr_kernel<<<dim3((NN + 255) / 256, 1), 256, 0, stream>>>(h, wl, wr, el, er, NN, p, 0);
      agg_kernel<<<dim3((NN + 3) / 4, 1), 256, 0, stream>>>(
          hp_b, el, er, csr, off, gatb, emb_b, NN, p, 0, 0, 0);
      gemm2_kernel<<<dim3((NN + 63) / 64, 1), 256, 0, stream>>>(
          emb_b, W1_t, semb1, semW2, wsum, NN, p, 0);
      pool_kernel<<<dim3(BG, 1), 256, 0, stream>>>(emb_b, glist, gcnt2, pool, p, 0);
    }
  }

  final_kernel<<<BG, 256, 0, stream>>>(pool, wsum, gcnt2, clsW, clsb, out, NN);
}

// Round 8
// 663.097 us; speedup vs baseline: 1.3938x; 1.0374x over previous
//
#include <hip/hip_runtime.h>

#define NN 50000
#define PM 4
#define EE 500000
#define INF_ 128
#define NH 8
#define FF 32
#define HF 256
#define HS 128
#define BG 128
#define OUTC 2

#define NB2 98        // buckets per path: dst>>9 (512 nodes/bucket)
#define BCAP 6144     // bucket capacity (mean 5102, sd ~71 -> 14 sigma slack)
#define BCH 4096      // edges per workgroup in bucket pass
#define GCAP 576      // nodes per graph capacity (mean 390, sd ~20 -> 9 sigma)

typedef __attribute__((ext_vector_type(8))) short bf16x8;
typedef __attribute__((ext_vector_type(4))) float f32x4;

__device__ __forceinline__ float b2f(unsigned short x) {
  unsigned u = ((unsigned)x) << 16;
  return __builtin_bit_cast(float, u);
}
__device__ __forceinline__ unsigned short f2b(float f) {
  unsigned u = __builtin_bit_cast(unsigned, f);
  u += 0x7fff + ((u >> 16) & 1);   // RNE
  return (unsigned short)(u >> 16);
}
// fast exp (v_exp_f32 path); inputs here are bounded (logits ~<10, ELU arg <0)
__device__ __forceinline__ float fexp(float x) { return __expf(x); }
// overflow-safe fast tanh: t = e^{-2|x|} in (0,1]
__device__ __forceinline__ float ftanh(float x) {
  float t = __expf(-2.f * fabsf(x));
  float r = (1.f - t) / (1.f + t);
  return copysignf(r, x);
}

// ---------------------------------------------------------------------------
// prep: zero gcnt/gcnt2/wsum + h->bf16 + Wg transpose + W1 transpose + fold
// ---------------------------------------------------------------------------
__global__ __launch_bounds__(256) void prep_kernel(
    const float* __restrict__ h, const float* __restrict__ Wg,
    const float* __restrict__ W1, const float* __restrict__ al,
    const float* __restrict__ ar,
    unsigned short* __restrict__ h_b, unsigned short* __restrict__ Wb_t,
    unsigned short* __restrict__ W1_t, float* __restrict__ wl,
    float* __restrict__ wr, int* __restrict__ gcnt, int* __restrict__ gcnt2,
    float* __restrict__ wsum) {
  int b = blockIdx.x;
  int tid = threadIdx.x;
  if (b < 1) {                 // zero gcnt + gcnt2 + wsum
    for (int i = tid; i < PM * NB2; i += 256) gcnt[i] = 0;
    if (tid < BG) gcnt2[tid] = 0;
    if (tid < PM) wsum[tid] = 0.f;
    return;
  }
  b -= 1;
  if (b < 6250) {              // h -> bf16 (float4 granular)
    int t = b * 256 + tid;
    float4 v = *(const float4*)(h + (size_t)t * 4);
    ushort4 o;
    o.x = f2b(v.x); o.y = f2b(v.y); o.z = f2b(v.z); o.w = f2b(v.w);
    *(ushort4*)(h_b + (size_t)t * 4) = o;
    return;
  }
  b -= 6250;
  if (b < 512) {               // Wg [P][128k][256n] -> [P][256n][128k] bf16
    int t = b * 256 + tid;
    int p = t >> 15, rem = t & 32767;
    int n = rem >> 7, k = rem & 127;
    Wb_t[(size_t)p * 32768 + n * 128 + k] = f2b(Wg[(size_t)p * 32768 + k * 256 + n]);
    return;
  }
  b -= 512;
  if (b < 128) {               // W1 [256k][128n] -> [128n][256k] bf16
    int t = b * 256 + tid;
    int n = t >> 8, k = t & 255;
    W1_t[n * 256 + k] = f2b(W1[k * 128 + n]);
    return;
  }
  b -= 128;
  {                            // fold: wl/wr[p][k][h]
    int t = b * 256 + tid;
    int p = t >> 10, rem = t & 1023;
    int k = rem >> 3, hh = rem & 7;
    const float* wrow = Wg + (size_t)p * 32768 + k * 256 + hh * 32;
    const float* alp = al + p * 256 + hh * 32;
    const float* arp = ar + p * 256 + hh * 32;
    float sl = 0.f, sr = 0.f;
    #pragma unroll
    for (int f = 0; f < 32; f++) { sl += wrow[f] * alp[f]; sr += wrow[f] * arp[f]; }
    wl[t] = sl; wr[t] = sr;
  }
}

// ---------------------------------------------------------------------------
// bucket: per-block histogram -> global segment reserve -> LDS-cursor scatter
// ---------------------------------------------------------------------------
__global__ __launch_bounds__(256) void bucket_kernel(
    const int* __restrict__ src, const int* __restrict__ dst,
    unsigned* __restrict__ bdata, int* __restrict__ gcnt) {
  __shared__ unsigned ed[BCH];
  __shared__ int hist[NB2], gbase[NB2], cur[NB2];
  int p = blockIdx.y;
  int e0 = blockIdx.x * BCH;
  int n = min(BCH, EE - e0);
  int tid = threadIdx.x;
  if (tid < NB2) hist[tid] = 0;
  __syncthreads();
  const int* sp = src + (size_t)p * EE + e0;
  const int* dp = dst + (size_t)p * EE + e0;
  for (int i = tid; i < n; i += 256) {
    int s = sp[i], d = dp[i];
    ed[i] = ((unsigned)d << 16) | (unsigned)s;
    atomicAdd(&hist[d >> 9], 1);
  }
  __syncthreads();
  if (tid < NB2) {
    gbase[tid] = atomicAdd(&gcnt[p * NB2 + tid], hist[tid]);
    cur[tid] = 0;
  }
  __syncthreads();
  for (int i = tid; i < n; i += 256) {
    unsigned pk = ed[i];
    int bk = pk >> 25;           // (dst>>9)
    int slot = gbase[bk] + atomicAdd(&cur[bk], 1);
    if (slot < BCAP)
      bdata[((size_t)(p * NB2 + bk)) * BCAP + slot] = pk;
  }
}

// ---------------------------------------------------------------------------
// gbucket: bin node ids by graph id -> glist[BG][GCAP] + per-graph counts
// ---------------------------------------------------------------------------
__global__ __launch_bounds__(256) void gbucket_kernel(
    const int* __restrict__ gid, int* __restrict__ glist, int* __restrict__ gcnt2) {
  __shared__ int gl[BCH];
  __shared__ int hist[BG], gbase[BG], cur[BG];
  int e0 = blockIdx.x * BCH;
  int n = min(BCH, NN - e0);
  int tid = threadIdx.x;
  if (tid < BG) hist[tid] = 0;
  __syncthreads();
  for (int i = tid; i < n; i += 256) {
    int g = gid[e0 + i];
    gl[i] = g;
    atomicAdd(&hist[g], 1);
  }
  __syncthreads();
  if (tid < BG) {
    gbase[tid] = atomicAdd(&gcnt2[tid], hist[tid]);
    cur[tid] = 0;
  }
  __syncthreads();
  for (int i = tid; i < n; i += 256) {
    int g = gl[i];
    int slot = gbase[g] + atomicAdd(&cur[g], 1);
    if (slot < GCAP) glist[g * GCAP + slot] = e0 + i;
  }
}

// ---------------------------------------------------------------------------
// csrify: per (bucket,path): 512-node local CSR in LDS -> global off/csr
// ---------------------------------------------------------------------------
__global__ __launch_bounds__(256) void csrify_kernel(
    const unsigned* __restrict__ bdata, const int* __restrict__ gcnt,
    int* __restrict__ off, unsigned short* __restrict__ csr) {
  __shared__ unsigned ebuf[BCAP];
  __shared__ int gc[NB2];
  __shared__ int degc[512];
  __shared__ int loff[513];
  __shared__ int tmp[256];
  __shared__ int base_s;
  int b = blockIdx.x, p = blockIdx.y;
  int tid = threadIdx.x;
  if (tid < NB2) gc[tid] = min(gcnt[p * NB2 + tid], BCAP);
  __syncthreads();
  if (tid == 0) {
    int s = 0;
    for (int i = 0; i < b; i++) s += gc[i];
    base_s = s;
  }
  int cnt = gc[b];
  const unsigned* bp = bdata + ((size_t)(p * NB2 + b)) * BCAP;
  for (int i = tid; i < cnt; i += 256) ebuf[i] = bp[i];
  degc[tid] = 0; degc[256 + tid] = 0;
  __syncthreads();
  for (int i = tid; i < cnt; i += 256)
    atomicAdd(&degc[(ebuf[i] >> 16) & 511], 1);
  __syncthreads();
  int d0 = degc[2 * tid], d1 = degc[2 * tid + 1];
  tmp[tid] = d0 + d1;
  __syncthreads();
  for (int o = 1; o < 256; o <<= 1) {
    int v = (tid >= o) ? tmp[tid - o] : 0;
    __syncthreads();
    tmp[tid] += v;
    __syncthreads();
  }
  int bse = tmp[tid] - d0 - d1;
  loff[2 * tid] = bse; loff[2 * tid + 1] = bse + d0;
  if (tid == 255) loff[512] = tmp[255];
  __syncthreads();
  int base = base_s;
  for (int dl = tid; dl < 512; dl += 256) {
    int n = b * 512 + dl;
    if (n <= NN) off[(size_t)p * (NN + 1) + n] = base + loff[dl];
  }
  degc[tid] = 0; degc[256 + tid] = 0;   // reuse as cursors
  __syncthreads();
  for (int i = tid; i < cnt; i += 256) {
    unsigned pk = ebuf[i];
    int dl = (pk >> 16) & 511;
    int slot = loff[dl] + atomicAdd(&degc[dl], 1);
    csr[(size_t)p * EE + base + slot] = (unsigned short)(pk & 0xffff);
  }
}

// ---------------------------------------------------------------------------
// GEMM1: hp_b[p][M,256] = h_b[M,128] @ W[p], MFMA bf16. p = p0 + blockIdx.z.
// ---------------------------------------------------------------------------
__global__ __launch_bounds__(256) void gemm1_kernel(
    const unsigned short* __restrict__ hA, const unsigned short* __restrict__ Bt,
    unsigned short* __restrict__ Cb, int M, int p0, size_t cstride) {
  __shared__ unsigned short As[64 * 128];
  __shared__ unsigned short Bs[128 * 128];
  int tid = threadIdx.x;
  int pl = blockIdx.z;
  const unsigned short* Bp = Bt + (size_t)(p0 + pl) * 32768;
  unsigned short* Cp = Cb + (size_t)pl * cstride;
  int row0 = blockIdx.x * 64, col0 = blockIdx.y * 128;
  #pragma unroll
  for (int i = 0; i < 4; i++) {
    int c = i * 256 + tid;
    int row = c >> 4, g = c & 15;
    int grow = row0 + row;
    uint4 v = make_uint4(0, 0, 0, 0);
    if (grow < M) v = *(const uint4*)(hA + (size_t)grow * 128 + g * 8);
    *(uint4*)&As[row * 128 + ((g ^ (row & 15)) << 3)] = v;
  }
  #pragma unroll
  for (int i = 0; i < 8; i++) {
    int c = i * 256 + tid;
    int row = c >> 4, g = c & 15;
    uint4 v = *(const uint4*)(Bp + (size_t)(col0 + row) * 128 + g * 8);
    *(uint4*)&Bs[row * 128 + ((g ^ (row & 15)) << 3)] = v;
  }
  __syncthreads();
  int wave = tid >> 6, lane = tid & 63;
  int ln = lane & 15, quad = lane >> 4;
  int mbase = (wave >> 1) * 32, nbase = (wave & 1) * 64;
  f32x4 acc[2][4] = {};
  #pragma unroll
  for (int ks = 0; ks < 4; ks++) {
    int g = ks * 4 + quad;
    bf16x8 a[2], bb[4];
    #pragma unroll
    for (int mi = 0; mi < 2; mi++) {
      int r = mbase + mi * 16 + ln;
      a[mi] = *(const bf16x8*)&As[r * 128 + ((g ^ ln) << 3)];
    }
    #pragma unroll
    for (int ni = 0; ni < 4; ni++) {
      int r = nbase + ni * 16 + ln;
      bb[ni] = *(const bf16x8*)&Bs[r * 128 + ((g ^ ln) << 3)];
    }
    #pragma unroll
    for (int mi = 0; mi < 2; mi++)
      #pragma unroll
      for (int ni = 0; ni < 4; ni++)
        acc[mi][ni] = __builtin_amdgcn_mfma_f32_16x16x32_bf16(a[mi], bb[ni], acc[mi][ni], 0, 0, 0);
  }
  #pragma unroll
  for (int mi = 0; mi < 2; mi++) {
    int gm0 = row0 + mbase + mi * 16 + quad * 4;
    #pragma unroll
    for (int ni = 0; ni < 4; ni++) {
      int gn = col0 + nbase + ni * 16 + ln;
      #pragma unroll
      for (int r = 0; r < 4; r++) {
        int gm = gm0 + r;
        if (gm < M) Cp[(size_t)gm * 256 + gn] = f2b(acc[mi][ni][r]);
      }
    }
  }
}

// ---------------------------------------------------------------------------
// elr: el/er = h_b (bf16) @ folded fp32 weights. p = p0 + blockIdx.y.
// ---------------------------------------------------------------------------
__global__ __launch_bounds__(256) void elr_kernel(
    const unsigned short* __restrict__ h_b, const float* __restrict__ wl,
    const float* __restrict__ wr, float* __restrict__ el,
    float* __restrict__ er, int N, int p0, size_t estride) {
  __shared__ float wls[128 * 8], wrs[128 * 8];
  int pl = blockIdx.y;
  const float* wlp = wl + (size_t)(p0 + pl) * 1024;
  const float* wrp = wr + (size_t)(p0 + pl) * 1024;
  float* elp = el + (size_t)pl * estride;
  float* erp = er + (size_t)pl * estride;
  for (int i = threadIdx.x; i < 1024; i += 256) { wls[i] = wlp[i]; wrs[i] = wrp[i]; }
  __syncthreads();
  int n = blockIdx.x * 256 + threadIdx.x;
  if (n >= N) return;
  float accl[8] = {}, accr[8] = {};
  for (int kk = 0; kk < 16; kk++) {          // 8 bf16 per step
    uint4 raw = *(const uint4*)(h_b + (size_t)n * 128 + kk * 8);
    unsigned uu[4] = {raw.x, raw.y, raw.z, raw.w};
    #pragma unroll
    for (int q = 0; q < 4; q++) {
      float v0 = __builtin_bit_cast(float, uu[q] << 16);
      float v1 = __builtin_bit_cast(float, uu[q] & 0xffff0000u);
      int k = kk * 8 + q * 2;
      #pragma unroll
      for (int hh = 0; hh < 8; hh++) {
        accl[hh] += v0 * wls[k * 8 + hh] + v1 * wls[(k + 1) * 8 + hh];
        accr[hh] += v0 * wrs[k * 8 + hh] + v1 * wrs[(k + 1) * 8 + hh];
      }
    }
  }
  *(float4*)(elp + (size_t)n * 8)     = make_float4(accl[0], accl[1], accl[2], accl[3]);
  *(float4*)(elp + (size_t)n * 8 + 4) = make_float4(accl[4], accl[5], accl[6], accl[7]);
  *(float4*)(erp + (size_t)n * 8)     = make_float4(accr[0], accr[1], accr[2], accr[3]);
  *(float4*)(erp + (size_t)n * 8 + 4) = make_float4(accr[4], accr[5], accr[6], accr[7]);
}

// ---------------------------------------------------------------------------
// agg: one wave per dst node: out = (sum w*hp)/(sum w), +bias, ELU -> bf16.
// ---------------------------------------------------------------------------
__global__ __launch_bounds__(256) void agg_kernel(
    const unsigned short* __restrict__ hp_b, const float* __restrict__ el,
    const float* __restrict__ er, const unsigned short* __restrict__ csr,
    const int* __restrict__ off, const float* __restrict__ bias,
    unsigned short* __restrict__ emb_b, int N, int p0,
    size_t hstride, size_t estride, size_t embstride) {
  int pl = blockIdx.y;
  int p = p0 + pl;
  const unsigned short* hp = hp_b + (size_t)pl * hstride;
  const float* elp = el + (size_t)pl * estride;
  const float* erp = er + (size_t)pl * estride;
  const unsigned short* csrp = csr + (size_t)p * EE;
  const int* offp = off + (size_t)p * (NN + 1);
  const float* bp = bias + (size_t)p * HF;
  unsigned short* embp = emb_b + (size_t)pl * embstride;
  int n = blockIdx.x * 4 + (threadIdx.x >> 6);
  if (n >= N) return;
  int lane = threadIdx.x & 63;
  int h = lane >> 3;
  int e0 = offp[n], e1 = offp[n + 1];
  float erh = erp[n * NH + h];
  float den = 0.f, a0 = 0.f, a1 = 0.f, a2 = 0.f, a3 = 0.f;
  for (int e = e0; e < e1; e++) {
    int s = csrp[e];
    float x = elp[s * NH + h] + erh;
    x = (x > 0.f) ? x : 0.2f * x;
    float w = fexp(x);
    den += w;
    ushort4 hv = *(const ushort4*)(hp + (size_t)s * HF + lane * 4);
    a0 += w * b2f(hv.x); a1 += w * b2f(hv.y);
    a2 += w * b2f(hv.z); a3 += w * b2f(hv.w);
  }
  float inv = (den > 0.f) ? 1.f / den : 0.f;
  float4 bv = *(const float4*)(bp + lane * 4);
  float o0 = a0 * inv + bv.x, o1 = a1 * inv + bv.y;
  float o2 = a2 * inv + bv.z, o3 = a3 * inv + bv.w;
  o0 = (o0 > 0.f) ? o0 : fexp(o0) - 1.f;
  o1 = (o1 > 0.f) ? o1 : fexp(o1) - 1.f;
  o2 = (o2 > 0.f) ? o2 : fexp(o2) - 1.f;
  o3 = (o3 > 0.f) ? o3 : fexp(o3) - 1.f;
  ushort4 ov;
  ov.x = f2b(o0); ov.y = f2b(o1); ov.z = f2b(o2); ov.w = f2b(o3);
  *(ushort4*)(embp + (size_t)n * HF + lane * 4) = ov;
}

// ---------------------------------------------------------------------------
// GEMM2 + semantic epilogue: wsum[p] += sum tanh(emb@W1+b1).W2
// ---------------------------------------------------------------------------
__global__ __launch_bounds__(256) void gemm2_kernel(
    const unsigned short* __restrict__ A, const unsigned short* __restrict__ Bt,
    const float* __restrict__ b1, const float* __restrict__ W2,
    float* __restrict__ wsum, int M, int p0, size_t astride) {
  __shared__ unsigned short As[64 * 128];
  __shared__ unsigned short Bs[128 * 128];
  int tid = threadIdx.x;
  int pl = blockIdx.y;
  const unsigned short* Ap = A + (size_t)pl * astride;
  int row0 = blockIdx.x * 64;
  int wave = tid >> 6, lane = tid & 63;
  int ln = lane & 15, quad = lane >> 4;
  int mbase = (wave >> 1) * 32, nbase = (wave & 1) * 64;
  f32x4 acc[2][4] = {};
  for (int kc = 0; kc < 2; kc++) {
    #pragma unroll
    for (int i = 0; i < 4; i++) {
      int c = i * 256 + tid;
      int row = c >> 4, g = c & 15;
      int grow = row0 + row;
      uint4 v = make_uint4(0, 0, 0, 0);
      if (grow < M) v = *(const uint4*)(Ap + (size_t)grow * 256 + kc * 128 + g * 8);
      *(uint4*)&As[row * 128 + ((g ^ (row & 15)) << 3)] = v;
    }
    #pragma unroll
    for (int i = 0; i < 8; i++) {
      int c = i * 256 + tid;
      int row = c >> 4, g = c & 15;
      uint4 v = *(const uint4*)(Bt + (size_t)row * 256 + kc * 128 + g * 8);
      *(uint4*)&Bs[row * 128 + ((g ^ (row & 15)) << 3)] = v;
    }
    __syncthreads();
    #pragma unroll
    for (int ks = 0; ks < 4; ks++) {
      int g = ks * 4 + quad;
      bf16x8 a[2], bb[4];
      #pragma unroll
      for (int mi = 0; mi < 2; mi++) {
        int r = mbase + mi * 16 + ln;
        a[mi] = *(const bf16x8*)&As[r * 128 + ((g ^ ln) << 3)];
      }
      #pragma unroll
      for (int ni = 0; ni < 4; ni++) {
        int r = nbase + ni * 16 + ln;
        bb[ni] = *(const bf16x8*)&Bs[r * 128 + ((g ^ ln) << 3)];
      }
      #pragma unroll
      for (int mi = 0; mi < 2; mi++)
        #pragma unroll
        for (int ni = 0; ni < 4; ni++)
          acc[mi][ni] = __builtin_amdgcn_mfma_f32_16x16x32_bf16(a[mi], bb[ni], acc[mi][ni], 0, 0, 0);
    }
    __syncthreads();
  }
  float b1v[4], w2v[4];
  #pragma unroll
  for (int ni = 0; ni < 4; ni++) {
    int col = nbase + ni * 16 + ln;
    b1v[ni] = b1[col]; w2v[ni] = W2[col];
  }
  float s = 0.f;
  #pragma unroll
  for (int mi = 0; mi < 2; mi++) {
    int gm0 = row0 + mbase + mi * 16 + quad * 4;
    #pragma unroll
    for (int r = 0; r < 4; r++) {
      if (gm0 + r < M) {
        #pragma unroll
        for (int ni = 0; ni < 4; ni++)
          s += ftanh(acc[mi][ni][r] + b1v[ni]) * w2v[ni];
      }
    }
  }
  #pragma unroll
  for (int o = 32; o > 0; o >>= 1) s += __shfl_down(s, o);
  if (lane == 0) atomicAdd(&wsum[p0 + pl], s);
}

// ---------------------------------------------------------------------------
// pool: one block per (graph, path); register accumulation, no atomics.
// ---------------------------------------------------------------------------
__global__ __launch_bounds__(256) void pool_kernel(
    const unsigned short* __restrict__ emb, const int* __restrict__ glist,
    const int* __restrict__ gcnt2, float* __restrict__ pool,
    int p0, size_t embstride) {
  __shared__ int nl[GCAP];
  __shared__ float sm[4][64][4];
  int b = blockIdx.x, pl = blockIdx.y;
  const unsigned short* embp = emb + (size_t)pl * embstride;
  int tid = threadIdx.x;
  int cnt = min(gcnt2[b], GCAP);
  for (int i = tid; i < cnt; i += 256) nl[i] = glist[b * GCAP + i];
  __syncthreads();
  int sub = tid >> 6, lane = tid & 63;
  float a0 = 0.f, a1 = 0.f, a2 = 0.f, a3 = 0.f;
  for (int i = sub; i < cnt; i += 4) {
    ushort4 v = *(const ushort4*)(embp + (size_t)nl[i] * HF + lane * 4);
    a0 += b2f(v.x); a1 += b2f(v.y); a2 += b2f(v.z); a3 += b2f(v.w);
  }
  sm[sub][lane][0] = a0; sm[sub][lane][1] = a1;
  sm[sub][lane][2] = a2; sm[sub][lane][3] = a3;
  __syncthreads();
  int fl = tid >> 2, j = tid & 3;
  float s = sm[0][fl][j] + sm[1][fl][j] + sm[2][fl][j] + sm[3][fl][j];
  pool[((size_t)(p0 + pl) * BG + b) * HF + tid] = s;
}

// ---------------------------------------------------------------------------
// final: counts from gcnt2, beta softmax, fuse, logits + pooled out
// ---------------------------------------------------------------------------
__global__ __launch_bounds__(256) void final_kernel(
    const float* __restrict__ pool, const float* __restrict__ wsum,
    const int* __restrict__ gcnt2, const float* __restrict__ clsW,
    const float* __restrict__ clsb, float* __restrict__ out, int N) {
  int b = blockIdx.x;
  int f = threadIdx.x;
  float c = fmaxf((float)gcnt2[b], 1.f);
  float wm[PM];
  float mx = -1e30f;
  #pragma unroll
  for (int p = 0; p < PM; p++) { wm[p] = wsum[p] / (float)N; mx = fmaxf(mx, wm[p]); }
  float es = 0.f, e[PM];
  #pragma unroll
  for (int p = 0; p < PM; p++) { e[p] = expf(wm[p] - mx); es += e[p]; }
  float v = 0.f;
  #pragma unroll
  for (int p = 0; p < PM; p++)
    v += (e[p] / es) * pool[((size_t)p * BG + b) * HF + f];
  v /= c;
  out[256 + (size_t)b * HF + f] = v;
  __shared__ float sm[256];
  sm[f] = v * clsW[f * 2 + 0];
  __syncthreads();
  for (int st = 128; st > 0; st >>= 1) {
    if (f < st) sm[f] += sm[f + st];
    __syncthreads();
  }
  float l0 = sm[0];
  __syncthreads();
  sm[f] = v * clsW[f * 2 + 1];
  __syncthreads();
  for (int st = 128; st > 0; st >>= 1) {
    if (f < st) sm[f] += sm[f + st];
    __syncthreads();
  }
  if (f == 0) {
    out[b * 2 + 0] = l0 + clsb[0];
    out[b * 2 + 1] = sm[0] + clsb[1];
  }
}

// ---------------------------------------------------------------------------
extern "C" void kernel_launch(void* const* d_in, const int* in_sizes, int n_in,
                              void* d_out, int out_size, void* d_ws, size_t ws_size,
                              hipStream_t stream) {
  const float* h      = (const float*)d_in[0];
  const float* Wg     = (const float*)d_in[1];
  const float* attn_l = (const float*)d_in[2];
  const float* attn_r = (const float*)d_in[3];
  const float* gatb   = (const float*)d_in[4];
  const float* semW1  = (const float*)d_in[5];
  const float* semb1  = (const float*)d_in[6];
  const float* semW2  = (const float*)d_in[7];
  const float* clsW   = (const float*)d_in[8];
  const float* clsb   = (const float*)d_in[9];
  const int*   src    = (const int*)d_in[10];
  const int*   dst    = (const int*)d_in[11];
  const int*   gid    = (const int*)d_in[12];
  float* out = (float*)d_out;

  auto layout_size = [](int PMg) -> size_t {
    size_t o = 0;
    auto alloc = [&](size_t bytes) { o += (bytes + 255) & ~(size_t)255; };
    alloc((size_t)NN * INF_ * 2);              // h_b
    alloc((size_t)PMg * NN * HF * 2);          // hp_b
    alloc((size_t)PMg * NN * HF * 2);          // emb_b
    alloc((size_t)PM * HF * INF_ * 2);         // Wb_t
    alloc((size_t)HS * HF * 2);                // W1_t
    alloc((size_t)PM * INF_ * NH * 4);         // wl
    alloc((size_t)PM * INF_ * NH * 4);         // wr
    alloc((size_t)PMg * NN * NH * 4);          // el
    alloc((size_t)PMg * NN * NH * 4);          // er
    alloc((size_t)PM * NB2 * BCAP * 4);        // bdata
    alloc((size_t)PM * NB2 * 4);               // gcnt
    alloc((size_t)BG * GCAP * 4);              // glist
    alloc((size_t)BG * 4);                     // gcnt2
    alloc((size_t)PM * (NN + 1) * 4);          // off
    alloc((size_t)PM * EE * 2);                // csr
    alloc((size_t)PM * BG * HF * 4);           // pool
    alloc(PM * 4);                             // wsum
    return o;
  };
  int PMg = (layout_size(4) <= ws_size) ? 4 : 1;

  char* ws = (char*)d_ws;
  size_t o = 0;
  auto alloc = [&](size_t bytes) { size_t r = o; o += (bytes + 255) & ~(size_t)255; return r; };
  unsigned short* h_b   = (unsigned short*)(ws + alloc((size_t)NN * INF_ * 2));
  unsigned short* hp_b  = (unsigned short*)(ws + alloc((size_t)PMg * NN * HF * 2));
  unsigned short* emb_b = (unsigned short*)(ws + alloc((size_t)PMg * NN * HF * 2));
  unsigned short* Wb_t  = (unsigned short*)(ws + alloc((size_t)PM * HF * INF_ * 2));
  unsigned short* W1_t  = (unsigned short*)(ws + alloc((size_t)HS * HF * 2));
  float* wl    = (float*)(ws + alloc((size_t)PM * INF_ * NH * 4));
  float* wr    = (float*)(ws + alloc((size_t)PM * INF_ * NH * 4));
  float* el    = (float*)(ws + alloc((size_t)PMg * NN * NH * 4));
  float* er    = (float*)(ws + alloc((size_t)PMg * NN * NH * 4));
  unsigned* bdata = (unsigned*)(ws + alloc((size_t)PM * NB2 * BCAP * 4));
  int*   gcnt  = (int*)(ws + alloc((size_t)PM * NB2 * 4));
  int*   glist = (int*)(ws + alloc((size_t)BG * GCAP * 4));
  int*   gcnt2 = (int*)(ws + alloc((size_t)BG * 4));
  int*   off   = (int*)(ws + alloc((size_t)PM * (NN + 1) * 4));
  unsigned short* csr = (unsigned short*)(ws + alloc((size_t)PM * EE * 2));
  float* pool  = (float*)(ws + alloc((size_t)PM * BG * HF * 4));
  float* wsum  = (float*)(ws + alloc(PM * 4));

  const size_t hpS  = (PMg == 4) ? (size_t)NN * HF : 0;
  const size_t embS = hpS;
  const size_t elS  = (PMg == 4) ? (size_t)NN * NH : 0;

  prep_kernel<<<1 + 6250 + 512 + 128 + 16, 256, 0, stream>>>(
      h, Wg, semW1, attn_l, attn_r, h_b, Wb_t, W1_t, wl, wr, gcnt, gcnt2, wsum);
  bucket_kernel<<<dim3((EE + BCH - 1) / BCH, PM), 256, 0, stream>>>(src, dst, bdata, gcnt);
  gbucket_kernel<<<(NN + BCH - 1) / BCH, 256, 0, stream>>>(gid, glist, gcnt2);
  csrify_kernel<<<dim3(NB2, PM), 256, 0, stream>>>(bdata, gcnt, off, csr);

  if (PMg == 4) {
    gemm1_kernel<<<dim3((NN + 63) / 64, 2, 4), 256, 0, stream>>>(h_b, Wb_t, hp_b, NN, 0, hpS);
    elr_kernel<<<dim3((NN + 255) / 256, 4), 256, 0, stream>>>(h_b, wl, wr, el, er, NN, 0, elS);
    agg_kernel<<<dim3((NN + 3) / 4, 4), 256, 0, stream>>>(
        hp_b, el, er, csr, off, gatb, emb_b, NN, 0, hpS, elS, embS);
    gemm2_kernel<<<dim3((NN + 63) / 64, 4), 256, 0, stream>>>(
        emb_b, W1_t, semb1, semW2, wsum, NN, 0, embS);
    pool_kernel<<<dim3(BG, 4), 256, 0, stream>>>(emb_b, glist, gcnt2, pool, 0, embS);
  } else {
    for (int p = 0; p < PM; p++) {
      gemm1_kernel<<<dim3((NN + 63) / 64, 2, 1), 256, 0, stream>>>(h_b, Wb_t, hp_b, NN, p, 0);
      elr_kernel<<<dim3((NN + 255) / 256, 1), 256, 0, stream>>>(h_b, wl, wr, el, er, NN, p, 0);
      agg_kernel<<<dim3((NN + 3) / 4, 1), 256, 0, stream>>>(
          hp_b, el, er, csr, off, gatb, emb_b, NN, p, 0, 0, 0);
      gemm2_kernel<<<dim3((NN + 63) / 64, 1), 256, 0, stream>>>(
          emb_b, W1_t, semb1, semW2, wsum, NN, p, 0);
      pool_kernel<<<dim3(BG, 1), 256, 0, stream>>>(emb_b, glist, gcnt2, pool, p, 0);
    }
  }

  final_kernel<<<BG, 256, 0, stream>>>(pool, wsum, gcnt2, clsW, clsb, out, NN);
}

// Round 9
// 589.501 us; speedup vs baseline: 1.5678x; 1.1248x over previous
//
#include <hip/hip_runtime.h>

#define NN 50000
#define PM 4
#define EE 500000
#define INF_ 128
#define NH 8
#define FF 32
#define HF 256
#define HS 128
#define BG 128
#define OUTC 2

#define NB2 98        // buckets per path: dst>>9 (512 nodes/bucket)
#define BCAP 6144     // bucket capacity (mean 5102, sd ~71 -> 14 sigma slack)
#define BCH 4096      // edges per workgroup in bucket pass
#define GCAP 576      // nodes per graph capacity (mean 390, sd ~20 -> 9 sigma)

typedef __attribute__((ext_vector_type(8))) short bf16x8;
typedef __attribute__((ext_vector_type(4))) float f32x4;

__device__ __forceinline__ float b2f(unsigned short x) {
  unsigned u = ((unsigned)x) << 16;
  return __builtin_bit_cast(float, u);
}
__device__ __forceinline__ unsigned short f2b(float f) {
  unsigned u = __builtin_bit_cast(unsigned, f);
  u += 0x7fff + ((u >> 16) & 1);   // RNE
  return (unsigned short)(u >> 16);
}
__device__ __forceinline__ float fexp(float x) { return __expf(x); }
// overflow-safe fast tanh: t = e^{-2|x|} in (0,1]
__device__ __forceinline__ float ftanh(float x) {
  float t = __expf(-2.f * fabsf(x));
  float r = (1.f - t) / (1.f + t);
  return copysignf(r, x);
}

// ---------------------------------------------------------------------------
// prep: zero gcnt/gcnt2/wsum + h->bf16 + Wg transpose + W1 transpose + fold
// ---------------------------------------------------------------------------
__global__ __launch_bounds__(256) void prep_kernel(
    const float* __restrict__ h, const float* __restrict__ Wg,
    const float* __restrict__ W1, const float* __restrict__ al,
    const float* __restrict__ ar,
    unsigned short* __restrict__ h_b, unsigned short* __restrict__ Wb_t,
    unsigned short* __restrict__ W1_t, float* __restrict__ wl,
    float* __restrict__ wr, int* __restrict__ gcnt, int* __restrict__ gcnt2,
    float* __restrict__ wsum) {
  int b = blockIdx.x;
  int tid = threadIdx.x;
  if (b < 1) {                 // zero gcnt + gcnt2 + wsum
    for (int i = tid; i < PM * NB2; i += 256) gcnt[i] = 0;
    if (tid < BG) gcnt2[tid] = 0;
    if (tid < PM) wsum[tid] = 0.f;
    return;
  }
  b -= 1;
  if (b < 6250) {              // h -> bf16 (float4 granular)
    int t = b * 256 + tid;
    float4 v = *(const float4*)(h + (size_t)t * 4);
    ushort4 o;
    o.x = f2b(v.x); o.y = f2b(v.y); o.z = f2b(v.z); o.w = f2b(v.w);
    *(ushort4*)(h_b + (size_t)t * 4) = o;
    return;
  }
  b -= 6250;
  if (b < 512) {               // Wg [P][128k][256n] -> [P][256n][128k] bf16
    int t = b * 256 + tid;
    int p = t >> 15, rem = t & 32767;
    int n = rem >> 7, k = rem & 127;
    Wb_t[(size_t)p * 32768 + n * 128 + k] = f2b(Wg[(size_t)p * 32768 + k * 256 + n]);
    return;
  }
  b -= 512;
  if (b < 128) {               // W1 [256k][128n] -> [128n][256k] bf16
    int t = b * 256 + tid;
    int n = t >> 8, k = t & 255;
    W1_t[n * 256 + k] = f2b(W1[k * 128 + n]);
    return;
  }
  b -= 128;
  {                            // fold: wl/wr[p][k][h]
    int t = b * 256 + tid;
    int p = t >> 10, rem = t & 1023;
    int k = rem >> 3, hh = rem & 7;
    const float* wrow = Wg + (size_t)p * 32768 + k * 256 + hh * 32;
    const float* alp = al + p * 256 + hh * 32;
    const float* arp = ar + p * 256 + hh * 32;
    float sl = 0.f, sr = 0.f;
    #pragma unroll
    for (int f = 0; f < 32; f++) { sl += wrow[f] * alp[f]; sr += wrow[f] * arp[f]; }
    wl[t] = sl; wr[t] = sr;
  }
}

// ---------------------------------------------------------------------------
// bucket: per-block histogram -> global segment reserve -> LDS-cursor scatter
// ---------------------------------------------------------------------------
__global__ __launch_bounds__(256) void bucket_kernel(
    const int* __restrict__ src, const int* __restrict__ dst,
    unsigned* __restrict__ bdata, int* __restrict__ gcnt) {
  __shared__ unsigned ed[BCH];
  __shared__ int hist[NB2], gbase[NB2], cur[NB2];
  int p = blockIdx.y;
  int e0 = blockIdx.x * BCH;
  int n = min(BCH, EE - e0);
  int tid = threadIdx.x;
  if (tid < NB2) hist[tid] = 0;
  __syncthreads();
  const int* sp = src + (size_t)p * EE + e0;
  const int* dp = dst + (size_t)p * EE + e0;
  for (int i = tid; i < n; i += 256) {
    int s = sp[i], d = dp[i];
    ed[i] = ((unsigned)d << 16) | (unsigned)s;
    atomicAdd(&hist[d >> 9], 1);
  }
  __syncthreads();
  if (tid < NB2) {
    gbase[tid] = atomicAdd(&gcnt[p * NB2 + tid], hist[tid]);
    cur[tid] = 0;
  }
  __syncthreads();
  for (int i = tid; i < n; i += 256) {
    unsigned pk = ed[i];
    int bk = pk >> 25;           // (dst>>9)
    int slot = gbase[bk] + atomicAdd(&cur[bk], 1);
    if (slot < BCAP)
      bdata[((size_t)(p * NB2 + bk)) * BCAP + slot] = pk;
  }
}

// ---------------------------------------------------------------------------
// gbucket: bin node ids by graph id -> glist[BG][GCAP] + per-graph counts
// ---------------------------------------------------------------------------
__global__ __launch_bounds__(256) void gbucket_kernel(
    const int* __restrict__ gid, int* __restrict__ glist, int* __restrict__ gcnt2) {
  __shared__ int gl[BCH];
  __shared__ int hist[BG], gbase[BG], cur[BG];
  int e0 = blockIdx.x * BCH;
  int n = min(BCH, NN - e0);
  int tid = threadIdx.x;
  if (tid < BG) hist[tid] = 0;
  __syncthreads();
  for (int i = tid; i < n; i += 256) {
    int g = gid[e0 + i];
    gl[i] = g;
    atomicAdd(&hist[g], 1);
  }
  __syncthreads();
  if (tid < BG) {
    gbase[tid] = atomicAdd(&gcnt2[tid], hist[tid]);
    cur[tid] = 0;
  }
  __syncthreads();
  for (int i = tid; i < n; i += 256) {
    int g = gl[i];
    int slot = gbase[g] + atomicAdd(&cur[g], 1);
    if (slot < GCAP) glist[g * GCAP + slot] = e0 + i;
  }
}

// ---------------------------------------------------------------------------
// csrify: per (bucket,path): 512-node local CSR in LDS -> global off/csr
// ---------------------------------------------------------------------------
__global__ __launch_bounds__(256) void csrify_kernel(
    const unsigned* __restrict__ bdata, const int* __restrict__ gcnt,
    int* __restrict__ off, unsigned short* __restrict__ csr) {
  __shared__ unsigned ebuf[BCAP];
  __shared__ int gc[NB2];
  __shared__ int degc[512];
  __shared__ int loff[513];
  __shared__ int tmp[256];
  __shared__ int base_s;
  int b = blockIdx.x, p = blockIdx.y;
  int tid = threadIdx.x;
  if (tid < NB2) gc[tid] = min(gcnt[p * NB2 + tid], BCAP);
  __syncthreads();
  if (tid == 0) {
    int s = 0;
    for (int i = 0; i < b; i++) s += gc[i];
    base_s = s;
  }
  int cnt = gc[b];
  const unsigned* bp = bdata + ((size_t)(p * NB2 + b)) * BCAP;
  for (int i = tid; i < cnt; i += 256) ebuf[i] = bp[i];
  degc[tid] = 0; degc[256 + tid] = 0;
  __syncthreads();
  for (int i = tid; i < cnt; i += 256)
    atomicAdd(&degc[(ebuf[i] >> 16) & 511], 1);
  __syncthreads();
  int d0 = degc[2 * tid], d1 = degc[2 * tid + 1];
  tmp[tid] = d0 + d1;
  __syncthreads();
  for (int o = 1; o < 256; o <<= 1) {
    int v = (tid >= o) ? tmp[tid - o] : 0;
    __syncthreads();
    tmp[tid] += v;
    __syncthreads();
  }
  int bse = tmp[tid] - d0 - d1;
  loff[2 * tid] = bse; loff[2 * tid + 1] = bse + d0;
  if (tid == 255) loff[512] = tmp[255];
  __syncthreads();
  int base = base_s;
  for (int dl = tid; dl < 512; dl += 256) {
    int n = b * 512 + dl;
    if (n <= NN) off[(size_t)p * (NN + 1) + n] = base + loff[dl];
  }
  degc[tid] = 0; degc[256 + tid] = 0;   // reuse as cursors
  __syncthreads();
  for (int i = tid; i < cnt; i += 256) {
    unsigned pk = ebuf[i];
    int dl = (pk >> 16) & 511;
    int slot = loff[dl] + atomicAdd(&degc[dl], 1);
    csr[(size_t)p * EE + base + slot] = (unsigned short)(pk & 0xffff);
  }
}

// ---------------------------------------------------------------------------
// GEMM1: hp_b[p][M,256] = h_b[M,128] @ W[p], MFMA bf16. p = p0 + blockIdx.z.
// ---------------------------------------------------------------------------
__global__ __launch_bounds__(256) void gemm1_kernel(
    const unsigned short* __restrict__ hA, const unsigned short* __restrict__ Bt,
    unsigned short* __restrict__ Cb, int M, int p0, size_t cstride) {
  __shared__ unsigned short As[64 * 128];
  __shared__ unsigned short Bs[128 * 128];
  int tid = threadIdx.x;
  int pl = blockIdx.z;
  const unsigned short* Bp = Bt + (size_t)(p0 + pl) * 32768;
  unsigned short* Cp = Cb + (size_t)pl * cstride;
  int row0 = blockIdx.x * 64, col0 = blockIdx.y * 128;
  #pragma unroll
  for (int i = 0; i < 4; i++) {
    int c = i * 256 + tid;
    int row = c >> 4, g = c & 15;
    int grow = row0 + row;
    uint4 v = make_uint4(0, 0, 0, 0);
    if (grow < M) v = *(const uint4*)(hA + (size_t)grow * 128 + g * 8);
    *(uint4*)&As[row * 128 + ((g ^ (row & 15)) << 3)] = v;
  }
  #pragma unroll
  for (int i = 0; i < 8; i++) {
    int c = i * 256 + tid;
    int row = c >> 4, g = c & 15;
    uint4 v = *(const uint4*)(Bp + (size_t)(col0 + row) * 128 + g * 8);
    *(uint4*)&Bs[row * 128 + ((g ^ (row & 15)) << 3)] = v;
  }
  __syncthreads();
  int wave = tid >> 6, lane = tid & 63;
  int ln = lane & 15, quad = lane >> 4;
  int mbase = (wave >> 1) * 32, nbase = (wave & 1) * 64;
  f32x4 acc[2][4] = {};
  #pragma unroll
  for (int ks = 0; ks < 4; ks++) {
    int g = ks * 4 + quad;
    bf16x8 a[2], bb[4];
    #pragma unroll
    for (int mi = 0; mi < 2; mi++) {
      int r = mbase + mi * 16 + ln;
      a[mi] = *(const bf16x8*)&As[r * 128 + ((g ^ ln) << 3)];
    }
    #pragma unroll
    for (int ni = 0; ni < 4; ni++) {
      int r = nbase + ni * 16 + ln;
      bb[ni] = *(const bf16x8*)&Bs[r * 128 + ((g ^ ln) << 3)];
    }
    #pragma unroll
    for (int mi = 0; mi < 2; mi++)
      #pragma unroll
      for (int ni = 0; ni < 4; ni++)
        acc[mi][ni] = __builtin_amdgcn_mfma_f32_16x16x32_bf16(a[mi], bb[ni], acc[mi][ni], 0, 0, 0);
  }
  #pragma unroll
  for (int mi = 0; mi < 2; mi++) {
    int gm0 = row0 + mbase + mi * 16 + quad * 4;
    #pragma unroll
    for (int ni = 0; ni < 4; ni++) {
      int gn = col0 + nbase + ni * 16 + ln;
      #pragma unroll
      for (int r = 0; r < 4; r++) {
        int gm = gm0 + r;
        if (gm < M) Cp[(size_t)gm * 256 + gn] = f2b(acc[mi][ni][r]);
      }
    }
  }
}

// ---------------------------------------------------------------------------
// elr: el/er = h_b (bf16) @ folded fp32 weights. p = p0 + blockIdx.y.
// ---------------------------------------------------------------------------
__global__ __launch_bounds__(256) void elr_kernel(
    const unsigned short* __restrict__ h_b, const float* __restrict__ wl,
    const float* __restrict__ wr, float* __restrict__ el,
    float* __restrict__ er, int N, int p0, size_t estride) {
  __shared__ float wls[128 * 8], wrs[128 * 8];
  int pl = blockIdx.y;
  const float* wlp = wl + (size_t)(p0 + pl) * 1024;
  const float* wrp = wr + (size_t)(p0 + pl) * 1024;
  float* elp = el + (size_t)pl * estride;
  float* erp = er + (size_t)pl * estride;
  for (int i = threadIdx.x; i < 1024; i += 256) { wls[i] = wlp[i]; wrs[i] = wrp[i]; }
  __syncthreads();
  int n = blockIdx.x * 256 + threadIdx.x;
  if (n >= N) return;
  float accl[8] = {}, accr[8] = {};
  for (int kk = 0; kk < 16; kk++) {          // 8 bf16 per step
    uint4 raw = *(const uint4*)(h_b + (size_t)n * 128 + kk * 8);
    unsigned uu[4] = {raw.x, raw.y, raw.z, raw.w};
    #pragma unroll
    for (int q = 0; q < 4; q++) {
      float v0 = __builtin_bit_cast(float, uu[q] << 16);
      float v1 = __builtin_bit_cast(float, uu[q] & 0xffff0000u);
      int k = kk * 8 + q * 2;
      #pragma unroll
      for (int hh = 0; hh < 8; hh++) {
        accl[hh] += v0 * wls[k * 8 + hh] + v1 * wls[(k + 1) * 8 + hh];
        accr[hh] += v0 * wrs[k * 8 + hh] + v1 * wrs[(k + 1) * 8 + hh];
      }
    }
  }
  *(float4*)(elp + (size_t)n * 8)     = make_float4(accl[0], accl[1], accl[2], accl[3]);
  *(float4*)(elp + (size_t)n * 8 + 4) = make_float4(accl[4], accl[5], accl[6], accl[7]);
  *(float4*)(erp + (size_t)n * 8)     = make_float4(accr[0], accr[1], accr[2], accr[3]);
  *(float4*)(erp + (size_t)n * 8 + 4) = make_float4(accr[4], accr[5], accr[6], accr[7]);
}

// ---------------------------------------------------------------------------
// agg: one wave per dst node, edge loop UNROLLED x4 for memory-level
// parallelism (csr contiguous; el/hp random). out=(sum w*hp)/(sum w)+bias,ELU.
// ---------------------------------------------------------------------------
__global__ __launch_bounds__(256) void agg_kernel(
    const unsigned short* __restrict__ hp_b, const float* __restrict__ el,
    const float* __restrict__ er, const unsigned short* __restrict__ csr,
    const int* __restrict__ off, const float* __restrict__ bias,
    unsigned short* __restrict__ emb_b, int N, int p0,
    size_t hstride, size_t estride, size_t embstride) {
  int pl = blockIdx.y;
  int p = p0 + pl;
  const unsigned short* hp = hp_b + (size_t)pl * hstride;
  const float* elp = el + (size_t)pl * estride;
  const float* erp = er + (size_t)pl * estride;
  const unsigned short* csrp = csr + (size_t)p * EE;
  const int* offp = off + (size_t)p * (NN + 1);
  const float* bp = bias + (size_t)p * HF;
  unsigned short* embp = emb_b + (size_t)pl * embstride;
  int n = blockIdx.x * 4 + (threadIdx.x >> 6);
  if (n >= N) return;
  int lane = threadIdx.x & 63;
  int h = lane >> 3;
  int e0 = offp[n], e1 = offp[n + 1];
  float erh = erp[n * NH + h];
  float den = 0.f, a0 = 0.f, a1 = 0.f, a2 = 0.f, a3 = 0.f;
  int e = e0;
  for (; e + 4 <= e1; e += 4) {
    int s0 = csrp[e], s1 = csrp[e + 1], s2 = csrp[e + 2], s3 = csrp[e + 3];
    float x0 = elp[s0 * NH + h] + erh;
    float x1 = elp[s1 * NH + h] + erh;
    float x2 = elp[s2 * NH + h] + erh;
    float x3 = elp[s3 * NH + h] + erh;
    ushort4 h0 = *(const ushort4*)(hp + (size_t)s0 * HF + lane * 4);
    ushort4 h1 = *(const ushort4*)(hp + (size_t)s1 * HF + lane * 4);
    ushort4 h2 = *(const ushort4*)(hp + (size_t)s2 * HF + lane * 4);
    ushort4 h3 = *(const ushort4*)(hp + (size_t)s3 * HF + lane * 4);
    x0 = (x0 > 0.f) ? x0 : 0.2f * x0;
    x1 = (x1 > 0.f) ? x1 : 0.2f * x1;
    x2 = (x2 > 0.f) ? x2 : 0.2f * x2;
    x3 = (x3 > 0.f) ? x3 : 0.2f * x3;
    float w0 = fexp(x0), w1 = fexp(x1), w2 = fexp(x2), w3 = fexp(x3);
    den += (w0 + w1) + (w2 + w3);
    a0 += (w0 * b2f(h0.x) + w1 * b2f(h1.x)) + (w2 * b2f(h2.x) + w3 * b2f(h3.x));
    a1 += (w0 * b2f(h0.y) + w1 * b2f(h1.y)) + (w2 * b2f(h2.y) + w3 * b2f(h3.y));
    a2 += (w0 * b2f(h0.z) + w1 * b2f(h1.z)) + (w2 * b2f(h2.z) + w3 * b2f(h3.z));
    a3 += (w0 * b2f(h0.w) + w1 * b2f(h1.w)) + (w2 * b2f(h2.w) + w3 * b2f(h3.w));
  }
  for (; e < e1; e++) {
    int s = csrp[e];
    float x = elp[s * NH + h] + erh;
    x = (x > 0.f) ? x : 0.2f * x;
    float w = fexp(x);
    den += w;
    ushort4 hv = *(const ushort4*)(hp + (size_t)s * HF + lane * 4);
    a0 += w * b2f(hv.x); a1 += w * b2f(hv.y);
    a2 += w * b2f(hv.z); a3 += w * b2f(hv.w);
  }
  float inv = (den > 0.f) ? 1.f / den : 0.f;
  float4 bv = *(const float4*)(bp + lane * 4);
  float o0 = a0 * inv + bv.x, o1 = a1 * inv + bv.y;
  float o2 = a2 * inv + bv.z, o3 = a3 * inv + bv.w;
  o0 = (o0 > 0.f) ? o0 : fexp(o0) - 1.f;
  o1 = (o1 > 0.f) ? o1 : fexp(o1) - 1.f;
  o2 = (o2 > 0.f) ? o2 : fexp(o2) - 1.f;
  o3 = (o3 > 0.f) ? o3 : fexp(o3) - 1.f;
  ushort4 ov;
  ov.x = f2b(o0); ov.y = f2b(o1); ov.z = f2b(o2); ov.w = f2b(o3);
  *(ushort4*)(embp + (size_t)n * HF + lane * 4) = ov;
}

// ---------------------------------------------------------------------------
// GEMM2 + semantic epilogue: wsum[p] += sum tanh(emb@W1+b1).W2
// ---------------------------------------------------------------------------
__global__ __launch_bounds__(256) void gemm2_kernel(
    const unsigned short* __restrict__ A, const unsigned short* __restrict__ Bt,
    const float* __restrict__ b1, const float* __restrict__ W2,
    float* __restrict__ wsum, int M, int p0, size_t astride) {
  __shared__ unsigned short As[64 * 128];
  __shared__ unsigned short Bs[128 * 128];
  int tid = threadIdx.x;
  int pl = blockIdx.y;
  const unsigned short* Ap = A + (size_t)pl * astride;
  int row0 = blockIdx.x * 64;
  int wave = tid >> 6, lane = tid & 63;
  int ln = lane & 15, quad = lane >> 4;
  int mbase = (wave >> 1) * 32, nbase = (wave & 1) * 64;
  f32x4 acc[2][4] = {};
  for (int kc = 0; kc < 2; kc++) {
    #pragma unroll
    for (int i = 0; i < 4; i++) {
      int c = i * 256 + tid;
      int row = c >> 4, g = c & 15;
      int grow = row0 + row;
      uint4 v = make_uint4(0, 0, 0, 0);
      if (grow < M) v = *(const uint4*)(Ap + (size_t)grow * 256 + kc * 128 + g * 8);
      *(uint4*)&As[row * 128 + ((g ^ (row & 15)) << 3)] = v;
    }
    #pragma unroll
    for (int i = 0; i < 8; i++) {
      int c = i * 256 + tid;
      int row = c >> 4, g = c & 15;
      uint4 v = *(const uint4*)(Bt + (size_t)row * 256 + kc * 128 + g * 8);
      *(uint4*)&Bs[row * 128 + ((g ^ (row & 15)) << 3)] = v;
    }
    __syncthreads();
    #pragma unroll
    for (int ks = 0; ks < 4; ks++) {
      int g = ks * 4 + quad;
      bf16x8 a[2], bb[4];
      #pragma unroll
      for (int mi = 0; mi < 2; mi++) {
        int r = mbase + mi * 16 + ln;
        a[mi] = *(const bf16x8*)&As[r * 128 + ((g ^ ln) << 3)];
      }
      #pragma unroll
      for (int ni = 0; ni < 4; ni++) {
        int r = nbase + ni * 16 + ln;
        bb[ni] = *(const bf16x8*)&Bs[r * 128 + ((g ^ ln) << 3)];
      }
      #pragma unroll
      for (int mi = 0; mi < 2; mi++)
        #pragma unroll
        for (int ni = 0; ni < 4; ni++)
          acc[mi][ni] = __builtin_amdgcn_mfma_f32_16x16x32_bf16(a[mi], bb[ni], acc[mi][ni], 0, 0, 0);
    }
    __syncthreads();
  }
  float b1v[4], w2v[4];
  #pragma unroll
  for (int ni = 0; ni < 4; ni++) {
    int col = nbase + ni * 16 + ln;
    b1v[ni] = b1[col]; w2v[ni] = W2[col];
  }
  float s = 0.f;
  #pragma unroll
  for (int mi = 0; mi < 2; mi++) {
    int gm0 = row0 + mbase + mi * 16 + quad * 4;
    #pragma unroll
    for (int r = 0; r < 4; r++) {
      if (gm0 + r < M) {
        #pragma unroll
        for (int ni = 0; ni < 4; ni++)
          s += ftanh(acc[mi][ni][r] + b1v[ni]) * w2v[ni];
      }
    }
  }
  #pragma unroll
  for (int o = 32; o > 0; o >>= 1) s += __shfl_down(s, o);
  if (lane == 0) atomicAdd(&wsum[p0 + pl], s);
}

// ---------------------------------------------------------------------------
// pool: one block per (graph, path); register accumulation, no atomics.
// ---------------------------------------------------------------------------
__global__ __launch_bounds__(256) void pool_kernel(
    const unsigned short* __restrict__ emb, const int* __restrict__ glist,
    const int* __restrict__ gcnt2, float* __restrict__ pool,
    int p0, size_t embstride) {
  __shared__ int nl[GCAP];
  __shared__ float sm[4][64][4];
  int b = blockIdx.x, pl = blockIdx.y;
  const unsigned short* embp = emb + (size_t)pl * embstride;
  int tid = threadIdx.x;
  int cnt = min(gcnt2[b], GCAP);
  for (int i = tid; i < cnt; i += 256) nl[i] = glist[b * GCAP + i];
  __syncthreads();
  int sub = tid >> 6, lane = tid & 63;
  float a0 = 0.f, a1 = 0.f, a2 = 0.f, a3 = 0.f;
  for (int i = sub; i < cnt; i += 4) {
    ushort4 v = *(const ushort4*)(embp + (size_t)nl[i] * HF + lane * 4);
    a0 += b2f(v.x); a1 += b2f(v.y); a2 += b2f(v.z); a3 += b2f(v.w);
  }
  sm[sub][lane][0] = a0; sm[sub][lane][1] = a1;
  sm[sub][lane][2] = a2; sm[sub][lane][3] = a3;
  __syncthreads();
  int fl = tid >> 2, j = tid & 3;
  float s = sm[0][fl][j] + sm[1][fl][j] + sm[2][fl][j] + sm[3][fl][j];
  pool[((size_t)(p0 + pl) * BG + b) * HF + tid] = s;
}

// ---------------------------------------------------------------------------
// final: counts from gcnt2, beta softmax, fuse, logits + pooled out
// ---------------------------------------------------------------------------
__global__ __launch_bounds__(256) void final_kernel(
    const float* __restrict__ pool, const float* __restrict__ wsum,
    const int* __restrict__ gcnt2, const float* __restrict__ clsW,
    const float* __restrict__ clsb, float* __restrict__ out, int N) {
  int b = blockIdx.x;
  int f = threadIdx.x;
  float c = fmaxf((float)gcnt2[b], 1.f);
  float wm[PM];
  float mx = -1e30f;
  #pragma unroll
  for (int p = 0; p < PM; p++) { wm[p] = wsum[p] / (float)N; mx = fmaxf(mx, wm[p]); }
  float es = 0.f, e[PM];
  #pragma unroll
  for (int p = 0; p < PM; p++) { e[p] = expf(wm[p] - mx); es += e[p]; }
  float v = 0.f;
  #pragma unroll
  for (int p = 0; p < PM; p++)
    v += (e[p] / es) * pool[((size_t)p * BG + b) * HF + f];
  v /= c;
  out[256 + (size_t)b * HF + f] = v;
  __shared__ float sm[256];
  sm[f] = v * clsW[f * 2 + 0];
  __syncthreads();
  for (int st = 128; st > 0; st >>= 1) {
    if (f < st) sm[f] += sm[f + st];
    __syncthreads();
  }
  float l0 = sm[0];
  __syncthreads();
  sm[f] = v * clsW[f * 2 + 1];
  __syncthreads();
  for (int st = 128; st > 0; st >>= 1) {
    if (f < st) sm[f] += sm[f + st];
    __syncthreads();
  }
  if (f == 0) {
    out[b * 2 + 0] = l0 + clsb[0];
    out[b * 2 + 1] = sm[0] + clsb[1];
  }
}

// ---------------------------------------------------------------------------
extern "C" void kernel_launch(void* const* d_in, const int* in_sizes, int n_in,
                              void* d_out, int out_size, void* d_ws, size_t ws_size,
                              hipStream_t stream) {
  const float* h      = (const float*)d_in[0];
  const float* Wg     = (const float*)d_in[1];
  const float* attn_l = (const float*)d_in[2];
  const float* attn_r = (const float*)d_in[3];
  const float* gatb   = (const float*)d_in[4];
  const float* semW1  = (const float*)d_in[5];
  const float* semb1  = (const float*)d_in[6];
  const float* semW2  = (const float*)d_in[7];
  const float* clsW   = (const float*)d_in[8];
  const float* clsb   = (const float*)d_in[9];
  const int*   src    = (const int*)d_in[10];
  const int*   dst    = (const int*)d_in[11];
  const int*   gid    = (const int*)d_in[12];
  float* out = (float*)d_out;

  auto layout_size = [](int PMg) -> size_t {
    size_t o = 0;
    auto alloc = [&](size_t bytes) { o += (bytes + 255) & ~(size_t)255; };
    alloc((size_t)NN * INF_ * 2);              // h_b
    alloc((size_t)PMg * NN * HF * 2);          // hp_b
    alloc((size_t)PMg * NN * HF * 2);          // emb_b
    alloc((size_t)PM * HF * INF_ * 2);         // Wb_t
    alloc((size_t)HS * HF * 2);                // W1_t
    alloc((size_t)PM * INF_ * NH * 4);         // wl
    alloc((size_t)PM * INF_ * NH * 4);         // wr
    alloc((size_t)PMg * NN * NH * 4);          // el
    alloc((size_t)PMg * NN * NH * 4);          // er
    alloc((size_t)PM * NB2 * BCAP * 4);        // bdata
    alloc((size_t)PM * NB2 * 4);               // gcnt
    alloc((size_t)BG * GCAP * 4);              // glist
    alloc((size_t)BG * 4);                     // gcnt2
    alloc((size_t)PM * (NN + 1) * 4);          // off
    alloc((size_t)PM * EE * 2);                // csr
    alloc((size_t)PM * BG * HF * 4);           // pool
    alloc(PM * 4);                             // wsum
    return o;
  };
  int PMg = (layout_size(4) <= ws_size) ? 4 : 1;

  char* ws = (char*)d_ws;
  size_t o = 0;
  auto alloc = [&](size_t bytes) { size_t r = o; o += (bytes + 255) & ~(size_t)255; return r; };
  unsigned short* h_b   = (unsigned short*)(ws + alloc((size_t)NN * INF_ * 2));
  unsigned short* hp_b  = (unsigned short*)(ws + alloc((size_t)PMg * NN * HF * 2));
  unsigned short* emb_b = (unsigned short*)(ws + alloc((size_t)PMg * NN * HF * 2));
  unsigned short* Wb_t  = (unsigned short*)(ws + alloc((size_t)PM * HF * INF_ * 2));
  unsigned short* W1_t  = (unsigned short*)(ws + alloc((size_t)HS * HF * 2));
  float* wl    = (float*)(ws + alloc((size_t)PM * INF_ * NH * 4));
  float* wr    = (float*)(ws + alloc((size_t)PM * INF_ * NH * 4));
  float* el    = (float*)(ws + alloc((size_t)PMg * NN * NH * 4));
  float* er    = (float*)(ws + alloc((size_t)PMg * NN * NH * 4));
  unsigned* bdata = (unsigned*)(ws + alloc((size_t)PM * NB2 * BCAP * 4));
  int*   gcnt  = (int*)(ws + alloc((size_t)PM * NB2 * 4));
  int*   glist = (int*)(ws + alloc((size_t)BG * GCAP * 4));
  int*   gcnt2 = (int*)(ws + alloc((size_t)BG * 4));
  int*   off   = (int*)(ws + alloc((size_t)PM * (NN + 1) * 4));
  unsigned short* csr = (unsigned short*)(ws + alloc((size_t)PM * EE * 2));
  float* pool  = (float*)(ws + alloc((size_t)PM * BG * HF * 4));
  float* wsum  = (float*)(ws + alloc(PM * 4));

  const size_t hpS  = (PMg == 4) ? (size_t)NN * HF : 0;
  const size_t embS = hpS;
  const size_t elS  = (PMg == 4) ? (size_t)NN * NH : 0;

  prep_kernel<<<1 + 6250 + 512 + 128 + 16, 256, 0, stream>>>(
      h, Wg, semW1, attn_l, attn_r, h_b, Wb_t, W1_t, wl, wr, gcnt, gcnt2, wsum);
  bucket_kernel<<<dim3((EE + BCH - 1) / BCH, PM), 256, 0, stream>>>(src, dst, bdata, gcnt);
  gbucket_kernel<<<(NN + BCH - 1) / BCH, 256, 0, stream>>>(gid, glist, gcnt2);
  csrify_kernel<<<dim3(NB2, PM), 256, 0, stream>>>(bdata, gcnt, off, csr);

  if (PMg == 4) {
    gemm1_kernel<<<dim3((NN + 63) / 64, 2, 4), 256, 0, stream>>>(h_b, Wb_t, hp_b, NN, 0, hpS);
    elr_kernel<<<dim3((NN + 255) / 256, 4), 256, 0, stream>>>(h_b, wl, wr, el, er, NN, 0, elS);
    agg_kernel<<<dim3((NN + 3) / 4, 4), 256, 0, stream>>>(
        hp_b, el, er, csr, off, gatb, emb_b, NN, 0, hpS, elS, embS);
    gemm2_kernel<<<dim3((NN + 63) / 64, 4), 256, 0, stream>>>(
        emb_b, W1_t, semb1, semW2, wsum, NN, 0, embS);
    pool_kernel<<<dim3(BG, 4), 256, 0, stream>>>(emb_b, glist, gcnt2, pool, 0, embS);
  } else {
    for (int p = 0; p < PM; p++) {
      gemm1_kernel<<<dim3((NN + 63) / 64, 2, 1), 256, 0, stream>>>(h_b, Wb_t, hp_b, NN, p, 0);
      elr_kernel<<<dim3((NN + 255) / 256, 1), 256, 0, stream>>>(h_b, wl, wr, el, er, NN, p, 0);
      agg_kernel<<<dim3((NN + 3) / 4, 1), 256, 0, stream>>>(
          hp_b, el, er, csr, off, gatb, emb_b, NN, p, 0, 0, 0);
      gemm2_kernel<<<dim3((NN + 63) / 64, 1), 256, 0, stream>>>(
          emb_b, W1_t, semb1, semW2, wsum, NN, p, 0);
      pool_kernel<<<dim3(BG, 1), 256, 0, stream>>>(emb_b, glist, gcnt2, pool, p, 0);
    }
  }

  final_kernel<<<BG, 256, 0, stream>>>(pool, wsum, gcnt2, clsW, clsb, out, NN);
}

// Round 10
// 458.954 us; speedup vs baseline: 2.0137x; 1.2844x over previous
//
#include <hip/hip_runtime.h>

#define NN 50000
#define PM 4
#define EE 500000
#define INF_ 128
#define NH 8
#define FF 32
#define HF 256
#define HS 128
#define BG 128
#define OUTC 2

#define NB2 98        // buckets per path: dst>>9 (512 nodes/bucket)
#define BCAP 6144     // bucket capacity (mean 5102, sd ~71 -> 14 sigma slack)
#define BCH 4096      // edges per workgroup in bucket pass
#define GCAP 576      // nodes per graph capacity (mean 390, sd ~20 -> 9 sigma)
#define NBG2 782      // gemm2 blocks per path = ceil(NN/64)

typedef __attribute__((ext_vector_type(8))) short bf16x8;
typedef __attribute__((ext_vector_type(4))) float f32x4;

__device__ __forceinline__ float b2f(unsigned short x) {
  unsigned u = ((unsigned)x) << 16;
  return __builtin_bit_cast(float, u);
}
__device__ __forceinline__ unsigned short f2b(float f) {
  unsigned u = __builtin_bit_cast(unsigned, f);
  u += 0x7fff + ((u >> 16) & 1);   // RNE
  return (unsigned short)(u >> 16);
}
__device__ __forceinline__ float fexp(float x) { return __expf(x); }
// overflow-safe fast tanh: t = e^{-2|x|} in (0,1]
__device__ __forceinline__ float ftanh(float x) {
  float t = __expf(-2.f * fabsf(x));
  float r = (1.f - t) / (1.f + t);
  return copysignf(r, x);
}

// ---------------------------------------------------------------------------
// prep: zero gcnt/gcnt2 + h->bf16 + Wg transpose + W1 transpose + fold
// ---------------------------------------------------------------------------
__global__ __launch_bounds__(256) void prep_kernel(
    const float* __restrict__ h, const float* __restrict__ Wg,
    const float* __restrict__ W1, const float* __restrict__ al,
    const float* __restrict__ ar,
    unsigned short* __restrict__ h_b, unsigned short* __restrict__ Wb_t,
    unsigned short* __restrict__ W1_t, float* __restrict__ wl,
    float* __restrict__ wr, int* __restrict__ gcnt, int* __restrict__ gcnt2) {
  int b = blockIdx.x;
  int tid = threadIdx.x;
  if (b < 1) {                 // zero gcnt + gcnt2
    for (int i = tid; i < PM * NB2; i += 256) gcnt[i] = 0;
    if (tid < BG) gcnt2[tid] = 0;
    return;
  }
  b -= 1;
  if (b < 6250) {              // h -> bf16 (float4 granular)
    int t = b * 256 + tid;
    float4 v = *(const float4*)(h + (size_t)t * 4);
    ushort4 o;
    o.x = f2b(v.x); o.y = f2b(v.y); o.z = f2b(v.z); o.w = f2b(v.w);
    *(ushort4*)(h_b + (size_t)t * 4) = o;
    return;
  }
  b -= 6250;
  if (b < 512) {               // Wg [P][128k][256n] -> [P][256n][128k] bf16
    int t = b * 256 + tid;
    int p = t >> 15, rem = t & 32767;
    int n = rem >> 7, k = rem & 127;
    Wb_t[(size_t)p * 32768 + n * 128 + k] = f2b(Wg[(size_t)p * 32768 + k * 256 + n]);
    return;
  }
  b -= 512;
  if (b < 128) {               // W1 [256k][128n] -> [128n][256k] bf16
    int t = b * 256 + tid;
    int n = t >> 8, k = t & 255;
    W1_t[n * 256 + k] = f2b(W1[k * 128 + n]);
    return;
  }
  b -= 128;
  {                            // fold: wl/wr[p][k][h]
    int t = b * 256 + tid;
    int p = t >> 10, rem = t & 1023;
    int k = rem >> 3, hh = rem & 7;
    const float* wrow = Wg + (size_t)p * 32768 + k * 256 + hh * 32;
    const float* alp = al + p * 256 + hh * 32;
    const float* arp = ar + p * 256 + hh * 32;
    float sl = 0.f, sr = 0.f;
    #pragma unroll
    for (int f = 0; f < 32; f++) { sl += wrow[f] * alp[f]; sr += wrow[f] * arp[f]; }
    wl[t] = sl; wr[t] = sr;
  }
}

// ---------------------------------------------------------------------------
// bucket: per-block histogram -> global segment reserve -> LDS-cursor scatter
// ---------------------------------------------------------------------------
__global__ __launch_bounds__(256) void bucket_kernel(
    const int* __restrict__ src, const int* __restrict__ dst,
    unsigned* __restrict__ bdata, int* __restrict__ gcnt) {
  __shared__ unsigned ed[BCH];
  __shared__ int hist[NB2], gbase[NB2], cur[NB2];
  int p = blockIdx.y;
  int e0 = blockIdx.x * BCH;
  int n = min(BCH, EE - e0);
  int tid = threadIdx.x;
  if (tid < NB2) hist[tid] = 0;
  __syncthreads();
  const int* sp = src + (size_t)p * EE + e0;
  const int* dp = dst + (size_t)p * EE + e0;
  for (int i = tid; i < n; i += 256) {
    int s = sp[i], d = dp[i];
    ed[i] = ((unsigned)d << 16) | (unsigned)s;
    atomicAdd(&hist[d >> 9], 1);
  }
  __syncthreads();
  if (tid < NB2) {
    gbase[tid] = atomicAdd(&gcnt[p * NB2 + tid], hist[tid]);
    cur[tid] = 0;
  }
  __syncthreads();
  for (int i = tid; i < n; i += 256) {
    unsigned pk = ed[i];
    int bk = pk >> 25;           // (dst>>9)
    int slot = gbase[bk] + atomicAdd(&cur[bk], 1);
    if (slot < BCAP)
      bdata[((size_t)(p * NB2 + bk)) * BCAP + slot] = pk;
  }
}

// ---------------------------------------------------------------------------
// gbucket: bin node ids by graph id -> glist[BG][GCAP] + per-graph counts
// ---------------------------------------------------------------------------
__global__ __launch_bounds__(256) void gbucket_kernel(
    const int* __restrict__ gid, int* __restrict__ glist, int* __restrict__ gcnt2) {
  __shared__ int gl[BCH];
  __shared__ int hist[BG], gbase[BG], cur[BG];
  int e0 = blockIdx.x * BCH;
  int n = min(BCH, NN - e0);
  int tid = threadIdx.x;
  if (tid < BG) hist[tid] = 0;
  __syncthreads();
  for (int i = tid; i < n; i += 256) {
    int g = gid[e0 + i];
    gl[i] = g;
    atomicAdd(&hist[g], 1);
  }
  __syncthreads();
  if (tid < BG) {
    gbase[tid] = atomicAdd(&gcnt2[tid], hist[tid]);
    cur[tid] = 0;
  }
  __syncthreads();
  for (int i = tid; i < n; i += 256) {
    int g = gl[i];
    int slot = gbase[g] + atomicAdd(&cur[g], 1);
    if (slot < GCAP) glist[g * GCAP + slot] = e0 + i;
  }
}

// ---------------------------------------------------------------------------
// csrify: per (bucket,path): 512-node local CSR in LDS -> global off/csr
// ---------------------------------------------------------------------------
__global__ __launch_bounds__(256) void csrify_kernel(
    const unsigned* __restrict__ bdata, const int* __restrict__ gcnt,
    int* __restrict__ off, unsigned short* __restrict__ csr) {
  __shared__ unsigned ebuf[BCAP];
  __shared__ int gc[NB2];
  __shared__ int degc[512];
  __shared__ int loff[513];
  __shared__ int tmp[256];
  __shared__ int base_s;
  int b = blockIdx.x, p = blockIdx.y;
  int tid = threadIdx.x;
  if (tid < NB2) gc[tid] = min(gcnt[p * NB2 + tid], BCAP);
  __syncthreads();
  if (tid == 0) {
    int s = 0;
    for (int i = 0; i < b; i++) s += gc[i];
    base_s = s;
  }
  int cnt = gc[b];
  const unsigned* bp = bdata + ((size_t)(p * NB2 + b)) * BCAP;
  for (int i = tid; i < cnt; i += 256) ebuf[i] = bp[i];
  degc[tid] = 0; degc[256 + tid] = 0;
  __syncthreads();
  for (int i = tid; i < cnt; i += 256)
    atomicAdd(&degc[(ebuf[i] >> 16) & 511], 1);
  __syncthreads();
  int d0 = degc[2 * tid], d1 = degc[2 * tid + 1];
  tmp[tid] = d0 + d1;
  __syncthreads();
  for (int o = 1; o < 256; o <<= 1) {
    int v = (tid >= o) ? tmp[tid - o] : 0;
    __syncthreads();
    tmp[tid] += v;
    __syncthreads();
  }
  int bse = tmp[tid] - d0 - d1;
  loff[2 * tid] = bse; loff[2 * tid + 1] = bse + d0;
  if (tid == 255) loff[512] = tmp[255];
  __syncthreads();
  int base = base_s;
  for (int dl = tid; dl < 512; dl += 256) {
    int n = b * 512 + dl;
    if (n <= NN) off[(size_t)p * (NN + 1) + n] = base + loff[dl];
  }
  degc[tid] = 0; degc[256 + tid] = 0;   // reuse as cursors
  __syncthreads();
  for (int i = tid; i < cnt; i += 256) {
    unsigned pk = ebuf[i];
    int dl = (pk >> 16) & 511;
    int slot = loff[dl] + atomicAdd(&degc[dl], 1);
    csr[(size_t)p * EE + base + slot] = (unsigned short)(pk & 0xffff);
  }
}

// ---------------------------------------------------------------------------
// GEMM1: hp_b[p][M,256] = h_b[M,128] @ W[p], MFMA bf16. p = p0 + blockIdx.z.
// ---------------------------------------------------------------------------
__global__ __launch_bounds__(256) void gemm1_kernel(
    const unsigned short* __restrict__ hA, const unsigned short* __restrict__ Bt,
    unsigned short* __restrict__ Cb, int M, int p0, size_t cstride) {
  __shared__ unsigned short As[64 * 128];
  __shared__ unsigned short Bs[128 * 128];
  int tid = threadIdx.x;
  int pl = blockIdx.z;
  const unsigned short* Bp = Bt + (size_t)(p0 + pl) * 32768;
  unsigned short* Cp = Cb + (size_t)pl * cstride;
  int row0 = blockIdx.x * 64, col0 = blockIdx.y * 128;
  #pragma unroll
  for (int i = 0; i < 4; i++) {
    int c = i * 256 + tid;
    int row = c >> 4, g = c & 15;
    int grow = row0 + row;
    uint4 v = make_uint4(0, 0, 0, 0);
    if (grow < M) v = *(const uint4*)(hA + (size_t)grow * 128 + g * 8);
    *(uint4*)&As[row * 128 + ((g ^ (row & 15)) << 3)] = v;
  }
  #pragma unroll
  for (int i = 0; i < 8; i++) {
    int c = i * 256 + tid;
    int row = c >> 4, g = c & 15;
    uint4 v = *(const uint4*)(Bp + (size_t)(col0 + row) * 128 + g * 8);
    *(uint4*)&Bs[row * 128 + ((g ^ (row & 15)) << 3)] = v;
  }
  __syncthreads();
  int wave = tid >> 6, lane = tid & 63;
  int ln = lane & 15, quad = lane >> 4;
  int mbase = (wave >> 1) * 32, nbase = (wave & 1) * 64;
  f32x4 acc[2][4] = {};
  #pragma unroll
  for (int ks = 0; ks < 4; ks++) {
    int g = ks * 4 + quad;
    bf16x8 a[2], bb[4];
    #pragma unroll
    for (int mi = 0; mi < 2; mi++) {
      int r = mbase + mi * 16 + ln;
      a[mi] = *(const bf16x8*)&As[r * 128 + ((g ^ ln) << 3)];
    }
    #pragma unroll
    for (int ni = 0; ni < 4; ni++) {
      int r = nbase + ni * 16 + ln;
      bb[ni] = *(const bf16x8*)&Bs[r * 128 + ((g ^ ln) << 3)];
    }
    #pragma unroll
    for (int mi = 0; mi < 2; mi++)
      #pragma unroll
      for (int ni = 0; ni < 4; ni++)
        acc[mi][ni] = __builtin_amdgcn_mfma_f32_16x16x32_bf16(a[mi], bb[ni], acc[mi][ni], 0, 0, 0);
  }
  #pragma unroll
  for (int mi = 0; mi < 2; mi++) {
    int gm0 = row0 + mbase + mi * 16 + quad * 4;
    #pragma unroll
    for (int ni = 0; ni < 4; ni++) {
      int gn = col0 + nbase + ni * 16 + ln;
      #pragma unroll
      for (int r = 0; r < 4; r++) {
        int gm = gm0 + r;
        if (gm < M) Cp[(size_t)gm * 256 + gn] = f2b(acc[mi][ni][r]);
      }
    }
  }
}

// ---------------------------------------------------------------------------
// elr: el/er = h_b (bf16) @ folded fp32 weights. p = p0 + blockIdx.y.
// ---------------------------------------------------------------------------
__global__ __launch_bounds__(256) void elr_kernel(
    const unsigned short* __restrict__ h_b, const float* __restrict__ wl,
    const float* __restrict__ wr, float* __restrict__ el,
    float* __restrict__ er, int N, int p0, size_t estride) {
  __shared__ float wls[128 * 8], wrs[128 * 8];
  int pl = blockIdx.y;
  const float* wlp = wl + (size_t)(p0 + pl) * 1024;
  const float* wrp = wr + (size_t)(p0 + pl) * 1024;
  float* elp = el + (size_t)pl * estride;
  float* erp = er + (size_t)pl * estride;
  for (int i = threadIdx.x; i < 1024; i += 256) { wls[i] = wlp[i]; wrs[i] = wrp[i]; }
  __syncthreads();
  int n = blockIdx.x * 256 + threadIdx.x;
  if (n >= N) return;
  float accl[8] = {}, accr[8] = {};
  for (int kk = 0; kk < 16; kk++) {          // 8 bf16 per step
    uint4 raw = *(const uint4*)(h_b + (size_t)n * 128 + kk * 8);
    unsigned uu[4] = {raw.x, raw.y, raw.z, raw.w};
    #pragma unroll
    for (int q = 0; q < 4; q++) {
      float v0 = __builtin_bit_cast(float, uu[q] << 16);
      float v1 = __builtin_bit_cast(float, uu[q] & 0xffff0000u);
      int k = kk * 8 + q * 2;
      #pragma unroll
      for (int hh = 0; hh < 8; hh++) {
        accl[hh] += v0 * wls[k * 8 + hh] + v1 * wls[(k + 1) * 8 + hh];
        accr[hh] += v0 * wrs[k * 8 + hh] + v1 * wrs[(k + 1) * 8 + hh];
      }
    }
  }
  *(float4*)(elp + (size_t)n * 8)     = make_float4(accl[0], accl[1], accl[2], accl[3]);
  *(float4*)(elp + (size_t)n * 8 + 4) = make_float4(accl[4], accl[5], accl[6], accl[7]);
  *(float4*)(erp + (size_t)n * 8)     = make_float4(accr[0], accr[1], accr[2], accr[3]);
  *(float4*)(erp + (size_t)n * 8 + 4) = make_float4(accr[4], accr[5], accr[6], accr[7]);
}

// ---------------------------------------------------------------------------
// agg: one wave per dst node, edge loop UNROLLED x4 for memory-level
// parallelism (csr contiguous; el/hp random). out=(sum w*hp)/(sum w)+bias,ELU.
// ---------------------------------------------------------------------------
__global__ __launch_bounds__(256) void agg_kernel(
    const unsigned short* __restrict__ hp_b, const float* __restrict__ el,
    const float* __restrict__ er, const unsigned short* __restrict__ csr,
    const int* __restrict__ off, const float* __restrict__ bias,
    unsigned short* __restrict__ emb_b, int N, int p0,
    size_t hstride, size_t estride, size_t embstride) {
  int pl = blockIdx.y;
  int p = p0 + pl;
  const unsigned short* hp = hp_b + (size_t)pl * hstride;
  const float* elp = el + (size_t)pl * estride;
  const float* erp = er + (size_t)pl * estride;
  const unsigned short* csrp = csr + (size_t)p * EE;
  const int* offp = off + (size_t)p * (NN + 1);
  const float* bp = bias + (size_t)p * HF;
  unsigned short* embp = emb_b + (size_t)pl * embstride;
  int n = blockIdx.x * 4 + (threadIdx.x >> 6);
  if (n >= N) return;
  int lane = threadIdx.x & 63;
  int h = lane >> 3;
  int e0 = offp[n], e1 = offp[n + 1];
  float erh = erp[n * NH + h];
  float den = 0.f, a0 = 0.f, a1 = 0.f, a2 = 0.f, a3 = 0.f;
  int e = e0;
  for (; e + 4 <= e1; e += 4) {
    int s0 = csrp[e], s1 = csrp[e + 1], s2 = csrp[e + 2], s3 = csrp[e + 3];
    float x0 = elp[s0 * NH + h] + erh;
    float x1 = elp[s1 * NH + h] + erh;
    float x2 = elp[s2 * NH + h] + erh;
    float x3 = elp[s3 * NH + h] + erh;
    ushort4 h0 = *(const ushort4*)(hp + (size_t)s0 * HF + lane * 4);
    ushort4 h1 = *(const ushort4*)(hp + (size_t)s1 * HF + lane * 4);
    ushort4 h2 = *(const ushort4*)(hp + (size_t)s2 * HF + lane * 4);
    ushort4 h3 = *(const ushort4*)(hp + (size_t)s3 * HF + lane * 4);
    x0 = (x0 > 0.f) ? x0 : 0.2f * x0;
    x1 = (x1 > 0.f) ? x1 : 0.2f * x1;
    x2 = (x2 > 0.f) ? x2 : 0.2f * x2;
    x3 = (x3 > 0.f) ? x3 : 0.2f * x3;
    float w0 = fexp(x0), w1 = fexp(x1), w2 = fexp(x2), w3 = fexp(x3);
    den += (w0 + w1) + (w2 + w3);
    a0 += (w0 * b2f(h0.x) + w1 * b2f(h1.x)) + (w2 * b2f(h2.x) + w3 * b2f(h3.x));
    a1 += (w0 * b2f(h0.y) + w1 * b2f(h1.y)) + (w2 * b2f(h2.y) + w3 * b2f(h3.y));
    a2 += (w0 * b2f(h0.z) + w1 * b2f(h1.z)) + (w2 * b2f(h2.z) + w3 * b2f(h3.z));
    a3 += (w0 * b2f(h0.w) + w1 * b2f(h1.w)) + (w2 * b2f(h2.w) + w3 * b2f(h3.w));
  }
  for (; e < e1; e++) {
    int s = csrp[e];
    float x = elp[s * NH + h] + erh;
    x = (x > 0.f) ? x : 0.2f * x;
    float w = fexp(x);
    den += w;
    ushort4 hv = *(const ushort4*)(hp + (size_t)s * HF + lane * 4);
    a0 += w * b2f(hv.x); a1 += w * b2f(hv.y);
    a2 += w * b2f(hv.z); a3 += w * b2f(hv.w);
  }
  float inv = (den > 0.f) ? 1.f / den : 0.f;
  float4 bv = *(const float4*)(bp + lane * 4);
  float o0 = a0 * inv + bv.x, o1 = a1 * inv + bv.y;
  float o2 = a2 * inv + bv.z, o3 = a3 * inv + bv.w;
  o0 = (o0 > 0.f) ? o0 : fexp(o0) - 1.f;
  o1 = (o1 > 0.f) ? o1 : fexp(o1) - 1.f;
  o2 = (o2 > 0.f) ? o2 : fexp(o2) - 1.f;
  o3 = (o3 > 0.f) ? o3 : fexp(o3) - 1.f;
  ushort4 ov;
  ov.x = f2b(o0); ov.y = f2b(o1); ov.z = f2b(o2); ov.w = f2b(o3);
  *(ushort4*)(embp + (size_t)n * HF + lane * 4) = ov;
}

// ---------------------------------------------------------------------------
// GEMM2 + semantic epilogue: wpart[p][bx] = block-sum of tanh(emb@W1+b1).W2
// (NO cross-block atomics — 12.5K same-address atomic RMWs were the R9 cost)
// ---------------------------------------------------------------------------
__global__ __launch_bounds__(256) void gemm2_kernel(
    const unsigned short* __restrict__ A, const unsigned short* __restrict__ Bt,
    const float* __restrict__ b1, const float* __restrict__ W2,
    float* __restrict__ wpart, int M, int p0, size_t astride) {
  __shared__ unsigned short As[64 * 128];
  __shared__ unsigned short Bs[128 * 128];
  __shared__ float wred[4];
  int tid = threadIdx.x;
  int pl = blockIdx.y;
  const unsigned short* Ap = A + (size_t)pl * astride;
  int row0 = blockIdx.x * 64;
  int wave = tid >> 6, lane = tid & 63;
  int ln = lane & 15, quad = lane >> 4;
  int mbase = (wave >> 1) * 32, nbase = (wave & 1) * 64;
  f32x4 acc[2][4] = {};
  for (int kc = 0; kc < 2; kc++) {
    #pragma unroll
    for (int i = 0; i < 4; i++) {
      int c = i * 256 + tid;
      int row = c >> 4, g = c & 15;
      int grow = row0 + row;
      uint4 v = make_uint4(0, 0, 0, 0);
      if (grow < M) v = *(const uint4*)(Ap + (size_t)grow * 256 + kc * 128 + g * 8);
      *(uint4*)&As[row * 128 + ((g ^ (row & 15)) << 3)] = v;
    }
    #pragma unroll
    for (int i = 0; i < 8; i++) {
      int c = i * 256 + tid;
      int row = c >> 4, g = c & 15;
      uint4 v = *(const uint4*)(Bt + (size_t)row * 256 + kc * 128 + g * 8);
      *(uint4*)&Bs[row * 128 + ((g ^ (row & 15)) << 3)] = v;
    }
    __syncthreads();
    #pragma unroll
    for (int ks = 0; ks < 4; ks++) {
      int g = ks * 4 + quad;
      bf16x8 a[2], bb[4];
      #pragma unroll
      for (int mi = 0; mi < 2; mi++) {
        int r = mbase + mi * 16 + ln;
        a[mi] = *(const bf16x8*)&As[r * 128 + ((g ^ ln) << 3)];
      }
      #pragma unroll
      for (int ni = 0; ni < 4; ni++) {
        int r = nbase + ni * 16 + ln;
        bb[ni] = *(const bf16x8*)&Bs[r * 128 + ((g ^ ln) << 3)];
      }
      #pragma unroll
      for (int mi = 0; mi < 2; mi++)
        #pragma unroll
        for (int ni = 0; ni < 4; ni++)
          acc[mi][ni] = __builtin_amdgcn_mfma_f32_16x16x32_bf16(a[mi], bb[ni], acc[mi][ni], 0, 0, 0);
    }
    __syncthreads();
  }
  float b1v[4], w2v[4];
  #pragma unroll
  for (int ni = 0; ni < 4; ni++) {
    int col = nbase + ni * 16 + ln;
    b1v[ni] = b1[col]; w2v[ni] = W2[col];
  }
  float s = 0.f;
  #pragma unroll
  for (int mi = 0; mi < 2; mi++) {
    int gm0 = row0 + mbase + mi * 16 + quad * 4;
    #pragma unroll
    for (int r = 0; r < 4; r++) {
      if (gm0 + r < M) {
        #pragma unroll
        for (int ni = 0; ni < 4; ni++)
          s += ftanh(acc[mi][ni][r] + b1v[ni]) * w2v[ni];
      }
    }
  }
  #pragma unroll
  for (int o = 32; o > 0; o >>= 1) s += __shfl_down(s, o);
  if (lane == 0) wred[wave] = s;
  __syncthreads();
  if (tid == 0)
    wpart[(size_t)(p0 + pl) * NBG2 + blockIdx.x] =
        (wred[0] + wred[1]) + (wred[2] + wred[3]);
}

// ---------------------------------------------------------------------------
// pool: one block per (graph, path); register accumulation, no atomics.
// ---------------------------------------------------------------------------
__global__ __launch_bounds__(256) void pool_kernel(
    const unsigned short* __restrict__ emb, const int* __restrict__ glist,
    const int* __restrict__ gcnt2, float* __restrict__ pool,
    int p0, size_t embstride) {
  __shared__ int nl[GCAP];
  __shared__ float sm[4][64][4];
  int b = blockIdx.x, pl = blockIdx.y;
  const unsigned short* embp = emb + (size_t)pl * embstride;
  int tid = threadIdx.x;
  int cnt = min(gcnt2[b], GCAP);
  for (int i = tid; i < cnt; i += 256) nl[i] = glist[b * GCAP + i];
  __syncthreads();
  int sub = tid >> 6, lane = tid & 63;
  float a0 = 0.f, a1 = 0.f, a2 = 0.f, a3 = 0.f;
  for (int i = sub; i < cnt; i += 4) {
    ushort4 v = *(const ushort4*)(embp + (size_t)nl[i] * HF + lane * 4);
    a0 += b2f(v.x); a1 += b2f(v.y); a2 += b2f(v.z); a3 += b2f(v.w);
  }
  sm[sub][lane][0] = a0; sm[sub][lane][1] = a1;
  sm[sub][lane][2] = a2; sm[sub][lane][3] = a3;
  __syncthreads();
  int fl = tid >> 2, j = tid & 3;
  float s = sm[0][fl][j] + sm[1][fl][j] + sm[2][fl][j] + sm[3][fl][j];
  pool[((size_t)(p0 + pl) * BG + b) * HF + tid] = s;
}

// ---------------------------------------------------------------------------
// final: reduce wpart -> beta softmax; counts from gcnt2; logits + pooled out
// ---------------------------------------------------------------------------
__global__ __launch_bounds__(256) void final_kernel(
    const float* __restrict__ pool, const float* __restrict__ wpart,
    const int* __restrict__ gcnt2, const float* __restrict__ clsW,
    const float* __restrict__ clsb, float* __restrict__ out, int N) {
  int b = blockIdx.x;
  int f = threadIdx.x;
  __shared__ float red[256];
  float wm[PM];
  #pragma unroll
  for (int p = 0; p < PM; p++) {
    float s = 0.f;
    for (int i = f; i < NBG2; i += 256) s += wpart[(size_t)p * NBG2 + i];
    red[f] = s;
    __syncthreads();
    for (int st = 128; st > 0; st >>= 1) {
      if (f < st) red[f] += red[f + st];
      __syncthreads();
    }
    wm[p] = red[0] / (float)N;
    __syncthreads();
  }
  float c = fmaxf((float)gcnt2[b], 1.f);
  float mx = -1e30f;
  #pragma unroll
  for (int p = 0; p < PM; p++) mx = fmaxf(mx, wm[p]);
  float es = 0.f, e[PM];
  #pragma unroll
  for (int p = 0; p < PM; p++) { e[p] = expf(wm[p] - mx); es += e[p]; }
  float v = 0.f;
  #pragma unroll
  for (int p = 0; p < PM; p++)
    v += (e[p] / es) * pool[((size_t)p * BG + b) * HF + f];
  v /= c;
  out[256 + (size_t)b * HF + f] = v;
  __shared__ float sm[256];
  sm[f] = v * clsW[f * 2 + 0];
  __syncthreads();
  for (int st = 128; st > 0; st >>= 1) {
    if (f < st) sm[f] += sm[f + st];
    __syncthreads();
  }
  float l0 = sm[0];
  __syncthreads();
  sm[f] = v * clsW[f * 2 + 1];
  __syncthreads();
  for (int st = 128; st > 0; st >>= 1) {
    if (f < st) sm[f] += sm[f + st];
    __syncthreads();
  }
  if (f == 0) {
    out[b * 2 + 0] = l0 + clsb[0];
    out[b * 2 + 1] = sm[0] + clsb[1];
  }
}

// ---------------------------------------------------------------------------
extern "C" void kernel_launch(void* const* d_in, const int* in_sizes, int n_in,
                              void* d_out, int out_size, void* d_ws, size_t ws_size,
                              hipStream_t stream) {
  const float* h      = (const float*)d_in[0];
  const float* Wg     = (const float*)d_in[1];
  const float* attn_l = (const float*)d_in[2];
  const float* attn_r = (const float*)d_in[3];
  const float* gatb   = (const float*)d_in[4];
  const float* semW1  = (const float*)d_in[5];
  const float* semb1  = (const float*)d_in[6];
  const float* semW2  = (const float*)d_in[7];
  const float* clsW   = (const float*)d_in[8];
  const float* clsb   = (const float*)d_in[9];
  const int*   src    = (const int*)d_in[10];
  const int*   dst    = (const int*)d_in[11];
  const int*   gid    = (const int*)d_in[12];
  float* out = (float*)d_out;

  auto layout_size = [](int PMg) -> size_t {
    size_t o = 0;
    auto alloc = [&](size_t bytes) { o += (bytes + 255) & ~(size_t)255; };
    alloc((size_t)NN * INF_ * 2);              // h_b
    alloc((size_t)PMg * NN * HF * 2);          // hp_b
    alloc((size_t)PMg * NN * HF * 2);          // emb_b
    alloc((size_t)PM * HF * INF_ * 2);         // Wb_t
    alloc((size_t)HS * HF * 2);                // W1_t
    alloc((size_t)PM * INF_ * NH * 4);         // wl
    alloc((size_t)PM * INF_ * NH * 4);         // wr
    alloc((size_t)PMg * NN * NH * 4);          // el
    alloc((size_t)PMg * NN * NH * 4);          // er
    alloc((size_t)PM * NB2 * BCAP * 4);        // bdata
    alloc((size_t)PM * NB2 * 4);               // gcnt
    alloc((size_t)BG * GCAP * 4);              // glist
    alloc((size_t)BG * 4);                     // gcnt2
    alloc((size_t)PM * (NN + 1) * 4);          // off
    alloc((size_t)PM * EE * 2);                // csr
    alloc((size_t)PM * BG * HF * 4);           // pool
    alloc((size_t)PM * NBG2 * 4);              // wpart
    return o;
  };
  int PMg = (layout_size(4) <= ws_size) ? 4 : 1;

  char* ws = (char*)d_ws;
  size_t o = 0;
  auto alloc = [&](size_t bytes) { size_t r = o; o += (bytes + 255) & ~(size_t)255; return r; };
  unsigned short* h_b   = (unsigned short*)(ws + alloc((size_t)NN * INF_ * 2));
  unsigned short* hp_b  = (unsigned short*)(ws + alloc((size_t)PMg * NN * HF * 2));
  unsigned short* emb_b = (unsigned short*)(ws + alloc((size_t)PMg * NN * HF * 2));
  unsigned short* Wb_t  = (unsigned short*)(ws + alloc((size_t)PM * HF * INF_ * 2));
  unsigned short* W1_t  = (unsigned short*)(ws + alloc((size_t)HS * HF * 2));
  float* wl    = (float*)(ws + alloc((size_t)PM * INF_ * NH * 4));
  float* wr    = (float*)(ws + alloc((size_t)PM * INF_ * NH * 4));
  float* el    = (float*)(ws + alloc((size_t)PMg * NN * NH * 4));
  float* er    = (float*)(ws + alloc((size_t)PMg * NN * NH * 4));
  unsigned* bdata = (unsigned*)(ws + alloc((size_t)PM * NB2 * BCAP * 4));
  int*   gcnt  = (int*)(ws + alloc((size_t)PM * NB2 * 4));
  int*   glist = (int*)(ws + alloc((size_t)BG * GCAP * 4));
  int*   gcnt2 = (int*)(ws + alloc((size_t)BG * 4));
  int*   off   = (int*)(ws + alloc((size_t)PM * (NN + 1) * 4));
  unsigned short* csr = (unsigned short*)(ws + alloc((size_t)PM * EE * 2));
  float* pool  = (float*)(ws + alloc((size_t)PM * BG * HF * 4));
  float* wpart = (float*)(ws + alloc((size_t)PM * NBG2 * 4));

  const size_t hpS  = (PMg == 4) ? (size_t)NN * HF : 0;
  const size_t embS = hpS;
  const size_t elS  = (PMg == 4) ? (size_t)NN * NH : 0;

  prep_kernel<<<1 + 6250 + 512 + 128 + 16, 256, 0, stream>>>(
      h, Wg, semW1, attn_l, attn_r, h_b, Wb_t, W1_t, wl, wr, gcnt, gcnt2);
  bucket_kernel<<<dim3((EE + BCH - 1) / BCH, PM), 256, 0, stream>>>(src, dst, bdata, gcnt);
  gbucket_kernel<<<(NN + BCH - 1) / BCH, 256, 0, stream>>>(gid, glist, gcnt2);
  csrify_kernel<<<dim3(NB2, PM), 256, 0, stream>>>(bdata, gcnt, off, csr);

  if (PMg == 4) {
    gemm1_kernel<<<dim3((NN + 63) / 64, 2, 4), 256, 0, stream>>>(h_b, Wb_t, hp_b, NN, 0, hpS);
    elr_kernel<<<dim3((NN + 255) / 256, 4), 256, 0, stream>>>(h_b, wl, wr, el, er, NN, 0, elS);
    agg_kernel<<<dim3((NN + 3) / 4, 4), 256, 0, stream>>>(
        hp_b, el, er, csr, off, gatb, emb_b, NN, 0, hpS, elS, embS);
    gemm2_kernel<<<dim3(NBG2, 4), 256, 0, stream>>>(
        emb_b, W1_t, semb1, semW2, wpart, NN, 0, embS);
    pool_kernel<<<dim3(BG, 4), 256, 0, stream>>>(emb_b, glist, gcnt2, pool, 0, embS);
  } else {
    for (int p = 0; p < PM; p++) {
      gemm1_kernel<<<dim3((NN + 63) / 64, 2, 1), 256, 0, stream>>>(h_b, Wb_t, hp_b, NN, p, 0);
      elr_kernel<<<dim3((NN + 255) / 256, 1), 256, 0, stream>>>(h_b, wl, wr, el, er, NN, p, 0);
      agg_kernel<<<dim3((NN + 3) / 4, 1), 256, 0, stream>>>(
          hp_b, el, er, csr, off, gatb, emb_b, NN, p, 0, 0, 0);
      gemm2_kernel<<<dim3(NBG2, 1), 256, 0, stream>>>(
          emb_b, W1_t, semb1, semW2, wpart, NN, p, 0);
      pool_kernel<<<dim3(BG, 1), 256, 0, stream>>>(emb_b, glist, gcnt2, pool, p, 0);
    }
  }

  final_kernel<<<BG, 256, 0, stream>>>(pool, wpart, gcnt2, clsW, clsb, out, NN);
}

// Round 11
// 457.210 us; speedup vs baseline: 2.0214x; 1.0038x over previous
//
#include <hip/hip_runtime.h>

#define NN 50000
#define PM 4
#define EE 500000
#define INF_ 128
#define NH 8
#define FF 32
#define HF 256
#define HS 128
#define BG 128
#define OUTC 2

#define NB2 98        // buckets per path: dst>>9 (512 nodes/bucket)
#define BCAP 6144     // bucket capacity (mean 5102, sd ~71 -> 14 sigma slack)
#define BCH 4096      // edges per workgroup in bucket pass
#define GCAP 576      // nodes per graph capacity (mean 390, sd ~20 -> 9 sigma)
#define NBG2 782      // gemm2 blocks per path = ceil(NN/64)

typedef __attribute__((ext_vector_type(8))) short bf16x8;
typedef __attribute__((ext_vector_type(4))) float f32x4;

__device__ __forceinline__ float b2f(unsigned short x) {
  unsigned u = ((unsigned)x) << 16;
  return __builtin_bit_cast(float, u);
}
__device__ __forceinline__ unsigned short f2b(float f) {
  unsigned u = __builtin_bit_cast(unsigned, f);
  u += 0x7fff + ((u >> 16) & 1);   // RNE
  return (unsigned short)(u >> 16);
}
__device__ __forceinline__ float fexp(float x) { return __expf(x); }
// overflow-safe fast tanh: t = e^{-2|x|} in (0,1]
__device__ __forceinline__ float ftanh(float x) {
  float t = __expf(-2.f * fabsf(x));
  float r = (1.f - t) / (1.f + t);
  return copysignf(r, x);
}

// ---------------------------------------------------------------------------
// prep: zero gcnt/gcnt2 + h->bf16 + Wg transpose + W1 transpose + fold
// ---------------------------------------------------------------------------
__global__ __launch_bounds__(256) void prep_kernel(
    const float* __restrict__ h, const float* __restrict__ Wg,
    const float* __restrict__ W1, const float* __restrict__ al,
    const float* __restrict__ ar,
    unsigned short* __restrict__ h_b, unsigned short* __restrict__ Wb_t,
    unsigned short* __restrict__ W1_t, float* __restrict__ wl,
    float* __restrict__ wr, int* __restrict__ gcnt, int* __restrict__ gcnt2) {
  int b = blockIdx.x;
  int tid = threadIdx.x;
  if (b < 1) {                 // zero gcnt + gcnt2
    for (int i = tid; i < PM * NB2; i += 256) gcnt[i] = 0;
    if (tid < BG) gcnt2[tid] = 0;
    return;
  }
  b -= 1;
  if (b < 6250) {              // h -> bf16 (float4 granular)
    int t = b * 256 + tid;
    float4 v = *(const float4*)(h + (size_t)t * 4);
    ushort4 o;
    o.x = f2b(v.x); o.y = f2b(v.y); o.z = f2b(v.z); o.w = f2b(v.w);
    *(ushort4*)(h_b + (size_t)t * 4) = o;
    return;
  }
  b -= 6250;
  if (b < 512) {               // Wg [P][128k][256n] -> [P][256n][128k] bf16
    int t = b * 256 + tid;
    int p = t >> 15, rem = t & 32767;
    int n = rem >> 7, k = rem & 127;
    Wb_t[(size_t)p * 32768 + n * 128 + k] = f2b(Wg[(size_t)p * 32768 + k * 256 + n]);
    return;
  }
  b -= 512;
  if (b < 128) {               // W1 [256k][128n] -> [128n][256k] bf16
    int t = b * 256 + tid;
    int n = t >> 8, k = t & 255;
    W1_t[n * 256 + k] = f2b(W1[k * 128 + n]);
    return;
  }
  b -= 128;
  {                            // fold: wl/wr[p][k][h]
    int t = b * 256 + tid;
    int p = t >> 10, rem = t & 1023;
    int k = rem >> 3, hh = rem & 7;
    const float* wrow = Wg + (size_t)p * 32768 + k * 256 + hh * 32;
    const float* alp = al + p * 256 + hh * 32;
    const float* arp = ar + p * 256 + hh * 32;
    float sl = 0.f, sr = 0.f;
    #pragma unroll
    for (int f = 0; f < 32; f++) { sl += wrow[f] * alp[f]; sr += wrow[f] * arp[f]; }
    wl[t] = sl; wr[t] = sr;
  }
}

// ---------------------------------------------------------------------------
// bucket: per-block histogram -> global segment reserve -> LDS-cursor scatter
// ---------------------------------------------------------------------------
__global__ __launch_bounds__(256) void bucket_kernel(
    const int* __restrict__ src, const int* __restrict__ dst,
    unsigned* __restrict__ bdata, int* __restrict__ gcnt) {
  __shared__ unsigned ed[BCH];
  __shared__ int hist[NB2], gbase[NB2], cur[NB2];
  int p = blockIdx.y;
  int e0 = blockIdx.x * BCH;
  int n = min(BCH, EE - e0);
  int tid = threadIdx.x;
  if (tid < NB2) hist[tid] = 0;
  __syncthreads();
  const int* sp = src + (size_t)p * EE + e0;
  const int* dp = dst + (size_t)p * EE + e0;
  for (int i = tid; i < n; i += 256) {
    int s = sp[i], d = dp[i];
    ed[i] = ((unsigned)d << 16) | (unsigned)s;
    atomicAdd(&hist[d >> 9], 1);
  }
  __syncthreads();
  if (tid < NB2) {
    gbase[tid] = atomicAdd(&gcnt[p * NB2 + tid], hist[tid]);
    cur[tid] = 0;
  }
  __syncthreads();
  for (int i = tid; i < n; i += 256) {
    unsigned pk = ed[i];
    int bk = pk >> 25;           // (dst>>9)
    int slot = gbase[bk] + atomicAdd(&cur[bk], 1);
    if (slot < BCAP)
      bdata[((size_t)(p * NB2 + bk)) * BCAP + slot] = pk;
  }
}

// ---------------------------------------------------------------------------
// gbucket: bin node ids by graph id -> glist[BG][GCAP] + per-graph counts
// ---------------------------------------------------------------------------
__global__ __launch_bounds__(256) void gbucket_kernel(
    const int* __restrict__ gid, int* __restrict__ glist, int* __restrict__ gcnt2) {
  __shared__ int gl[BCH];
  __shared__ int hist[BG], gbase[BG], cur[BG];
  int e0 = blockIdx.x * BCH;
  int n = min(BCH, NN - e0);
  int tid = threadIdx.x;
  if (tid < BG) hist[tid] = 0;
  __syncthreads();
  for (int i = tid; i < n; i += 256) {
    int g = gid[e0 + i];
    gl[i] = g;
    atomicAdd(&hist[g], 1);
  }
  __syncthreads();
  if (tid < BG) {
    gbase[tid] = atomicAdd(&gcnt2[tid], hist[tid]);
    cur[tid] = 0;
  }
  __syncthreads();
  for (int i = tid; i < n; i += 256) {
    int g = gl[i];
    int slot = gbase[g] + atomicAdd(&cur[g], 1);
    if (slot < GCAP) glist[g * GCAP + slot] = e0 + i;
  }
}

// ---------------------------------------------------------------------------
// csrify: per (bucket,path): 512-node local CSR in LDS -> global off/csr
// ---------------------------------------------------------------------------
__global__ __launch_bounds__(256) void csrify_kernel(
    const unsigned* __restrict__ bdata, const int* __restrict__ gcnt,
    int* __restrict__ off, unsigned short* __restrict__ csr) {
  __shared__ unsigned ebuf[BCAP];
  __shared__ int gc[NB2];
  __shared__ int degc[512];
  __shared__ int loff[513];
  __shared__ int tmp[256];
  __shared__ int base_s;
  int b = blockIdx.x, p = blockIdx.y;
  int tid = threadIdx.x;
  if (tid < NB2) gc[tid] = min(gcnt[p * NB2 + tid], BCAP);
  __syncthreads();
  if (tid == 0) {
    int s = 0;
    for (int i = 0; i < b; i++) s += gc[i];
    base_s = s;
  }
  int cnt = gc[b];
  const unsigned* bp = bdata + ((size_t)(p * NB2 + b)) * BCAP;
  for (int i = tid; i < cnt; i += 256) ebuf[i] = bp[i];
  degc[tid] = 0; degc[256 + tid] = 0;
  __syncthreads();
  for (int i = tid; i < cnt; i += 256)
    atomicAdd(&degc[(ebuf[i] >> 16) & 511], 1);
  __syncthreads();
  int d0 = degc[2 * tid], d1 = degc[2 * tid + 1];
  tmp[tid] = d0 + d1;
  __syncthreads();
  for (int o = 1; o < 256; o <<= 1) {
    int v = (tid >= o) ? tmp[tid - o] : 0;
    __syncthreads();
    tmp[tid] += v;
    __syncthreads();
  }
  int bse = tmp[tid] - d0 - d1;
  loff[2 * tid] = bse; loff[2 * tid + 1] = bse + d0;
  if (tid == 255) loff[512] = tmp[255];
  __syncthreads();
  int base = base_s;
  for (int dl = tid; dl < 512; dl += 256) {
    int n = b * 512 + dl;
    if (n <= NN) off[(size_t)p * (NN + 1) + n] = base + loff[dl];
  }
  degc[tid] = 0; degc[256 + tid] = 0;   // reuse as cursors
  __syncthreads();
  for (int i = tid; i < cnt; i += 256) {
    unsigned pk = ebuf[i];
    int dl = (pk >> 16) & 511;
    int slot = loff[dl] + atomicAdd(&degc[dl], 1);
    csr[(size_t)p * EE + base + slot] = (unsigned short)(pk & 0xffff);
  }
}

// ---------------------------------------------------------------------------
// GEMM1: hp_b[p][M,256] = h_b[M,128] @ W[p], MFMA bf16. p = p0 + blockIdx.z.
// ---------------------------------------------------------------------------
__global__ __launch_bounds__(256) void gemm1_kernel(
    const unsigned short* __restrict__ hA, const unsigned short* __restrict__ Bt,
    unsigned short* __restrict__ Cb, int M, int p0, size_t cstride) {
  __shared__ unsigned short As[64 * 128];
  __shared__ unsigned short Bs[128 * 128];
  int tid = threadIdx.x;
  int pl = blockIdx.z;
  const unsigned short* Bp = Bt + (size_t)(p0 + pl) * 32768;
  unsigned short* Cp = Cb + (size_t)pl * cstride;
  int row0 = blockIdx.x * 64, col0 = blockIdx.y * 128;
  #pragma unroll
  for (int i = 0; i < 4; i++) {
    int c = i * 256 + tid;
    int row = c >> 4, g = c & 15;
    int grow = row0 + row;
    uint4 v = make_uint4(0, 0, 0, 0);
    if (grow < M) v = *(const uint4*)(hA + (size_t)grow * 128 + g * 8);
    *(uint4*)&As[row * 128 + ((g ^ (row & 15)) << 3)] = v;
  }
  #pragma unroll
  for (int i = 0; i < 8; i++) {
    int c = i * 256 + tid;
    int row = c >> 4, g = c & 15;
    uint4 v = *(const uint4*)(Bp + (size_t)(col0 + row) * 128 + g * 8);
    *(uint4*)&Bs[row * 128 + ((g ^ (row & 15)) << 3)] = v;
  }
  __syncthreads();
  int wave = tid >> 6, lane = tid & 63;
  int ln = lane & 15, quad = lane >> 4;
  int mbase = (wave >> 1) * 32, nbase = (wave & 1) * 64;
  f32x4 acc[2][4] = {};
  #pragma unroll
  for (int ks = 0; ks < 4; ks++) {
    int g = ks * 4 + quad;
    bf16x8 a[2], bb[4];
    #pragma unroll
    for (int mi = 0; mi < 2; mi++) {
      int r = mbase + mi * 16 + ln;
      a[mi] = *(const bf16x8*)&As[r * 128 + ((g ^ ln) << 3)];
    }
    #pragma unroll
    for (int ni = 0; ni < 4; ni++) {
      int r = nbase + ni * 16 + ln;
      bb[ni] = *(const bf16x8*)&Bs[r * 128 + ((g ^ ln) << 3)];
    }
    #pragma unroll
    for (int mi = 0; mi < 2; mi++)
      #pragma unroll
      for (int ni = 0; ni < 4; ni++)
        acc[mi][ni] = __builtin_amdgcn_mfma_f32_16x16x32_bf16(a[mi], bb[ni], acc[mi][ni], 0, 0, 0);
  }
  #pragma unroll
  for (int mi = 0; mi < 2; mi++) {
    int gm0 = row0 + mbase + mi * 16 + quad * 4;
    #pragma unroll
    for (int ni = 0; ni < 4; ni++) {
      int gn = col0 + nbase + ni * 16 + ln;
      #pragma unroll
      for (int r = 0; r < 4; r++) {
        int gm = gm0 + r;
        if (gm < M) Cp[(size_t)gm * 256 + gn] = f2b(acc[mi][ni][r]);
      }
    }
  }
}

// ---------------------------------------------------------------------------
// elr: el/er = h_b (bf16) @ folded fp32 weights. p = p0 + blockIdx.y.
// ---------------------------------------------------------------------------
__global__ __launch_bounds__(256) void elr_kernel(
    const unsigned short* __restrict__ h_b, const float* __restrict__ wl,
    const float* __restrict__ wr, float* __restrict__ el,
    float* __restrict__ er, int N, int p0, size_t estride) {
  __shared__ float wls[128 * 8], wrs[128 * 8];
  int pl = blockIdx.y;
  const float* wlp = wl + (size_t)(p0 + pl) * 1024;
  const float* wrp = wr + (size_t)(p0 + pl) * 1024;
  float* elp = el + (size_t)pl * estride;
  float* erp = er + (size_t)pl * estride;
  for (int i = threadIdx.x; i < 1024; i += 256) { wls[i] = wlp[i]; wrs[i] = wrp[i]; }
  __syncthreads();
  int n = blockIdx.x * 256 + threadIdx.x;
  if (n >= N) return;
  float accl[8] = {}, accr[8] = {};
  for (int kk = 0; kk < 16; kk++) {          // 8 bf16 per step
    uint4 raw = *(const uint4*)(h_b + (size_t)n * 128 + kk * 8);
    unsigned uu[4] = {raw.x, raw.y, raw.z, raw.w};
    #pragma unroll
    for (int q = 0; q < 4; q++) {
      float v0 = __builtin_bit_cast(float, uu[q] << 16);
      float v1 = __builtin_bit_cast(float, uu[q] & 0xffff0000u);
      int k = kk * 8 + q * 2;
      #pragma unroll
      for (int hh = 0; hh < 8; hh++) {
        accl[hh] += v0 * wls[k * 8 + hh] + v1 * wls[(k + 1) * 8 + hh];
        accr[hh] += v0 * wrs[k * 8 + hh] + v1 * wrs[(k + 1) * 8 + hh];
      }
    }
  }
  *(float4*)(elp + (size_t)n * 8)     = make_float4(accl[0], accl[1], accl[2], accl[3]);
  *(float4*)(elp + (size_t)n * 8 + 4) = make_float4(accl[4], accl[5], accl[6], accl[7]);
  *(float4*)(erp + (size_t)n * 8)     = make_float4(accr[0], accr[1], accr[2], accr[3]);
  *(float4*)(erp + (size_t)n * 8 + 4) = make_float4(accr[4], accr[5], accr[6], accr[7]);
}

// ---------------------------------------------------------------------------
// agg: one wave per dst node, edge loop UNROLLED x8 (+x4+tail) for MLP.
// out=(sum w*hp)/(sum w)+bias, ELU -> bf16.
// ---------------------------------------------------------------------------
__global__ __launch_bounds__(256) void agg_kernel(
    const unsigned short* __restrict__ hp_b, const float* __restrict__ el,
    const float* __restrict__ er, const unsigned short* __restrict__ csr,
    const int* __restrict__ off, const float* __restrict__ bias,
    unsigned short* __restrict__ emb_b, int N, int p0,
    size_t hstride, size_t estride, size_t embstride) {
  int pl = blockIdx.y;
  int p = p0 + pl;
  const unsigned short* hp = hp_b + (size_t)pl * hstride;
  const float* elp = el + (size_t)pl * estride;
  const float* erp = er + (size_t)pl * estride;
  const unsigned short* csrp = csr + (size_t)p * EE;
  const int* offp = off + (size_t)p * (NN + 1);
  const float* bp = bias + (size_t)p * HF;
  unsigned short* embp = emb_b + (size_t)pl * embstride;
  int n = blockIdx.x * 4 + (threadIdx.x >> 6);
  if (n >= N) return;
  int lane = threadIdx.x & 63;
  int h = lane >> 3;
  int e0 = offp[n], e1 = offp[n + 1];
  float erh = erp[n * NH + h];
  float den = 0.f, a0 = 0.f, a1 = 0.f, a2 = 0.f, a3 = 0.f;
  int e = e0;
  for (; e + 8 <= e1; e += 8) {
    int s[8];
    #pragma unroll
    for (int j = 0; j < 8; j++) s[j] = csrp[e + j];
    float x[8];
    #pragma unroll
    for (int j = 0; j < 8; j++) x[j] = elp[s[j] * NH + h];
    ushort4 hv[8];
    #pragma unroll
    for (int j = 0; j < 8; j++)
      hv[j] = *(const ushort4*)(hp + (size_t)s[j] * HF + lane * 4);
    float w[8];
    #pragma unroll
    for (int j = 0; j < 8; j++) {
      float xx = x[j] + erh;
      xx = fmaxf(xx, 0.2f * xx);          // leaky relu
      w[j] = fexp(xx);
    }
    den += ((w[0] + w[1]) + (w[2] + w[3])) + ((w[4] + w[5]) + (w[6] + w[7]));
    a0 += ((w[0] * b2f(hv[0].x) + w[1] * b2f(hv[1].x)) + (w[2] * b2f(hv[2].x) + w[3] * b2f(hv[3].x)))
        + ((w[4] * b2f(hv[4].x) + w[5] * b2f(hv[5].x)) + (w[6] * b2f(hv[6].x) + w[7] * b2f(hv[7].x)));
    a1 += ((w[0] * b2f(hv[0].y) + w[1] * b2f(hv[1].y)) + (w[2] * b2f(hv[2].y) + w[3] * b2f(hv[3].y)))
        + ((w[4] * b2f(hv[4].y) + w[5] * b2f(hv[5].y)) + (w[6] * b2f(hv[6].y) + w[7] * b2f(hv[7].y)));
    a2 += ((w[0] * b2f(hv[0].z) + w[1] * b2f(hv[1].z)) + (w[2] * b2f(hv[2].z) + w[3] * b2f(hv[3].z)))
        + ((w[4] * b2f(hv[4].z) + w[5] * b2f(hv[5].z)) + (w[6] * b2f(hv[6].z) + w[7] * b2f(hv[7].z)));
    a3 += ((w[0] * b2f(hv[0].w) + w[1] * b2f(hv[1].w)) + (w[2] * b2f(hv[2].w) + w[3] * b2f(hv[3].w)))
        + ((w[4] * b2f(hv[4].w) + w[5] * b2f(hv[5].w)) + (w[6] * b2f(hv[6].w) + w[7] * b2f(hv[7].w)));
  }
  if (e + 4 <= e1) {
    int s0 = csrp[e], s1 = csrp[e + 1], s2 = csrp[e + 2], s3 = csrp[e + 3];
    float x0 = elp[s0 * NH + h] + erh;
    float x1 = elp[s1 * NH + h] + erh;
    float x2 = elp[s2 * NH + h] + erh;
    float x3 = elp[s3 * NH + h] + erh;
    ushort4 h0 = *(const ushort4*)(hp + (size_t)s0 * HF + lane * 4);
    ushort4 h1 = *(const ushort4*)(hp + (size_t)s1 * HF + lane * 4);
    ushort4 h2 = *(const ushort4*)(hp + (size_t)s2 * HF + lane * 4);
    ushort4 h3 = *(const ushort4*)(hp + (size_t)s3 * HF + lane * 4);
    x0 = fmaxf(x0, 0.2f * x0); x1 = fmaxf(x1, 0.2f * x1);
    x2 = fmaxf(x2, 0.2f * x2); x3 = fmaxf(x3, 0.2f * x3);
    float w0 = fexp(x0), w1 = fexp(x1), w2 = fexp(x2), w3 = fexp(x3);
    den += (w0 + w1) + (w2 + w3);
    a0 += (w0 * b2f(h0.x) + w1 * b2f(h1.x)) + (w2 * b2f(h2.x) + w3 * b2f(h3.x));
    a1 += (w0 * b2f(h0.y) + w1 * b2f(h1.y)) + (w2 * b2f(h2.y) + w3 * b2f(h3.y));
    a2 += (w0 * b2f(h0.z) + w1 * b2f(h1.z)) + (w2 * b2f(h2.z) + w3 * b2f(h3.z));
    a3 += (w0 * b2f(h0.w) + w1 * b2f(h1.w)) + (w2 * b2f(h2.w) + w3 * b2f(h3.w));
    e += 4;
  }
  for (; e < e1; e++) {
    int s = csrp[e];
    float x = elp[s * NH + h] + erh;
    x = fmaxf(x, 0.2f * x);
    float w = fexp(x);
    den += w;
    ushort4 hv = *(const ushort4*)(hp + (size_t)s * HF + lane * 4);
    a0 += w * b2f(hv.x); a1 += w * b2f(hv.y);
    a2 += w * b2f(hv.z); a3 += w * b2f(hv.w);
  }
  float inv = (den > 0.f) ? 1.f / den : 0.f;
  float4 bv = *(const float4*)(bp + lane * 4);
  float o0 = a0 * inv + bv.x, o1 = a1 * inv + bv.y;
  float o2 = a2 * inv + bv.z, o3 = a3 * inv + bv.w;
  o0 = (o0 > 0.f) ? o0 : fexp(o0) - 1.f;
  o1 = (o1 > 0.f) ? o1 : fexp(o1) - 1.f;
  o2 = (o2 > 0.f) ? o2 : fexp(o2) - 1.f;
  o3 = (o3 > 0.f) ? o3 : fexp(o3) - 1.f;
  ushort4 ov;
  ov.x = f2b(o0); ov.y = f2b(o1); ov.z = f2b(o2); ov.w = f2b(o3);
  *(ushort4*)(embp + (size_t)n * HF + lane * 4) = ov;
}

// ---------------------------------------------------------------------------
// GEMM2 + semantic epilogue: wpart[p][bx] = block-sum of tanh(emb@W1+b1).W2
// ---------------------------------------------------------------------------
__global__ __launch_bounds__(256) void gemm2_kernel(
    const unsigned short* __restrict__ A, const unsigned short* __restrict__ Bt,
    const float* __restrict__ b1, const float* __restrict__ W2,
    float* __restrict__ wpart, int M, int p0, size_t astride) {
  __shared__ unsigned short As[64 * 128];
  __shared__ unsigned short Bs[128 * 128];
  __shared__ float wred[4];
  int tid = threadIdx.x;
  int pl = blockIdx.y;
  const unsigned short* Ap = A + (size_t)pl * astride;
  int row0 = blockIdx.x * 64;
  int wave = tid >> 6, lane = tid & 63;
  int ln = lane & 15, quad = lane >> 4;
  int mbase = (wave >> 1) * 32, nbase = (wave & 1) * 64;
  f32x4 acc[2][4] = {};
  for (int kc = 0; kc < 2; kc++) {
    #pragma unroll
    for (int i = 0; i < 4; i++) {
      int c = i * 256 + tid;
      int row = c >> 4, g = c & 15;
      int grow = row0 + row;
      uint4 v = make_uint4(0, 0, 0, 0);
      if (grow < M) v = *(const uint4*)(Ap + (size_t)grow * 256 + kc * 128 + g * 8);
      *(uint4*)&As[row * 128 + ((g ^ (row & 15)) << 3)] = v;
    }
    #pragma unroll
    for (int i = 0; i < 8; i++) {
      int c = i * 256 + tid;
      int row = c >> 4, g = c & 15;
      uint4 v = *(const uint4*)(Bt + (size_t)row * 256 + kc * 128 + g * 8);
      *(uint4*)&Bs[row * 128 + ((g ^ (row & 15)) << 3)] = v;
    }
    __syncthreads();
    #pragma unroll
    for (int ks = 0; ks < 4; ks++) {
      int g = ks * 4 + quad;
      bf16x8 a[2], bb[4];
      #pragma unroll
      for (int mi = 0; mi < 2; mi++) {
        int r = mbase + mi * 16 + ln;
        a[mi] = *(const bf16x8*)&As[r * 128 + ((g ^ ln) << 3)];
      }
      #pragma unroll
      for (int ni = 0; ni < 4; ni++) {
        int r = nbase + ni * 16 + ln;
        bb[ni] = *(const bf16x8*)&Bs[r * 128 + ((g ^ ln) << 3)];
      }
      #pragma unroll
      for (int mi = 0; mi < 2; mi++)
        #pragma unroll
        for (int ni = 0; ni < 4; ni++)
          acc[mi][ni] = __builtin_amdgcn_mfma_f32_16x16x32_bf16(a[mi], bb[ni], acc[mi][ni], 0, 0, 0);
    }
    __syncthreads();
  }
  float b1v[4], w2v[4];
  #pragma unroll
  for (int ni = 0; ni < 4; ni++) {
    int col = nbase + ni * 16 + ln;
    b1v[ni] = b1[col]; w2v[ni] = W2[col];
  }
  float s = 0.f;
  #pragma unroll
  for (int mi = 0; mi < 2; mi++) {
    int gm0 = row0 + mbase + mi * 16 + quad * 4;
    #pragma unroll
    for (int r = 0; r < 4; r++) {
      if (gm0 + r < M) {
        #pragma unroll
        for (int ni = 0; ni < 4; ni++)
          s += ftanh(acc[mi][ni][r] + b1v[ni]) * w2v[ni];
      }
    }
  }
  #pragma unroll
  for (int o = 32; o > 0; o >>= 1) s += __shfl_down(s, o);
  if (lane == 0) wred[wave] = s;
  __syncthreads();
  if (tid == 0)
    wpart[(size_t)(p0 + pl) * NBG2 + blockIdx.x] =
        (wred[0] + wred[1]) + (wred[2] + wred[3]);
}

// ---------------------------------------------------------------------------
// pool: one block per (graph, path); register accumulation, no atomics.
// ---------------------------------------------------------------------------
__global__ __launch_bounds__(256) void pool_kernel(
    const unsigned short* __restrict__ emb, const int* __restrict__ glist,
    const int* __restrict__ gcnt2, float* __restrict__ pool,
    int p0, size_t embstride) {
  __shared__ int nl[GCAP];
  __shared__ float sm[4][64][4];
  int b = blockIdx.x, pl = blockIdx.y;
  const unsigned short* embp = emb + (size_t)pl * embstride;
  int tid = threadIdx.x;
  int cnt = min(gcnt2[b], GCAP);
  for (int i = tid; i < cnt; i += 256) nl[i] = glist[b * GCAP + i];
  __syncthreads();
  int sub = tid >> 6, lane = tid & 63;
  float a0 = 0.f, a1 = 0.f, a2 = 0.f, a3 = 0.f;
  for (int i = sub; i < cnt; i += 4) {
    ushort4 v = *(const ushort4*)(embp + (size_t)nl[i] * HF + lane * 4);
    a0 += b2f(v.x); a1 += b2f(v.y); a2 += b2f(v.z); a3 += b2f(v.w);
  }
  sm[sub][lane][0] = a0; sm[sub][lane][1] = a1;
  sm[sub][lane][2] = a2; sm[sub][lane][3] = a3;
  __syncthreads();
  int fl = tid >> 2, j = tid & 3;
  float s = sm[0][fl][j] + sm[1][fl][j] + sm[2][fl][j] + sm[3][fl][j];
  pool[((size_t)(p0 + pl) * BG + b) * HF + tid] = s;
}

// ---------------------------------------------------------------------------
// final: reduce wpart -> beta softmax; counts from gcnt2; logits + pooled out
// ---------------------------------------------------------------------------
__global__ __launch_bounds__(256) void final_kernel(
    const float* __restrict__ pool, const float* __restrict__ wpart,
    const int* __restrict__ gcnt2, const float* __restrict__ clsW,
    const float* __restrict__ clsb, float* __restrict__ out, int N) {
  int b = blockIdx.x;
  int f = threadIdx.x;
  __shared__ float red[256];
  float wm[PM];
  #pragma unroll
  for (int p = 0; p < PM; p++) {
    float s = 0.f;
    for (int i = f; i < NBG2; i += 256) s += wpart[(size_t)p * NBG2 + i];
    red[f] = s;
    __syncthreads();
    for (int st = 128; st > 0; st >>= 1) {
      if (f < st) red[f] += red[f + st];
      __syncthreads();
    }
    wm[p] = red[0] / (float)N;
    __syncthreads();
  }
  float c = fmaxf((float)gcnt2[b], 1.f);
  float mx = -1e30f;
  #pragma unroll
  for (int p = 0; p < PM; p++) mx = fmaxf(mx, wm[p]);
  float es = 0.f, e[PM];
  #pragma unroll
  for (int p = 0; p < PM; p++) { e[p] = expf(wm[p] - mx); es += e[p]; }
  float v = 0.f;
  #pragma unroll
  for (int p = 0; p < PM; p++)
    v += (e[p] / es) * pool[((size_t)p * BG + b) * HF + f];
  v /= c;
  out[256 + (size_t)b * HF + f] = v;
  __shared__ float sm[256];
  sm[f] = v * clsW[f * 2 + 0];
  __syncthreads();
  for (int st = 128; st > 0; st >>= 1) {
    if (f < st) sm[f] += sm[f + st];
    __syncthreads();
  }
  float l0 = sm[0];
  __syncthreads();
  sm[f] = v * clsW[f * 2 + 1];
  __syncthreads();
  for (int st = 128; st > 0; st >>= 1) {
    if (f < st) sm[f] += sm[f + st];
    __syncthreads();
  }
  if (f == 0) {
    out[b * 2 + 0] = l0 + clsb[0];
    out[b * 2 + 1] = sm[0] + clsb[1];
  }
}

// ---------------------------------------------------------------------------
extern "C" void kernel_launch(void* const* d_in, const int* in_sizes, int n_in,
                              void* d_out, int out_size, void* d_ws, size_t ws_size,
                              hipStream_t stream) {
  const float* h      = (const float*)d_in[0];
  const float* Wg     = (const float*)d_in[1];
  const float* attn_l = (const float*)d_in[2];
  const float* attn_r = (const float*)d_in[3];
  const float* gatb   = (const float*)d_in[4];
  const float* semW1  = (const float*)d_in[5];
  const float* semb1  = (const float*)d_in[6];
  const float* semW2  = (const float*)d_in[7];
  const float* clsW   = (const float*)d_in[8];
  const float* clsb   = (const float*)d_in[9];
  const int*   src    = (const int*)d_in[10];
  const int*   dst    = (const int*)d_in[11];
  const int*   gid    = (const int*)d_in[12];
  float* out = (float*)d_out;

  auto layout_size = [](int PMg) -> size_t {
    size_t o = 0;
    auto alloc = [&](size_t bytes) { o += (bytes + 255) & ~(size_t)255; };
    alloc((size_t)NN * INF_ * 2);              // h_b
    alloc((size_t)PMg * NN * HF * 2);          // hp_b
    alloc((size_t)PMg * NN * HF * 2);          // emb_b
    alloc((size_t)PM * HF * INF_ * 2);         // Wb_t
    alloc((size_t)HS * HF * 2);                // W1_t
    alloc((size_t)PM * INF_ * NH * 4);         // wl
    alloc((size_t)PM * INF_ * NH * 4);         // wr
    alloc((size_t)PMg * NN * NH * 4);          // el
    alloc((size_t)PMg * NN * NH * 4);          // er
    alloc((size_t)PM * NB2 * BCAP * 4);        // bdata
    alloc((size_t)PM * NB2 * 4);               // gcnt
    alloc((size_t)BG * GCAP * 4);              // glist
    alloc((size_t)BG * 4);                     // gcnt2
    alloc((size_t)PM * (NN + 1) * 4);          // off
    alloc((size_t)PM * EE * 2);                // csr
    alloc((size_t)PM * BG * HF * 4);           // pool
    alloc((size_t)PM * NBG2 * 4);              // wpart
    return o;
  };
  int PMg = (layout_size(4) <= ws_size) ? 4 : 1;

  char* ws = (char*)d_ws;
  size_t o = 0;
  auto alloc = [&](size_t bytes) { size_t r = o; o += (bytes + 255) & ~(size_t)255; return r; };
  unsigned short* h_b   = (unsigned short*)(ws + alloc((size_t)NN * INF_ * 2));
  unsigned short* hp_b  = (unsigned short*)(ws + alloc((size_t)PMg * NN * HF * 2));
  unsigned short* emb_b = (unsigned short*)(ws + alloc((size_t)PMg * NN * HF * 2));
  unsigned short* Wb_t  = (unsigned short*)(ws + alloc((size_t)PM * HF * INF_ * 2));
  unsigned short* W1_t  = (unsigned short*)(ws + alloc((size_t)HS * HF * 2));
  float* wl    = (float*)(ws + alloc((size_t)PM * INF_ * NH * 4));
  float* wr    = (float*)(ws + alloc((size_t)PM * INF_ * NH * 4));
  float* el    = (float*)(ws + alloc((size_t)PMg * NN * NH * 4));
  float* er    = (float*)(ws + alloc((size_t)PMg * NN * NH * 4));
  unsigned* bdata = (unsigned*)(ws + alloc((size_t)PM * NB2 * BCAP * 4));
  int*   gcnt  = (int*)(ws + alloc((size_t)PM * NB2 * 4));
  int*   glist = (int*)(ws + alloc((size_t)BG * GCAP * 4));
  int*   gcnt2 = (int*)(ws + alloc((size_t)BG * 4));
  int*   off   = (int*)(ws + alloc((size_t)PM * (NN + 1) * 4));
  unsigned short* csr = (unsigned short*)(ws + alloc((size_t)PM * EE * 2));
  float* pool  = (float*)(ws + alloc((size_t)PM * BG * HF * 4));
  float* wpart = (float*)(ws + alloc((size_t)PM * NBG2 * 4));

  const size_t hpS  = (PMg == 4) ? (size_t)NN * HF : 0;
  const size_t embS = hpS;
  const size_t elS  = (PMg == 4) ? (size_t)NN * NH : 0;

  prep_kernel<<<1 + 6250 + 512 + 128 + 16, 256, 0, stream>>>(
      h, Wg, semW1, attn_l, attn_r, h_b, Wb_t, W1_t, wl, wr, gcnt, gcnt2);
  bucket_kernel<<<dim3((EE + BCH - 1) / BCH, PM), 256, 0, stream>>>(src, dst, bdata, gcnt);
  gbucket_kernel<<<(NN + BCH - 1) / BCH, 256, 0, stream>>>(gid, glist, gcnt2);
  csrify_kernel<<<dim3(NB2, PM), 256, 0, stream>>>(bdata, gcnt, off, csr);

  if (PMg == 4) {
    gemm1_kernel<<<dim3((NN + 63) / 64, 2, 4), 256, 0, stream>>>(h_b, Wb_t, hp_b, NN, 0, hpS);
    elr_kernel<<<dim3((NN + 255) / 256, 4), 256, 0, stream>>>(h_b, wl, wr, el, er, NN, 0, elS);
    agg_kernel<<<dim3((NN + 3) / 4, 4), 256, 0, stream>>>(
        hp_b, el, er, csr, off, gatb, emb_b, NN, 0, hpS, elS, embS);
    gemm2_kernel<<<dim3(NBG2, 4), 256, 0, stream>>>(
        emb_b, W1_t, semb1, semW2, wpart, NN, 0, embS);
    pool_kernel<<<dim3(BG, 4), 256, 0, stream>>>(emb_b, glist, gcnt2, pool, 0, embS);
  } else {
    for (int p = 0; p < PM; p++) {
      gemm1_kernel<<<dim3((NN + 63) / 64, 2, 1), 256, 0, stream>>>(h_b, Wb_t, hp_b, NN, p, 0);
      elr_kernel<<<dim3((NN + 255) / 256, 1), 256, 0, stream>>>(h_b, wl, wr, el, er, NN, p, 0);
      agg_kernel<<<dim3((NN + 3) / 4, 1), 256, 0, stream>>>(
          hp_b, el, er, csr, off, gatb, emb_b, NN, p, 0, 0, 0);
      gemm2_kernel<<<dim3(NBG2, 1), 256, 0, stream>>>(
          emb_b, W1_t, semb1, semW2, wpart, NN, p, 0);
      pool_kernel<<<dim3(BG, 1), 256, 0, stream>>>(emb_b, glist, gcnt2, pool, p, 0);
    }
  }

  final_kernel<<<BG, 256, 0, stream>>>(pool, wpart, gcnt2, clsW, clsb, out, NN);
}

// Round 12
// 432.255 us; speedup vs baseline: 2.1381x; 1.0577x over previous
//
#include <hip/hip_runtime.h>

#define NN 50000
#define PM 4
#define EE 500000
#define INF_ 128
#define NH 8
#define FF 32
#define HF 256
#define HS 128
#define BG 128
#define OUTC 2

#define NB2 98        // buckets per path: dst>>9 (512 nodes/bucket)
#define BCAP 6144     // bucket capacity (mean 5102, sd ~71 -> 14 sigma slack)
#define BCH 4096      // edges per workgroup in bucket pass
#define NBB 123       // bucket blocks per path = ceil(EE/BCH)
#define NGB 13        // gbucket blocks = ceil(NN/BCH)
#define GCAP 576      // nodes per graph capacity (mean 390, sd ~20 -> 9 sigma)
#define NBG1 782      // gemm1/gemm2 row-blocks = ceil(NN/64)
#define NBE 196       // elr blocks per path = ceil(NN/256)
#define NBG2 782

typedef __attribute__((ext_vector_type(8))) short bf16x8;
typedef __attribute__((ext_vector_type(4))) float f32x4;

__device__ __forceinline__ float b2f(unsigned short x) {
  unsigned u = ((unsigned)x) << 16;
  return __builtin_bit_cast(float, u);
}
__device__ __forceinline__ unsigned short f2b(float f) {
  unsigned u = __builtin_bit_cast(unsigned, f);
  u += 0x7fff + ((u >> 16) & 1);   // RNE
  return (unsigned short)(u >> 16);
}
__device__ __forceinline__ float fexp(float x) { return __expf(x); }
__device__ __forceinline__ float ftanh(float x) {
  float t = __expf(-2.f * fabsf(x));
  float r = (1.f - t) / (1.f + t);
  return copysignf(r, x);
}

// ---------------------------------------------------------------------------
// prep: zero gcnt/gcnt2 + h->bf16 + Wg transpose + W1 transpose + fold
// ---------------------------------------------------------------------------
__global__ __launch_bounds__(256) void prep_kernel(
    const float* __restrict__ h, const float* __restrict__ Wg,
    const float* __restrict__ W1, const float* __restrict__ al,
    const float* __restrict__ ar,
    unsigned short* __restrict__ h_b, unsigned short* __restrict__ Wb_t,
    unsigned short* __restrict__ W1_t, float* __restrict__ wl,
    float* __restrict__ wr, int* __restrict__ gcnt, int* __restrict__ gcnt2) {
  int b = blockIdx.x;
  int tid = threadIdx.x;
  if (b < 1) {
    for (int i = tid; i < PM * NB2; i += 256) gcnt[i] = 0;
    if (tid < BG) gcnt2[tid] = 0;
    return;
  }
  b -= 1;
  if (b < 6250) {
    int t = b * 256 + tid;
    float4 v = *(const float4*)(h + (size_t)t * 4);
    ushort4 o;
    o.x = f2b(v.x); o.y = f2b(v.y); o.z = f2b(v.z); o.w = f2b(v.w);
    *(ushort4*)(h_b + (size_t)t * 4) = o;
    return;
  }
  b -= 6250;
  if (b < 512) {
    int t = b * 256 + tid;
    int p = t >> 15, rem = t & 32767;
    int n = rem >> 7, k = rem & 127;
    Wb_t[(size_t)p * 32768 + n * 128 + k] = f2b(Wg[(size_t)p * 32768 + k * 256 + n]);
    return;
  }
  b -= 512;
  if (b < 128) {
    int t = b * 256 + tid;
    int n = t >> 8, k = t & 255;
    W1_t[n * 256 + k] = f2b(W1[k * 128 + n]);
    return;
  }
  b -= 128;
  {
    int t = b * 256 + tid;
    int p = t >> 10, rem = t & 1023;
    int k = rem >> 3, hh = rem & 7;
    const float* wrow = Wg + (size_t)p * 32768 + k * 256 + hh * 32;
    const float* alp = al + p * 256 + hh * 32;
    const float* arp = ar + p * 256 + hh * 32;
    float sl = 0.f, sr = 0.f;
    #pragma unroll
    for (int f = 0; f < 32; f++) { sl += wrow[f] * alp[f]; sr += wrow[f] * arp[f]; }
    wl[t] = sl; wr[t] = sr;
  }
}

// ---------------------------------------------------------------------------
// bg: bucket (edges by dst>>9) + gbucket (nodes by graph) in one dispatch
// ---------------------------------------------------------------------------
__global__ __launch_bounds__(256) void bg_kernel(
    const int* __restrict__ src, const int* __restrict__ dst,
    unsigned* __restrict__ bdata, int* __restrict__ gcnt,
    const int* __restrict__ gid, int* __restrict__ glist,
    int* __restrict__ gcnt2) {
  __shared__ __align__(16) char smem[18432];
  int b = blockIdx.x;
  int tid = threadIdx.x;
  if (b < NBB * PM) {
    unsigned* ed = (unsigned*)smem;
    int* hist  = (int*)(smem + BCH * 4);
    int* gbase = hist + NB2;
    int* cur   = gbase + NB2;
    int p = b / NBB, blk = b % NBB;
    int e0 = blk * BCH;
    int n = min(BCH, EE - e0);
    if (tid < NB2) hist[tid] = 0;
    __syncthreads();
    const int* sp = src + (size_t)p * EE + e0;
    const int* dp = dst + (size_t)p * EE + e0;
    for (int i = tid; i < n; i += 256) {
      int s = sp[i], d = dp[i];
      ed[i] = ((unsigned)d << 16) | (unsigned)s;
      atomicAdd(&hist[d >> 9], 1);
    }
    __syncthreads();
    if (tid < NB2) {
      gbase[tid] = atomicAdd(&gcnt[p * NB2 + tid], hist[tid]);
      cur[tid] = 0;
    }
    __syncthreads();
    for (int i = tid; i < n; i += 256) {
      unsigned pk = ed[i];
      int bk = pk >> 25;
      int slot = gbase[bk] + atomicAdd(&cur[bk], 1);
      if (slot < BCAP)
        bdata[((size_t)(p * NB2 + bk)) * BCAP + slot] = pk;
    }
  } else {
    int* gl    = (int*)smem;
    int* hist  = (int*)(smem + BCH * 4);
    int* gbase = hist + BG;
    int* cur   = gbase + BG;
    int blk = b - NBB * PM;
    int e0 = blk * BCH;
    int n = min(BCH, NN - e0);
    if (tid < BG) hist[tid] = 0;
    __syncthreads();
    for (int i = tid; i < n; i += 256) {
      int g = gid[e0 + i];
      gl[i] = g;
      atomicAdd(&hist[g], 1);
    }
    __syncthreads();
    if (tid < BG) {
      gbase[tid] = atomicAdd(&gcnt2[tid], hist[tid]);
      cur[tid] = 0;
    }
    __syncthreads();
    for (int i = tid; i < n; i += 256) {
      int g = gl[i];
      int slot = gbase[g] + atomicAdd(&cur[g], 1);
      if (slot < GCAP) glist[g * GCAP + slot] = e0 + i;
    }
  }
}

// ---------------------------------------------------------------------------
// csrify: per (bucket,path): 512-node local CSR in LDS -> global off/csr
// ---------------------------------------------------------------------------
__global__ __launch_bounds__(256) void csrify_kernel(
    const unsigned* __restrict__ bdata, const int* __restrict__ gcnt,
    int* __restrict__ off, unsigned short* __restrict__ csr) {
  __shared__ unsigned ebuf[BCAP];
  __shared__ int gc[NB2];
  __shared__ int degc[512];
  __shared__ int loff[513];
  __shared__ int tmp[256];
  __shared__ int base_s;
  int b = blockIdx.x, p = blockIdx.y;
  int tid = threadIdx.x;
  if (tid < NB2) gc[tid] = min(gcnt[p * NB2 + tid], BCAP);
  __syncthreads();
  if (tid == 0) {
    int s = 0;
    for (int i = 0; i < b; i++) s += gc[i];
    base_s = s;
  }
  int cnt = gc[b];
  const unsigned* bp = bdata + ((size_t)(p * NB2 + b)) * BCAP;
  for (int i = tid; i < cnt; i += 256) ebuf[i] = bp[i];
  degc[tid] = 0; degc[256 + tid] = 0;
  __syncthreads();
  for (int i = tid; i < cnt; i += 256)
    atomicAdd(&degc[(ebuf[i] >> 16) & 511], 1);
  __syncthreads();
  int d0 = degc[2 * tid], d1 = degc[2 * tid + 1];
  tmp[tid] = d0 + d1;
  __syncthreads();
  for (int o = 1; o < 256; o <<= 1) {
    int v = (tid >= o) ? tmp[tid - o] : 0;
    __syncthreads();
    tmp[tid] += v;
    __syncthreads();
  }
  int bse = tmp[tid] - d0 - d1;
  loff[2 * tid] = bse; loff[2 * tid + 1] = bse + d0;
  if (tid == 255) loff[512] = tmp[255];
  __syncthreads();
  int base = base_s;
  for (int dl = tid; dl < 512; dl += 256) {
    int n = b * 512 + dl;
    if (n <= NN) off[(size_t)p * (NN + 1) + n] = base + loff[dl];
  }
  degc[tid] = 0; degc[256 + tid] = 0;
  __syncthreads();
  for (int i = tid; i < cnt; i += 256) {
    unsigned pk = ebuf[i];
    int dl = (pk >> 16) & 511;
    int slot = loff[dl] + atomicAdd(&degc[dl], 1);
    csr[(size_t)p * EE + base + slot] = (unsigned short)(pk & 0xffff);
  }
}

// ---------------------------------------------------------------------------
// g1elr: gemm1 (multi-path, A staged+frag-cached once, loop B over paths)
//        + elr section. One dispatch.
// ---------------------------------------------------------------------------
__global__ __launch_bounds__(256) void g1elr_kernel(
    const unsigned short* __restrict__ hA, const unsigned short* __restrict__ Bt,
    unsigned short* __restrict__ Cb, const float* __restrict__ wl,
    const float* __restrict__ wr, float* __restrict__ el, float* __restrict__ er,
    int M, int p0, int npaths, size_t cstride, size_t estride) {
  __shared__ __align__(16) char smem[49152];
  int b = blockIdx.x;
  int tid = threadIdx.x;
  int nb1 = NBG1 * 2;
  if (b < nb1) {
    unsigned short* As = (unsigned short*)smem;            // 64x128 = 16 KB
    unsigned short* Bs = (unsigned short*)(smem + 16384);  // 128x128 = 32 KB
    int row0 = (b >> 1) * 64, col0 = (b & 1) * 128;
    // stage A once
    #pragma unroll
    for (int i = 0; i < 4; i++) {
      int c = i * 256 + tid;
      int row = c >> 4, g = c & 15;
      int grow = row0 + row;
      uint4 v = make_uint4(0, 0, 0, 0);
      if (grow < M) v = *(const uint4*)(hA + (size_t)grow * 128 + g * 8);
      *(uint4*)&As[row * 128 + ((g ^ (row & 15)) << 3)] = v;
    }
    int wave = tid >> 6, lane = tid & 63;
    int ln = lane & 15, quad = lane >> 4;
    int mbase = (wave >> 1) * 32, nbase = (wave & 1) * 64;
    bf16x8 afr[4][2];
    bool afr_ok = false;
    for (int pl = 0; pl < npaths; pl++) {
      const unsigned short* Bp = Bt + (size_t)(p0 + pl) * 32768;
      #pragma unroll
      for (int i = 0; i < 8; i++) {
        int c = i * 256 + tid;
        int row = c >> 4, g = c & 15;
        uint4 v = *(const uint4*)(Bp + (size_t)(col0 + row) * 128 + g * 8);
        *(uint4*)&Bs[row * 128 + ((g ^ (row & 15)) << 3)] = v;
      }
      __syncthreads();
      if (!afr_ok) {           // cache A fragments in registers (once)
        #pragma unroll
        for (int ks = 0; ks < 4; ks++) {
          int g = ks * 4 + quad;
          #pragma unroll
          for (int mi = 0; mi < 2; mi++) {
            int r = mbase + mi * 16 + ln;
            afr[ks][mi] = *(const bf16x8*)&As[r * 128 + ((g ^ ln) << 3)];
          }
        }
        afr_ok = true;
      }
      f32x4 acc[2][4] = {};
      #pragma unroll
      for (int ks = 0; ks < 4; ks++) {
        int g = ks * 4 + quad;
        bf16x8 bb[4];
        #pragma unroll
        for (int ni = 0; ni < 4; ni++) {
          int r = nbase + ni * 16 + ln;
          bb[ni] = *(const bf16x8*)&Bs[r * 128 + ((g ^ ln) << 3)];
        }
        #pragma unroll
        for (int mi = 0; mi < 2; mi++)
          #pragma unroll
          for (int ni = 0; ni < 4; ni++)
            acc[mi][ni] = __builtin_amdgcn_mfma_f32_16x16x32_bf16(afr[ks][mi], bb[ni], acc[mi][ni], 0, 0, 0);
      }
      unsigned short* Cp = Cb + (size_t)pl * cstride;
      #pragma unroll
      for (int mi = 0; mi < 2; mi++) {
        int gm0 = row0 + mbase + mi * 16 + quad * 4;
        #pragma unroll
        for (int ni = 0; ni < 4; ni++) {
          int gn = col0 + nbase + ni * 16 + ln;
          #pragma unroll
          for (int r = 0; r < 4; r++) {
            int gm = gm0 + r;
            if (gm < M) Cp[(size_t)gm * 256 + gn] = f2b(acc[mi][ni][r]);
          }
        }
      }
      __syncthreads();     // before restaging Bs
    }
  } else {
    float* wls = (float*)smem;
    float* wrs = wls + 1024;
    int t = b - nb1;
    int pl = t / NBE, nblk = t % NBE;
    const float* wlp = wl + (size_t)(p0 + pl) * 1024;
    const float* wrp = wr + (size_t)(p0 + pl) * 1024;
    float* elp = el + (size_t)pl * estride;
    float* erp = er + (size_t)pl * estride;
    for (int i = tid; i < 1024; i += 256) { wls[i] = wlp[i]; wrs[i] = wrp[i]; }
    __syncthreads();
    int n = nblk * 256 + tid;
    if (n >= M) return;
    float accl[8] = {}, accr[8] = {};
    for (int kk = 0; kk < 16; kk++) {
      uint4 raw = *(const uint4*)(hA + (size_t)n * 128 + kk * 8);
      unsigned uu[4] = {raw.x, raw.y, raw.z, raw.w};
      #pragma unroll
      for (int q = 0; q < 4; q++) {
        float v0 = __builtin_bit_cast(float, uu[q] << 16);
        float v1 = __builtin_bit_cast(float, uu[q] & 0xffff0000u);
        int k = kk * 8 + q * 2;
        #pragma unroll
        for (int hh = 0; hh < 8; hh++) {
          accl[hh] += v0 * wls[k * 8 + hh] + v1 * wls[(k + 1) * 8 + hh];
          accr[hh] += v0 * wrs[k * 8 + hh] + v1 * wrs[(k + 1) * 8 + hh];
        }
      }
    }
    *(float4*)(elp + (size_t)n * 8)     = make_float4(accl[0], accl[1], accl[2], accl[3]);
    *(float4*)(elp + (size_t)n * 8 + 4) = make_float4(accl[4], accl[5], accl[6], accl[7]);
    *(float4*)(erp + (size_t)n * 8)     = make_float4(accr[0], accr[1], accr[2], accr[3]);
    *(float4*)(erp + (size_t)n * 8 + 4) = make_float4(accr[4], accr[5], accr[6], accr[7]);
  }
}

// ---------------------------------------------------------------------------
// agg: one wave per dst node, x8-unrolled edge loop (bandwidth-roofline bound)
// ---------------------------------------------------------------------------
__global__ __launch_bounds__(256) void agg_kernel(
    const unsigned short* __restrict__ hp_b, const float* __restrict__ el,
    const float* __restrict__ er, const unsigned short* __restrict__ csr,
    const int* __restrict__ off, const float* __restrict__ bias,
    unsigned short* __restrict__ emb_b, int N, int p0,
    size_t hstride, size_t estride, size_t embstride) {
  int pl = blockIdx.y;
  int p = p0 + pl;
  const unsigned short* hp = hp_b + (size_t)pl * hstride;
  const float* elp = el + (size_t)pl * estride;
  const float* erp = er + (size_t)pl * estride;
  const unsigned short* csrp = csr + (size_t)p * EE;
  const int* offp = off + (size_t)p * (NN + 1);
  const float* bp = bias + (size_t)p * HF;
  unsigned short* embp = emb_b + (size_t)pl * embstride;
  int n = blockIdx.x * 4 + (threadIdx.x >> 6);
  if (n >= N) return;
  int lane = threadIdx.x & 63;
  int h = lane >> 3;
  int e0 = offp[n], e1 = offp[n + 1];
  float erh = erp[n * NH + h];
  float den = 0.f, a0 = 0.f, a1 = 0.f, a2 = 0.f, a3 = 0.f;
  int e = e0;
  for (; e + 8 <= e1; e += 8) {
    int s[8];
    #pragma unroll
    for (int j = 0; j < 8; j++) s[j] = csrp[e + j];
    float x[8];
    #pragma unroll
    for (int j = 0; j < 8; j++) x[j] = elp[s[j] * NH + h];
    ushort4 hv[8];
    #pragma unroll
    for (int j = 0; j < 8; j++)
      hv[j] = *(const ushort4*)(hp + (size_t)s[j] * HF + lane * 4);
    float w[8];
    #pragma unroll
    for (int j = 0; j < 8; j++) {
      float xx = x[j] + erh;
      xx = fmaxf(xx, 0.2f * xx);
      w[j] = fexp(xx);
    }
    den += ((w[0] + w[1]) + (w[2] + w[3])) + ((w[4] + w[5]) + (w[6] + w[7]));
    a0 += ((w[0] * b2f(hv[0].x) + w[1] * b2f(hv[1].x)) + (w[2] * b2f(hv[2].x) + w[3] * b2f(hv[3].x)))
        + ((w[4] * b2f(hv[4].x) + w[5] * b2f(hv[5].x)) + (w[6] * b2f(hv[6].x) + w[7] * b2f(hv[7].x)));
    a1 += ((w[0] * b2f(hv[0].y) + w[1] * b2f(hv[1].y)) + (w[2] * b2f(hv[2].y) + w[3] * b2f(hv[3].y)))
        + ((w[4] * b2f(hv[4].y) + w[5] * b2f(hv[5].y)) + (w[6] * b2f(hv[6].y) + w[7] * b2f(hv[7].y)));
    a2 += ((w[0] * b2f(hv[0].z) + w[1] * b2f(hv[1].z)) + (w[2] * b2f(hv[2].z) + w[3] * b2f(hv[3].z)))
        + ((w[4] * b2f(hv[4].z) + w[5] * b2f(hv[5].z)) + (w[6] * b2f(hv[6].z) + w[7] * b2f(hv[7].z)));
    a3 += ((w[0] * b2f(hv[0].w) + w[1] * b2f(hv[1].w)) + (w[2] * b2f(hv[2].w) + w[3] * b2f(hv[3].w)))
        + ((w[4] * b2f(hv[4].w) + w[5] * b2f(hv[5].w)) + (w[6] * b2f(hv[6].w) + w[7] * b2f(hv[7].w)));
  }
  if (e + 4 <= e1) {
    int s0 = csrp[e], s1 = csrp[e + 1], s2 = csrp[e + 2], s3 = csrp[e + 3];
    float x0 = elp[s0 * NH + h] + erh;
    float x1 = elp[s1 * NH + h] + erh;
    float x2 = elp[s2 * NH + h] + erh;
    float x3 = elp[s3 * NH + h] + erh;
    ushort4 h0 = *(const ushort4*)(hp + (size_t)s0 * HF + lane * 4);
    ushort4 h1 = *(const ushort4*)(hp + (size_t)s1 * HF + lane * 4);
    ushort4 h2 = *(const ushort4*)(hp + (size_t)s2 * HF + lane * 4);
    ushort4 h3 = *(const ushort4*)(hp + (size_t)s3 * HF + lane * 4);
    x0 = fmaxf(x0, 0.2f * x0); x1 = fmaxf(x1, 0.2f * x1);
    x2 = fmaxf(x2, 0.2f * x2); x3 = fmaxf(x3, 0.2f * x3);
    float w0 = fexp(x0), w1 = fexp(x1), w2 = fexp(x2), w3 = fexp(x3);
    den += (w0 + w1) + (w2 + w3);
    a0 += (w0 * b2f(h0.x) + w1 * b2f(h1.x)) + (w2 * b2f(h2.x) + w3 * b2f(h3.x));
    a1 += (w0 * b2f(h0.y) + w1 * b2f(h1.y)) + (w2 * b2f(h2.y) + w3 * b2f(h3.y));
    a2 += (w0 * b2f(h0.z) + w1 * b2f(h1.z)) + (w2 * b2f(h2.z) + w3 * b2f(h3.z));
    a3 += (w0 * b2f(h0.w) + w1 * b2f(h1.w)) + (w2 * b2f(h2.w) + w3 * b2f(h3.w));
    e += 4;
  }
  for (; e < e1; e++) {
    int s = csrp[e];
    float x = elp[s * NH + h] + erh;
    x = fmaxf(x, 0.2f * x);
    float w = fexp(x);
    den += w;
    ushort4 hv = *(const ushort4*)(hp + (size_t)s * HF + lane * 4);
    a0 += w * b2f(hv.x); a1 += w * b2f(hv.y);
    a2 += w * b2f(hv.z); a3 += w * b2f(hv.w);
  }
  float inv = (den > 0.f) ? 1.f / den : 0.f;
  float4 bv = *(const float4*)(bp + lane * 4);
  float o0 = a0 * inv + bv.x, o1 = a1 * inv + bv.y;
  float o2 = a2 * inv + bv.z, o3 = a3 * inv + bv.w;
  o0 = (o0 > 0.f) ? o0 : fexp(o0) - 1.f;
  o1 = (o1 > 0.f) ? o1 : fexp(o1) - 1.f;
  o2 = (o2 > 0.f) ? o2 : fexp(o2) - 1.f;
  o3 = (o3 > 0.f) ? o3 : fexp(o3) - 1.f;
  ushort4 ov;
  ov.x = f2b(o0); ov.y = f2b(o1); ov.z = f2b(o2); ov.w = f2b(o3);
  *(ushort4*)(embp + (size_t)n * HF + lane * 4) = ov;
}

// ---------------------------------------------------------------------------
// g2pool: gemm2 (tanh epilogue -> wpart, no atomics) + pool section. One
// dispatch; both read emb (co-scheduled for cache sharing).
// ---------------------------------------------------------------------------
__global__ __launch_bounds__(256) void g2pool_kernel(
    const unsigned short* __restrict__ A, const unsigned short* __restrict__ Bt,
    const float* __restrict__ b1, const float* __restrict__ W2,
    float* __restrict__ wpart, const int* __restrict__ glist,
    const int* __restrict__ gcnt2, float* __restrict__ pool,
    int M, int p0, int npaths, size_t astride) {
  __shared__ __align__(16) char smem[49168];
  int b = blockIdx.x;
  int tid = threadIdx.x;
  int nb2 = NBG2 * npaths;
  if (b < nb2) {
    unsigned short* As = (unsigned short*)smem;
    unsigned short* Bs = (unsigned short*)(smem + 16384);
    float* wred = (float*)(smem + 49152);
    int bx = b % NBG2, pl = b / NBG2;
    const unsigned short* Ap = A + (size_t)pl * astride;
    int row0 = bx * 64;
    int wave = tid >> 6, lane = tid & 63;
    int ln = lane & 15, quad = lane >> 4;
    int mbase = (wave >> 1) * 32, nbase = (wave & 1) * 64;
    f32x4 acc[2][4] = {};
    for (int kc = 0; kc < 2; kc++) {
      #pragma unroll
      for (int i = 0; i < 4; i++) {
        int c = i * 256 + tid;
        int row = c >> 4, g = c & 15;
        int grow = row0 + row;
        uint4 v = make_uint4(0, 0, 0, 0);
        if (grow < M) v = *(const uint4*)(Ap + (size_t)grow * 256 + kc * 128 + g * 8);
        *(uint4*)&As[row * 128 + ((g ^ (row & 15)) << 3)] = v;
      }
      #pragma unroll
      for (int i = 0; i < 8; i++) {
        int c = i * 256 + tid;
        int row = c >> 4, g = c & 15;
        uint4 v = *(const uint4*)(Bt + (size_t)row * 256 + kc * 128 + g * 8);
        *(uint4*)&Bs[row * 128 + ((g ^ (row & 15)) << 3)] = v;
      }
      __syncthreads();
      #pragma unroll
      for (int ks = 0; ks < 4; ks++) {
        int g = ks * 4 + quad;
        bf16x8 a[2], bb[4];
        #pragma unroll
        for (int mi = 0; mi < 2; mi++) {
          int r = mbase + mi * 16 + ln;
          a[mi] = *(const bf16x8*)&As[r * 128 + ((g ^ ln) << 3)];
        }
        #pragma unroll
        for (int ni = 0; ni < 4; ni++) {
          int r = nbase + ni * 16 + ln;
          bb[ni] = *(const bf16x8*)&Bs[r * 128 + ((g ^ ln) << 3)];
        }
        #pragma unroll
        for (int mi = 0; mi < 2; mi++)
          #pragma unroll
          for (int ni = 0; ni < 4; ni++)
            acc[mi][ni] = __builtin_amdgcn_mfma_f32_16x16x32_bf16(a[mi], bb[ni], acc[mi][ni], 0, 0, 0);
      }
      __syncthreads();
    }
    float b1v[4], w2v[4];
    #pragma unroll
    for (int ni = 0; ni < 4; ni++) {
      int col = nbase + ni * 16 + ln;
      b1v[ni] = b1[col]; w2v[ni] = W2[col];
    }
    float s = 0.f;
    #pragma unroll
    for (int mi = 0; mi < 2; mi++) {
      int gm0 = row0 + mbase + mi * 16 + quad * 4;
      #pragma unroll
      for (int r = 0; r < 4; r++) {
        if (gm0 + r < M) {
          #pragma unroll
          for (int ni = 0; ni < 4; ni++)
            s += ftanh(acc[mi][ni][r] + b1v[ni]) * w2v[ni];
        }
      }
    }
    #pragma unroll
    for (int o = 32; o > 0; o >>= 1) s += __shfl_down(s, o);
    if (lane == 0) wred[wave] = s;
    __syncthreads();
    if (tid == 0)
      wpart[(size_t)(p0 + pl) * NBG2 + bx] =
          (wred[0] + wred[1]) + (wred[2] + wred[3]);
  } else {
    int* nl = (int*)smem;                      // GCAP ints = 2304 B
    float* sm = (float*)(smem + GCAP * 4);     // 4096 B
    int i0 = b - nb2;
    int g = i0 % BG, pl = i0 / BG;
    const unsigned short* embp = A + (size_t)pl * astride;
    int cnt = min(gcnt2[g], GCAP);
    for (int i = tid; i < cnt; i += 256) nl[i] = glist[g * GCAP + i];
    __syncthreads();
    int sub = tid >> 6, lane = tid & 63;
    float a0 = 0.f, a1 = 0.f, a2 = 0.f, a3 = 0.f;
    for (int i = sub; i < cnt; i += 4) {
      ushort4 v = *(const ushort4*)(embp + (size_t)nl[i] * HF + lane * 4);
      a0 += b2f(v.x); a1 += b2f(v.y); a2 += b2f(v.z); a3 += b2f(v.w);
    }
    sm[(sub * 64 + lane) * 4 + 0] = a0;
    sm[(sub * 64 + lane) * 4 + 1] = a1;
    sm[(sub * 64 + lane) * 4 + 2] = a2;
    sm[(sub * 64 + lane) * 4 + 3] = a3;
    __syncthreads();
    int fl = tid >> 2, j = tid & 3;
    float s = sm[(0 * 64 + fl) * 4 + j] + sm[(1 * 64 + fl) * 4 + j]
            + sm[(2 * 64 + fl) * 4 + j] + sm[(3 * 64 + fl) * 4 + j];
    pool[((size_t)(p0 + pl) * BG + g) * HF + tid] = s;
  }
}

// ---------------------------------------------------------------------------
// final: reduce wpart -> beta softmax; counts from gcnt2; logits + pooled out
// ---------------------------------------------------------------------------
__global__ __launch_bounds__(256) void final_kernel(
    const float* __restrict__ pool, const float* __restrict__ wpart,
    const int* __restrict__ gcnt2, const float* __restrict__ clsW,
    const float* __restrict__ clsb, float* __restrict__ out, int N) {
  int b = blockIdx.x;
  int f = threadIdx.x;
  __shared__ float red[256];
  float wm[PM];
  #pragma unroll
  for (int p = 0; p < PM; p++) {
    float s = 0.f;
    for (int i = f; i < NBG2; i += 256) s += wpart[(size_t)p * NBG2 + i];
    red[f] = s;
    __syncthreads();
    for (int st = 128; st > 0; st >>= 1) {
      if (f < st) red[f] += red[f + st];
      __syncthreads();
    }
    wm[p] = red[0] / (float)N;
    __syncthreads();
  }
  float c = fmaxf((float)gcnt2[b], 1.f);
  float mx = -1e30f;
  #pragma unroll
  for (int p = 0; p < PM; p++) mx = fmaxf(mx, wm[p]);
  float es = 0.f, e[PM];
  #pragma unroll
  for (int p = 0; p < PM; p++) { e[p] = expf(wm[p] - mx); es += e[p]; }
  float v = 0.f;
  #pragma unroll
  for (int p = 0; p < PM; p++)
    v += (e[p] / es) * pool[((size_t)p * BG + b) * HF + f];
  v /= c;
  out[256 + (size_t)b * HF + f] = v;
  __shared__ float sm[256];
  sm[f] = v * clsW[f * 2 + 0];
  __syncthreads();
  for (int st = 128; st > 0; st >>= 1) {
    if (f < st) sm[f] += sm[f + st];
    __syncthreads();
  }
  float l0 = sm[0];
  __syncthreads();
  sm[f] = v * clsW[f * 2 + 1];
  __syncthreads();
  for (int st = 128; st > 0; st >>= 1) {
    if (f < st) sm[f] += sm[f + st];
    __syncthreads();
  }
  if (f == 0) {
    out[b * 2 + 0] = l0 + clsb[0];
    out[b * 2 + 1] = sm[0] + clsb[1];
  }
}

// ---------------------------------------------------------------------------
extern "C" void kernel_launch(void* const* d_in, const int* in_sizes, int n_in,
                              void* d_out, int out_size, void* d_ws, size_t ws_size,
                              hipStream_t stream) {
  const float* h      = (const float*)d_in[0];
  const float* Wg     = (const float*)d_in[1];
  const float* attn_l = (const float*)d_in[2];
  const float* attn_r = (const float*)d_in[3];
  const float* gatb   = (const float*)d_in[4];
  const float* semW1  = (const float*)d_in[5];
  const float* semb1  = (const float*)d_in[6];
  const float* semW2  = (const float*)d_in[7];
  const float* clsW   = (const float*)d_in[8];
  const float* clsb   = (const float*)d_in[9];
  const int*   src    = (const int*)d_in[10];
  const int*   dst    = (const int*)d_in[11];
  const int*   gid    = (const int*)d_in[12];
  float* out = (float*)d_out;

  auto layout_size = [](int PMg) -> size_t {
    size_t o = 0;
    auto alloc = [&](size_t bytes) { o += (bytes + 255) & ~(size_t)255; };
    alloc((size_t)NN * INF_ * 2);              // h_b
    alloc((size_t)PMg * NN * HF * 2);          // hp_b
    alloc((size_t)PMg * NN * HF * 2);          // emb_b
    alloc((size_t)PM * HF * INF_ * 2);         // Wb_t
    alloc((size_t)HS * HF * 2);                // W1_t
    alloc((size_t)PM * INF_ * NH * 4);         // wl
    alloc((size_t)PM * INF_ * NH * 4);         // wr
    alloc((size_t)PMg * NN * NH * 4);          // el
    alloc((size_t)PMg * NN * NH * 4);          // er
    alloc((size_t)PM * NB2 * BCAP * 4);        // bdata
    alloc((size_t)PM * NB2 * 4);               // gcnt
    alloc((size_t)BG * GCAP * 4);              // glist
    alloc((size_t)BG * 4);                     // gcnt2
    alloc((size_t)PM * (NN + 1) * 4);          // off
    alloc((size_t)PM * EE * 2);                // csr
    alloc((size_t)PM * BG * HF * 4);           // pool
    alloc((size_t)PM * NBG2 * 4);              // wpart
    return o;
  };
  int PMg = (layout_size(4) <= ws_size) ? 4 : 1;

  char* ws = (char*)d_ws;
  size_t o = 0;
  auto alloc = [&](size_t bytes) { size_t r = o; o += (bytes + 255) & ~(size_t)255; return r; };
  unsigned short* h_b   = (unsigned short*)(ws + alloc((size_t)NN * INF_ * 2));
  unsigned short* hp_b  = (unsigned short*)(ws + alloc((size_t)PMg * NN * HF * 2));
  unsigned short* emb_b = (unsigned short*)(ws + alloc((size_t)PMg * NN * HF * 2));
  unsigned short* Wb_t  = (unsigned short*)(ws + alloc((size_t)PM * HF * INF_ * 2));
  unsigned short* W1_t  = (unsigned short*)(ws + alloc((size_t)HS * HF * 2));
  float* wl    = (float*)(ws + alloc((size_t)PM * INF_ * NH * 4));
  float* wr    = (float*)(ws + alloc((size_t)PM * INF_ * NH * 4));
  float* el    = (float*)(ws + alloc((size_t)PMg * NN * NH * 4));
  float* er    = (float*)(ws + alloc((size_t)PMg * NN * NH * 4));
  unsigned* bdata = (unsigned*)(ws + alloc((size_t)PM * NB2 * BCAP * 4));
  int*   gcnt  = (int*)(ws + alloc((size_t)PM * NB2 * 4));
  int*   glist = (int*)(ws + alloc((size_t)BG * GCAP * 4));
  int*   gcnt2 = (int*)(ws + alloc((size_t)BG * 4));
  int*   off   = (int*)(ws + alloc((size_t)PM * (NN + 1) * 4));
  unsigned short* csr = (unsigned short*)(ws + alloc((size_t)PM * EE * 2));
  float* pool  = (float*)(ws + alloc((size_t)PM * BG * HF * 4));
  float* wpart = (float*)(ws + alloc((size_t)PM * NBG2 * 4));

  const size_t hpS  = (PMg == 4) ? (size_t)NN * HF : 0;
  const size_t embS = hpS;
  const size_t elS  = (PMg == 4) ? (size_t)NN * NH : 0;

  prep_kernel<<<1 + 6250 + 512 + 128 + 16, 256, 0, stream>>>(
      h, Wg, semW1, attn_l, attn_r, h_b, Wb_t, W1_t, wl, wr, gcnt, gcnt2);
  bg_kernel<<<NBB * PM + NGB, 256, 0, stream>>>(src, dst, bdata, gcnt, gid, glist, gcnt2);
  csrify_kernel<<<dim3(NB2, PM), 256, 0, stream>>>(bdata, gcnt, off, csr);

  if (PMg == 4) {
    g1elr_kernel<<<NBG1 * 2 + NBE * 4, 256, 0, stream>>>(
        h_b, Wb_t, hp_b, wl, wr, el, er, NN, 0, 4, hpS, elS);
    agg_kernel<<<dim3((NN + 3) / 4, 4), 256, 0, stream>>>(
        hp_b, el, er, csr, off, gatb, emb_b, NN, 0, hpS, elS, embS);
    g2pool_kernel<<<NBG2 * 4 + BG * 4, 256, 0, stream>>>(
        emb_b, W1_t, semb1, semW2, wpart, glist, gcnt2, pool, NN, 0, 4, embS);
  } else {
    for (int p = 0; p < PM; p++) {
      g1elr_kernel<<<NBG1 * 2 + NBE, 256, 0, stream>>>(
          h_b, Wb_t, hp_b, wl, wr, el, er, NN, p, 1, 0, 0);
      agg_kernel<<<dim3((NN + 3) / 4, 1), 256, 0, stream>>>(
          hp_b, el, er, csr, off, gatb, emb_b, NN, p, 0, 0, 0);
      g2pool_kernel<<<NBG2 + BG, 256, 0, stream>>>(
          emb_b, W1_t, semb1, semW2, wpart, glist, gcnt2, pool, NN, p, 1, 0);
    }
  }

  final_kernel<<<BG, 256, 0, stream>>>(pool, wpart, gcnt2, clsW, clsb, out, NN);
}

// Round 13
// 420.697 us; speedup vs baseline: 2.1968x; 1.0275x over previous
//
#include <hip/hip_runtime.h>

#define NN 50000
#define PM 4
#define EE 500000
#define INF_ 128
#define NH 8
#define FF 32
#define HF 256
#define HS 128
#define BG 128
#define OUTC 2

#define NB2 98        // buckets per path: dst>>9 (512 nodes/bucket)
#define BCAP 6144     // bucket capacity (mean 5102, sd ~71 -> 14 sigma slack)
#define BCH 4096      // edges per workgroup in bucket pass
#define NBB 123       // bucket blocks per path = ceil(EE/BCH)
#define NGB 13        // gbucket blocks = ceil(NN/BCH)
#define GCAP 576      // nodes per graph capacity (mean 390, sd ~20 -> 9 sigma)
#define NBG1 782      // gemm1/gemm2 row-blocks = ceil(NN/64)
#define NBE 196       // elr blocks per path = ceil(NN/256)
#define NBG2 782
#define CTS 136       // padded ushort stride for C-transpose tile (64x136)

typedef __attribute__((ext_vector_type(8))) short bf16x8;
typedef __attribute__((ext_vector_type(4))) float f32x4;

__device__ __forceinline__ float b2f(unsigned short x) {
  unsigned u = ((unsigned)x) << 16;
  return __builtin_bit_cast(float, u);
}
__device__ __forceinline__ unsigned short f2b(float f) {
  unsigned u = __builtin_bit_cast(unsigned, f);
  u += 0x7fff + ((u >> 16) & 1);   // RNE
  return (unsigned short)(u >> 16);
}
__device__ __forceinline__ float fexp(float x) { return __expf(x); }
__device__ __forceinline__ float ftanh(float x) {
  float t = __expf(-2.f * fabsf(x));
  float r = (1.f - t) / (1.f + t);
  return copysignf(r, x);
}

// ---------------------------------------------------------------------------
// prep: zero gcnt/gcnt2 + h->bf16 + Wg transpose + W1 transpose + fold
// ---------------------------------------------------------------------------
__global__ __launch_bounds__(256) void prep_kernel(
    const float* __restrict__ h, const float* __restrict__ Wg,
    const float* __restrict__ W1, const float* __restrict__ al,
    const float* __restrict__ ar,
    unsigned short* __restrict__ h_b, unsigned short* __restrict__ Wb_t,
    unsigned short* __restrict__ W1_t, float* __restrict__ wl,
    float* __restrict__ wr, int* __restrict__ gcnt, int* __restrict__ gcnt2) {
  int b = blockIdx.x;
  int tid = threadIdx.x;
  if (b < 1) {
    for (int i = tid; i < PM * NB2; i += 256) gcnt[i] = 0;
    if (tid < BG) gcnt2[tid] = 0;
    return;
  }
  b -= 1;
  if (b < 6250) {
    int t = b * 256 + tid;
    float4 v = *(const float4*)(h + (size_t)t * 4);
    ushort4 o;
    o.x = f2b(v.x); o.y = f2b(v.y); o.z = f2b(v.z); o.w = f2b(v.w);
    *(ushort4*)(h_b + (size_t)t * 4) = o;
    return;
  }
  b -= 6250;
  if (b < 512) {
    int t = b * 256 + tid;
    int p = t >> 15, rem = t & 32767;
    int n = rem >> 7, k = rem & 127;
    Wb_t[(size_t)p * 32768 + n * 128 + k] = f2b(Wg[(size_t)p * 32768 + k * 256 + n]);
    return;
  }
  b -= 512;
  if (b < 128) {
    int t = b * 256 + tid;
    int n = t >> 8, k = t & 255;
    W1_t[n * 256 + k] = f2b(W1[k * 128 + n]);
    return;
  }
  b -= 128;
  {
    int t = b * 256 + tid;
    int p = t >> 10, rem = t & 1023;
    int k = rem >> 3, hh = rem & 7;
    const float* wrow = Wg + (size_t)p * 32768 + k * 256 + hh * 32;
    const float* alp = al + p * 256 + hh * 32;
    const float* arp = ar + p * 256 + hh * 32;
    float sl = 0.f, sr = 0.f;
    #pragma unroll
    for (int f = 0; f < 32; f++) { sl += wrow[f] * alp[f]; sr += wrow[f] * arp[f]; }
    wl[t] = sl; wr[t] = sr;
  }
}

// ---------------------------------------------------------------------------
// bg: bucket (edges by dst>>9) + gbucket (nodes by graph) in one dispatch
// ---------------------------------------------------------------------------
__global__ __launch_bounds__(256) void bg_kernel(
    const int* __restrict__ src, const int* __restrict__ dst,
    unsigned* __restrict__ bdata, int* __restrict__ gcnt,
    const int* __restrict__ gid, int* __restrict__ glist,
    int* __restrict__ gcnt2) {
  __shared__ __align__(16) char smem[18432];
  int b = blockIdx.x;
  int tid = threadIdx.x;
  if (b < NBB * PM) {
    unsigned* ed = (unsigned*)smem;
    int* hist  = (int*)(smem + BCH * 4);
    int* gbase = hist + NB2;
    int* cur   = gbase + NB2;
    int p = b / NBB, blk = b % NBB;
    int e0 = blk * BCH;
    int n = min(BCH, EE - e0);
    if (tid < NB2) hist[tid] = 0;
    __syncthreads();
    const int* sp = src + (size_t)p * EE + e0;
    const int* dp = dst + (size_t)p * EE + e0;
    for (int i = tid; i < n; i += 256) {
      int s = sp[i], d = dp[i];
      ed[i] = ((unsigned)d << 16) | (unsigned)s;
      atomicAdd(&hist[d >> 9], 1);
    }
    __syncthreads();
    if (tid < NB2) {
      gbase[tid] = atomicAdd(&gcnt[p * NB2 + tid], hist[tid]);
      cur[tid] = 0;
    }
    __syncthreads();
    for (int i = tid; i < n; i += 256) {
      unsigned pk = ed[i];
      int bk = pk >> 25;
      int slot = gbase[bk] + atomicAdd(&cur[bk], 1);
      if (slot < BCAP)
        bdata[((size_t)(p * NB2 + bk)) * BCAP + slot] = pk;
    }
  } else {
    int* gl    = (int*)smem;
    int* hist  = (int*)(smem + BCH * 4);
    int* gbase = hist + BG;
    int* cur   = gbase + BG;
    int blk = b - NBB * PM;
    int e0 = blk * BCH;
    int n = min(BCH, NN - e0);
    if (tid < BG) hist[tid] = 0;
    __syncthreads();
    for (int i = tid; i < n; i += 256) {
      int g = gid[e0 + i];
      gl[i] = g;
      atomicAdd(&hist[g], 1);
    }
    __syncthreads();
    if (tid < BG) {
      gbase[tid] = atomicAdd(&gcnt2[tid], hist[tid]);
      cur[tid] = 0;
    }
    __syncthreads();
    for (int i = tid; i < n; i += 256) {
      int g = gl[i];
      int slot = gbase[g] + atomicAdd(&cur[g], 1);
      if (slot < GCAP) glist[g * GCAP + slot] = e0 + i;
    }
  }
}

// ---------------------------------------------------------------------------
// cg1: merged csrify + gemm1 + elr (all deps satisfied after prep+bg).
// Sections by blockIdx.x: [0,NCSR) csrify; [NCSR,+NBG1*2) gemm1;
// [..,+NBE*npaths) elr. gemm1 epilogue: LDS transpose -> 16B stores.
// ---------------------------------------------------------------------------
__global__ __launch_bounds__(256) void cg1_kernel(
    const unsigned* __restrict__ bdata, const int* __restrict__ gcnt,
    int* __restrict__ off, unsigned short* __restrict__ csr,
    const unsigned short* __restrict__ hA, const unsigned short* __restrict__ Bt,
    unsigned short* __restrict__ Cb, const float* __restrict__ wl,
    const float* __restrict__ wr, float* __restrict__ el, float* __restrict__ er,
    int M, int p0, int npaths, int ncsr, size_t cstride, size_t estride) {
  __shared__ __align__(16) char smem[49152];
  int b = blockIdx.x;
  int tid = threadIdx.x;
  if (b < ncsr) {
    // ---- csrify section ----
    unsigned* ebuf = (unsigned*)smem;               // 24576 B
    int* gc    = (int*)(smem + 24576);              // 392 B
    int* degc  = (int*)(smem + 24968);              // 2048 B
    int* loff  = (int*)(smem + 27016);              // 2052 B
    int* tmp   = (int*)(smem + 29068);              // 1024 B
    int* base_p = (int*)(smem + 30092);             // 4 B
    int bb = b % NB2, p = b / NB2;
    if (tid < NB2) gc[tid] = min(gcnt[p * NB2 + tid], BCAP);
    __syncthreads();
    if (tid == 0) {
      int s = 0;
      for (int i = 0; i < bb; i++) s += gc[i];
      *base_p = s;
    }
    int cnt = gc[bb];
    const unsigned* bp = bdata + ((size_t)(p * NB2 + bb)) * BCAP;
    for (int i = tid; i < cnt; i += 256) ebuf[i] = bp[i];
    degc[tid] = 0; degc[256 + tid] = 0;
    __syncthreads();
    for (int i = tid; i < cnt; i += 256)
      atomicAdd(&degc[(ebuf[i] >> 16) & 511], 1);
    __syncthreads();
    int d0 = degc[2 * tid], d1 = degc[2 * tid + 1];
    tmp[tid] = d0 + d1;
    __syncthreads();
    for (int o = 1; o < 256; o <<= 1) {
      int v = (tid >= o) ? tmp[tid - o] : 0;
      __syncthreads();
      tmp[tid] += v;
      __syncthreads();
    }
    int bse = tmp[tid] - d0 - d1;
    loff[2 * tid] = bse; loff[2 * tid + 1] = bse + d0;
    if (tid == 255) loff[512] = tmp[255];
    __syncthreads();
    int base = *base_p;
    for (int dl = tid; dl < 512; dl += 256) {
      int n = bb * 512 + dl;
      if (n <= NN) off[(size_t)p * (NN + 1) + n] = base + loff[dl];
    }
    degc[tid] = 0; degc[256 + tid] = 0;
    __syncthreads();
    for (int i = tid; i < cnt; i += 256) {
      unsigned pk = ebuf[i];
      int dl = (pk >> 16) & 511;
      int slot = loff[dl] + atomicAdd(&degc[dl], 1);
      csr[(size_t)p * EE + base + slot] = (unsigned short)(pk & 0xffff);
    }
    return;
  }
  b -= ncsr;
  int nb1 = NBG1 * 2;
  if (b < nb1) {
    // ---- gemm1 section (multi-path, A frag-cached, LDS-transpose stores) ----
    unsigned short* As = (unsigned short*)smem;            // 16 KB
    unsigned short* Bs = (unsigned short*)(smem + 16384);  // 32 KB
    unsigned short* Ct = (unsigned short*)smem;            // 64x136 = 17408 B (reuses As+1KB of Bs)
    int row0 = (b >> 1) * 64, col0 = (b & 1) * 128;
    #pragma unroll
    for (int i = 0; i < 4; i++) {
      int c = i * 256 + tid;
      int row = c >> 4, g = c & 15;
      int grow = row0 + row;
      uint4 v = make_uint4(0, 0, 0, 0);
      if (grow < M) v = *(const uint4*)(hA + (size_t)grow * 128 + g * 8);
      *(uint4*)&As[row * 128 + ((g ^ (row & 15)) << 3)] = v;
    }
    int wave = tid >> 6, lane = tid & 63;
    int ln = lane & 15, quad = lane >> 4;
    int mbase = (wave >> 1) * 32, nbase = (wave & 1) * 64;
    bf16x8 afr[4][2];
    bool afr_ok = false;
    for (int pl = 0; pl < npaths; pl++) {
      const unsigned short* Bp = Bt + (size_t)(p0 + pl) * 32768;
      #pragma unroll
      for (int i = 0; i < 8; i++) {
        int c = i * 256 + tid;
        int row = c >> 4, g = c & 15;
        uint4 v = *(const uint4*)(Bp + (size_t)(col0 + row) * 128 + g * 8);
        *(uint4*)&Bs[row * 128 + ((g ^ (row & 15)) << 3)] = v;
      }
      __syncthreads();
      if (!afr_ok) {
        #pragma unroll
        for (int ks = 0; ks < 4; ks++) {
          int g = ks * 4 + quad;
          #pragma unroll
          for (int mi = 0; mi < 2; mi++) {
            int r = mbase + mi * 16 + ln;
            afr[ks][mi] = *(const bf16x8*)&As[r * 128 + ((g ^ ln) << 3)];
          }
        }
        afr_ok = true;
      }
      f32x4 acc[2][4] = {};
      #pragma unroll
      for (int ks = 0; ks < 4; ks++) {
        int g = ks * 4 + quad;
        bf16x8 bb[4];
        #pragma unroll
        for (int ni = 0; ni < 4; ni++) {
          int r = nbase + ni * 16 + ln;
          bb[ni] = *(const bf16x8*)&Bs[r * 128 + ((g ^ ln) << 3)];
        }
        #pragma unroll
        for (int mi = 0; mi < 2; mi++)
          #pragma unroll
          for (int ni = 0; ni < 4; ni++)
            acc[mi][ni] = __builtin_amdgcn_mfma_f32_16x16x32_bf16(afr[ks][mi], bb[ni], acc[mi][ni], 0, 0, 0);
      }
      __syncthreads();   // all Bs reads done before Ct clobbers
      #pragma unroll
      for (int mi = 0; mi < 2; mi++) {
        int lr0 = mbase + mi * 16 + quad * 4;
        #pragma unroll
        for (int ni = 0; ni < 4; ni++) {
          int lc = nbase + ni * 16 + ln;
          #pragma unroll
          for (int r = 0; r < 4; r++)
            Ct[(lr0 + r) * CTS + lc] = f2b(acc[mi][ni][r]);
        }
      }
      __syncthreads();
      unsigned short* Cp = Cb + (size_t)pl * cstride;
      int r2 = tid >> 2, seg = tid & 3;
      int gm = row0 + r2;
      if (gm < M) {
        #pragma unroll
        for (int k = 0; k < 4; k++) {
          int c = seg * 8 + k * 32;
          uint4 v = *(const uint4*)&Ct[r2 * CTS + c];
          *(uint4*)(Cp + (size_t)gm * 256 + col0 + c) = v;
        }
      }
      __syncthreads();   // Ct reads done before next Bs staging
    }
  } else {
    // ---- elr section ----
    float* wls = (float*)smem;
    float* wrs = wls + 1024;
    int t = b - nb1;
    int pl = t / NBE, nblk = t % NBE;
    const float* wlp = wl + (size_t)(p0 + pl) * 1024;
    const float* wrp = wr + (size_t)(p0 + pl) * 1024;
    float* elp = el + (size_t)pl * estride;
    float* erp = er + (size_t)pl * estride;
    for (int i = tid; i < 1024; i += 256) { wls[i] = wlp[i]; wrs[i] = wrp[i]; }
    __syncthreads();
    int n = nblk * 256 + tid;
    if (n >= M) return;
    float accl[8] = {}, accr[8] = {};
    for (int kk = 0; kk < 16; kk++) {
      uint4 raw = *(const uint4*)(hA + (size_t)n * 128 + kk * 8);
      unsigned uu[4] = {raw.x, raw.y, raw.z, raw.w};
      #pragma unroll
      for (int q = 0; q < 4; q++) {
        float v0 = __builtin_bit_cast(float, uu[q] << 16);
        float v1 = __builtin_bit_cast(float, uu[q] & 0xffff0000u);
        int k = kk * 8 + q * 2;
        #pragma unroll
        for (int hh = 0; hh < 8; hh++) {
          accl[hh] += v0 * wls[k * 8 + hh] + v1 * wls[(k + 1) * 8 + hh];
          accr[hh] += v0 * wrs[k * 8 + hh] + v1 * wrs[(k + 1) * 8 + hh];
        }
      }
    }
    *(float4*)(elp + (size_t)n * 8)     = make_float4(accl[0], accl[1], accl[2], accl[3]);
    *(float4*)(elp + (size_t)n * 8 + 4) = make_float4(accl[4], accl[5], accl[6], accl[7]);
    *(float4*)(erp + (size_t)n * 8)     = make_float4(accr[0], accr[1], accr[2], accr[3]);
    *(float4*)(erp + (size_t)n * 8 + 4) = make_float4(accr[4], accr[5], accr[6], accr[7]);
  }
}

// ---------------------------------------------------------------------------
// agg: one wave per dst node, x8-unrolled edge loop (bandwidth-roofline bound)
// ---------------------------------------------------------------------------
__global__ __launch_bounds__(256) void agg_kernel(
    const unsigned short* __restrict__ hp_b, const float* __restrict__ el,
    const float* __restrict__ er, const unsigned short* __restrict__ csr,
    const int* __restrict__ off, const float* __restrict__ bias,
    unsigned short* __restrict__ emb_b, int N, int p0,
    size_t hstride, size_t estride, size_t embstride) {
  int pl = blockIdx.y;
  int p = p0 + pl;
  const unsigned short* hp = hp_b + (size_t)pl * hstride;
  const float* elp = el + (size_t)pl * estride;
  const float* erp = er + (size_t)pl * estride;
  const unsigned short* csrp = csr + (size_t)p * EE;
  const int* offp = off + (size_t)p * (NN + 1);
  const float* bp = bias + (size_t)p * HF;
  unsigned short* embp = emb_b + (size_t)pl * embstride;
  int n = blockIdx.x * 4 + (threadIdx.x >> 6);
  if (n >= N) return;
  int lane = threadIdx.x & 63;
  int h = lane >> 3;
  int e0 = offp[n], e1 = offp[n + 1];
  float erh = erp[n * NH + h];
  float den = 0.f, a0 = 0.f, a1 = 0.f, a2 = 0.f, a3 = 0.f;
  int e = e0;
  for (; e + 8 <= e1; e += 8) {
    int s[8];
    #pragma unroll
    for (int j = 0; j < 8; j++) s[j] = csrp[e + j];
    float x[8];
    #pragma unroll
    for (int j = 0; j < 8; j++) x[j] = elp[s[j] * NH + h];
    ushort4 hv[8];
    #pragma unroll
    for (int j = 0; j < 8; j++)
      hv[j] = *(const ushort4*)(hp + (size_t)s[j] * HF + lane * 4);
    float w[8];
    #pragma unroll
    for (int j = 0; j < 8; j++) {
      float xx = x[j] + erh;
      xx = fmaxf(xx, 0.2f * xx);
      w[j] = fexp(xx);
    }
    den += ((w[0] + w[1]) + (w[2] + w[3])) + ((w[4] + w[5]) + (w[6] + w[7]));
    a0 += ((w[0] * b2f(hv[0].x) + w[1] * b2f(hv[1].x)) + (w[2] * b2f(hv[2].x) + w[3] * b2f(hv[3].x)))
        + ((w[4] * b2f(hv[4].x) + w[5] * b2f(hv[5].x)) + (w[6] * b2f(hv[6].x) + w[7] * b2f(hv[7].x)));
    a1 += ((w[0] * b2f(hv[0].y) + w[1] * b2f(hv[1].y)) + (w[2] * b2f(hv[2].y) + w[3] * b2f(hv[3].y)))
        + ((w[4] * b2f(hv[4].y) + w[5] * b2f(hv[5].y)) + (w[6] * b2f(hv[6].y) + w[7] * b2f(hv[7].y)));
    a2 += ((w[0] * b2f(hv[0].z) + w[1] * b2f(hv[1].z)) + (w[2] * b2f(hv[2].z) + w[3] * b2f(hv[3].z)))
        + ((w[4] * b2f(hv[4].z) + w[5] * b2f(hv[5].z)) + (w[6] * b2f(hv[6].z) + w[7] * b2f(hv[7].z)));
    a3 += ((w[0] * b2f(hv[0].w) + w[1] * b2f(hv[1].w)) + (w[2] * b2f(hv[2].w) + w[3] * b2f(hv[3].w)))
        + ((w[4] * b2f(hv[4].w) + w[5] * b2f(hv[5].w)) + (w[6] * b2f(hv[6].w) + w[7] * b2f(hv[7].w)));
  }
  if (e + 4 <= e1) {
    int s0 = csrp[e], s1 = csrp[e + 1], s2 = csrp[e + 2], s3 = csrp[e + 3];
    float x0 = elp[s0 * NH + h] + erh;
    float x1 = elp[s1 * NH + h] + erh;
    float x2 = elp[s2 * NH + h] + erh;
    float x3 = elp[s3 * NH + h] + erh;
    ushort4 h0 = *(const ushort4*)(hp + (size_t)s0 * HF + lane * 4);
    ushort4 h1 = *(const ushort4*)(hp + (size_t)s1 * HF + lane * 4);
    ushort4 h2 = *(const ushort4*)(hp + (size_t)s2 * HF + lane * 4);
    ushort4 h3 = *(const ushort4*)(hp + (size_t)s3 * HF + lane * 4);
    x0 = fmaxf(x0, 0.2f * x0); x1 = fmaxf(x1, 0.2f * x1);
    x2 = fmaxf(x2, 0.2f * x2); x3 = fmaxf(x3, 0.2f * x3);
    float w0 = fexp(x0), w1 = fexp(x1), w2 = fexp(x2), w3 = fexp(x3);
    den += (w0 + w1) + (w2 + w3);
    a0 += (w0 * b2f(h0.x) + w1 * b2f(h1.x)) + (w2 * b2f(h2.x) + w3 * b2f(h3.x));
    a1 += (w0 * b2f(h0.y) + w1 * b2f(h1.y)) + (w2 * b2f(h2.y) + w3 * b2f(h3.y));
    a2 += (w0 * b2f(h0.z) + w1 * b2f(h1.z)) + (w2 * b2f(h2.z) + w3 * b2f(h3.z));
    a3 += (w0 * b2f(h0.w) + w1 * b2f(h1.w)) + (w2 * b2f(h2.w) + w3 * b2f(h3.w));
    e += 4;
  }
  for (; e < e1; e++) {
    int s = csrp[e];
    float x = elp[s * NH + h] + erh;
    x = fmaxf(x, 0.2f * x);
    float w = fexp(x);
    den += w;
    ushort4 hv = *(const ushort4*)(hp + (size_t)s * HF + lane * 4);
    a0 += w * b2f(hv.x); a1 += w * b2f(hv.y);
    a2 += w * b2f(hv.z); a3 += w * b2f(hv.w);
  }
  float inv = (den > 0.f) ? 1.f / den : 0.f;
  float4 bv = *(const float4*)(bp + lane * 4);
  float o0 = a0 * inv + bv.x, o1 = a1 * inv + bv.y;
  float o2 = a2 * inv + bv.z, o3 = a3 * inv + bv.w;
  o0 = (o0 > 0.f) ? o0 : fexp(o0) - 1.f;
  o1 = (o1 > 0.f) ? o1 : fexp(o1) - 1.f;
  o2 = (o2 > 0.f) ? o2 : fexp(o2) - 1.f;
  o3 = (o3 > 0.f) ? o3 : fexp(o3) - 1.f;
  ushort4 ov;
  ov.x = f2b(o0); ov.y = f2b(o1); ov.z = f2b(o2); ov.w = f2b(o3);
  *(ushort4*)(embp + (size_t)n * HF + lane * 4) = ov;
}

// ---------------------------------------------------------------------------
// g2pool: gemm2 (tanh epilogue -> wpart, no atomics) + pool section.
// ---------------------------------------------------------------------------
__global__ __launch_bounds__(256) void g2pool_kernel(
    const unsigned short* __restrict__ A, const unsigned short* __restrict__ Bt,
    const float* __restrict__ b1, const float* __restrict__ W2,
    float* __restrict__ wpart, const int* __restrict__ glist,
    const int* __restrict__ gcnt2, float* __restrict__ pool,
    int M, int p0, int npaths, size_t astride) {
  __shared__ __align__(16) char smem[49168];
  int b = blockIdx.x;
  int tid = threadIdx.x;
  int nb2 = NBG2 * npaths;
  if (b < nb2) {
    unsigned short* As = (unsigned short*)smem;
    unsigned short* Bs = (unsigned short*)(smem + 16384);
    float* wred = (float*)(smem + 49152);
    int bx = b % NBG2, pl = b / NBG2;
    const unsigned short* Ap = A + (size_t)pl * astride;
    int row0 = bx * 64;
    int wave = tid >> 6, lane = tid & 63;
    int ln = lane & 15, quad = lane >> 4;
    int mbase = (wave >> 1) * 32, nbase = (wave & 1) * 64;
    f32x4 acc[2][4] = {};
    for (int kc = 0; kc < 2; kc++) {
      #pragma unroll
      for (int i = 0; i < 4; i++) {
        int c = i * 256 + tid;
        int row = c >> 4, g = c & 15;
        int grow = row0 + row;
        uint4 v = make_uint4(0, 0, 0, 0);
        if (grow < M) v = *(const uint4*)(Ap + (size_t)grow * 256 + kc * 128 + g * 8);
        *(uint4*)&As[row * 128 + ((g ^ (row & 15)) << 3)] = v;
      }
      #pragma unroll
      for (int i = 0; i < 8; i++) {
        int c = i * 256 + tid;
        int row = c >> 4, g = c & 15;
        uint4 v = *(const uint4*)(Bt + (size_t)row * 256 + kc * 128 + g * 8);
        *(uint4*)&Bs[row * 128 + ((g ^ (row & 15)) << 3)] = v;
      }
      __syncthreads();
      #pragma unroll
      for (int ks = 0; ks < 4; ks++) {
        int g = ks * 4 + quad;
        bf16x8 a[2], bb[4];
        #pragma unroll
        for (int mi = 0; mi < 2; mi++) {
          int r = mbase + mi * 16 + ln;
          a[mi] = *(const bf16x8*)&As[r * 128 + ((g ^ ln) << 3)];
        }
        #pragma unroll
        for (int ni = 0; ni < 4; ni++) {
          int r = nbase + ni * 16 + ln;
          bb[ni] = *(const bf16x8*)&Bs[r * 128 + ((g ^ ln) << 3)];
        }
        #pragma unroll
        for (int mi = 0; mi < 2; mi++)
          #pragma unroll
          for (int ni = 0; ni < 4; ni++)
            acc[mi][ni] = __builtin_amdgcn_mfma_f32_16x16x32_bf16(a[mi], bb[ni], acc[mi][ni], 0, 0, 0);
      }
      __syncthreads();
    }
    float b1v[4], w2v[4];
    #pragma unroll
    for (int ni = 0; ni < 4; ni++) {
      int col = nbase + ni * 16 + ln;
      b1v[ni] = b1[col]; w2v[ni] = W2[col];
    }
    float s = 0.f;
    #pragma unroll
    for (int mi = 0; mi < 2; mi++) {
      int gm0 = row0 + mbase + mi * 16 + quad * 4;
      #pragma unroll
      for (int r = 0; r < 4; r++) {
        if (gm0 + r < M) {
          #pragma unroll
          for (int ni = 0; ni < 4; ni++)
            s += ftanh(acc[mi][ni][r] + b1v[ni]) * w2v[ni];
        }
      }
    }
    #pragma unroll
    for (int o = 32; o > 0; o >>= 1) s += __shfl_down(s, o);
    if (lane == 0) wred[wave] = s;
    __syncthreads();
    if (tid == 0)
      wpart[(size_t)(p0 + pl) * NBG2 + bx] =
          (wred[0] + wred[1]) + (wred[2] + wred[3]);
  } else {
    int* nl = (int*)smem;
    float* sm = (float*)(smem + GCAP * 4);
    int i0 = b - nb2;
    int g = i0 % BG, pl = i0 / BG;
    const unsigned short* embp = A + (size_t)pl * astride;
    int cnt = min(gcnt2[g], GCAP);
    for (int i = tid; i < cnt; i += 256) nl[i] = glist[g * GCAP + i];
    __syncthreads();
    int sub = tid >> 6, lane = tid & 63;
    float a0 = 0.f, a1 = 0.f, a2 = 0.f, a3 = 0.f;
    for (int i = sub; i < cnt; i += 4) {
      ushort4 v = *(const ushort4*)(embp + (size_t)nl[i] * HF + lane * 4);
      a0 += b2f(v.x); a1 += b2f(v.y); a2 += b2f(v.z); a3 += b2f(v.w);
    }
    sm[(sub * 64 + lane) * 4 + 0] = a0;
    sm[(sub * 64 + lane) * 4 + 1] = a1;
    sm[(sub * 64 + lane) * 4 + 2] = a2;
    sm[(sub * 64 + lane) * 4 + 3] = a3;
    __syncthreads();
    int fl = tid >> 2, j = tid & 3;
    float s = sm[(0 * 64 + fl) * 4 + j] + sm[(1 * 64 + fl) * 4 + j]
            + sm[(2 * 64 + fl) * 4 + j] + sm[(3 * 64 + fl) * 4 + j];
    pool[((size_t)(p0 + pl) * BG + g) * HF + tid] = s;
  }
}

// ---------------------------------------------------------------------------
// final: reduce wpart -> beta softmax; counts from gcnt2; logits + pooled out
// ---------------------------------------------------------------------------
__global__ __launch_bounds__(256) void final_kernel(
    const float* __restrict__ pool, const float* __restrict__ wpart,
    const int* __restrict__ gcnt2, const float* __restrict__ clsW,
    const float* __restrict__ clsb, float* __restrict__ out, int N) {
  int b = blockIdx.x;
  int f = threadIdx.x;
  __shared__ float red[256];
  float wm[PM];
  #pragma unroll
  for (int p = 0; p < PM; p++) {
    float s = 0.f;
    for (int i = f; i < NBG2; i += 256) s += wpart[(size_t)p * NBG2 + i];
    red[f] = s;
    __syncthreads();
    for (int st = 128; st > 0; st >>= 1) {
      if (f < st) red[f] += red[f + st];
      __syncthreads();
    }
    wm[p] = red[0] / (float)N;
    __syncthreads();
  }
  float c = fmaxf((float)gcnt2[b], 1.f);
  float mx = -1e30f;
  #pragma unroll
  for (int p = 0; p < PM; p++) mx = fmaxf(mx, wm[p]);
  float es = 0.f, e[PM];
  #pragma unroll
  for (int p = 0; p < PM; p++) { e[p] = expf(wm[p] - mx); es += e[p]; }
  float v = 0.f;
  #pragma unroll
  for (int p = 0; p < PM; p++)
    v += (e[p] / es) * pool[((size_t)p * BG + b) * HF + f];
  v /= c;
  out[256 + (size_t)b * HF + f] = v;
  __shared__ float sm[256];
  sm[f] = v * clsW[f * 2 + 0];
  __syncthreads();
  for (int st = 128; st > 0; st >>= 1) {
    if (f < st) sm[f] += sm[f + st];
    __syncthreads();
  }
  float l0 = sm[0];
  __syncthreads();
  sm[f] = v * clsW[f * 2 + 1];
  __syncthreads();
  for (int st = 128; st > 0; st >>= 1) {
    if (f < st) sm[f] += sm[f + st];
    __syncthreads();
  }
  if (f == 0) {
    out[b * 2 + 0] = l0 + clsb[0];
    out[b * 2 + 1] = sm[0] + clsb[1];
  }
}

// ---------------------------------------------------------------------------
extern "C" void kernel_launch(void* const* d_in, const int* in_sizes, int n_in,
                              void* d_out, int out_size, void* d_ws, size_t ws_size,
                              hipStream_t stream) {
  const float* h      = (const float*)d_in[0];
  const float* Wg     = (const float*)d_in[1];
  const float* attn_l = (const float*)d_in[2];
  const float* attn_r = (const float*)d_in[3];
  const float* gatb   = (const float*)d_in[4];
  const float* semW1  = (const float*)d_in[5];
  const float* semb1  = (const float*)d_in[6];
  const float* semW2  = (const float*)d_in[7];
  const float* clsW   = (const float*)d_in[8];
  const float* clsb   = (const float*)d_in[9];
  const int*   src    = (const int*)d_in[10];
  const int*   dst    = (const int*)d_in[11];
  const int*   gid    = (const int*)d_in[12];
  float* out = (float*)d_out;

  auto layout_size = [](int PMg) -> size_t {
    size_t o = 0;
    auto alloc = [&](size_t bytes) { o += (bytes + 255) & ~(size_t)255; };
    alloc((size_t)NN * INF_ * 2);              // h_b
    alloc((size_t)PMg * NN * HF * 2);          // hp_b
    alloc((size_t)PMg * NN * HF * 2);          // emb_b
    alloc((size_t)PM * HF * INF_ * 2);         // Wb_t
    alloc((size_t)HS * HF * 2);                // W1_t
    alloc((size_t)PM * INF_ * NH * 4);         // wl
    alloc((size_t)PM * INF_ * NH * 4);         // wr
    alloc((size_t)PMg * NN * NH * 4);          // el
    alloc((size_t)PMg * NN * NH * 4);          // er
    alloc((size_t)PM * NB2 * BCAP * 4);        // bdata
    alloc((size_t)PM * NB2 * 4);               // gcnt
    alloc((size_t)BG * GCAP * 4);              // glist
    alloc((size_t)BG * 4);                     // gcnt2
    alloc((size_t)PM * (NN + 1) * 4);          // off
    alloc((size_t)PM * EE * 2);                // csr
    alloc((size_t)PM * BG * HF * 4);           // pool
    alloc((size_t)PM * NBG2 * 4);              // wpart
    return o;
  };
  int PMg = (layout_size(4) <= ws_size) ? 4 : 1;

  char* ws = (char*)d_ws;
  size_t o = 0;
  auto alloc = [&](size_t bytes) { size_t r = o; o += (bytes + 255) & ~(size_t)255; return r; };
  unsigned short* h_b   = (unsigned short*)(ws + alloc((size_t)NN * INF_ * 2));
  unsigned short* hp_b  = (unsigned short*)(ws + alloc((size_t)PMg * NN * HF * 2));
  unsigned short* emb_b = (unsigned short*)(ws + alloc((size_t)PMg * NN * HF * 2));
  unsigned short* Wb_t  = (unsigned short*)(ws + alloc((size_t)PM * HF * INF_ * 2));
  unsigned short* W1_t  = (unsigned short*)(ws + alloc((size_t)HS * HF * 2));
  float* wl    = (float*)(ws + alloc((size_t)PM * INF_ * NH * 4));
  float* wr    = (float*)(ws + alloc((size_t)PM * INF_ * NH * 4));
  float* el    = (float*)(ws + alloc((size_t)PMg * NN * NH * 4));
  float* er    = (float*)(ws + alloc((size_t)PMg * NN * NH * 4));
  unsigned* bdata = (unsigned*)(ws + alloc((size_t)PM * NB2 * BCAP * 4));
  int*   gcnt  = (int*)(ws + alloc((size_t)PM * NB2 * 4));
  int*   glist = (int*)(ws + alloc((size_t)BG * GCAP * 4));
  int*   gcnt2 = (int*)(ws + alloc((size_t)BG * 4));
  int*   off   = (int*)(ws + alloc((size_t)PM * (NN + 1) * 4));
  unsigned short* csr = (unsigned short*)(ws + alloc((size_t)PM * EE * 2));
  float* pool  = (float*)(ws + alloc((size_t)PM * BG * HF * 4));
  float* wpart = (float*)(ws + alloc((size_t)PM * NBG2 * 4));

  const size_t hpS  = (PMg == 4) ? (size_t)NN * HF : 0;
  const size_t embS = hpS;
  const size_t elS  = (PMg == 4) ? (size_t)NN * NH : 0;

  prep_kernel<<<1 + 6250 + 512 + 128 + 16, 256, 0, stream>>>(
      h, Wg, semW1, attn_l, attn_r, h_b, Wb_t, W1_t, wl, wr, gcnt, gcnt2);
  bg_kernel<<<NBB * PM + NGB, 256, 0, stream>>>(src, dst, bdata, gcnt, gid, glist, gcnt2);

  if (PMg == 4) {
    cg1_kernel<<<NB2 * PM + NBG1 * 2 + NBE * 4, 256, 0, stream>>>(
        bdata, gcnt, off, csr, h_b, Wb_t, hp_b, wl, wr, el, er,
        NN, 0, 4, NB2 * PM, hpS, elS);
    agg_kernel<<<dim3((NN + 3) / 4, 4), 256, 0, stream>>>(
        hp_b, el, er, csr, off, gatb, emb_b, NN, 0, hpS, elS, embS);
    g2pool_kernel<<<NBG2 * 4 + BG * 4, 256, 0, stream>>>(
        emb_b, W1_t, semb1, semW2, wpart, glist, gcnt2, pool, NN, 0, 4, embS);
  } else {
    cg1_kernel<<<NB2 * PM, 256, 0, stream>>>(
        bdata, gcnt, off, csr, h_b, Wb_t, hp_b, wl, wr, el, er,
        NN, 0, 0, NB2 * PM, 0, 0);
    for (int p = 0; p < PM; p++) {
      cg1_kernel<<<NBG1 * 2 + NBE, 256, 0, stream>>>(
          bdata, gcnt, off, csr, h_b, Wb_t, hp_b, wl, wr, el, er,
          NN, p, 1, 0, 0, 0);
      agg_kernel<<<dim3((NN + 3) / 4, 1), 256, 0, stream>>>(
          hp_b, el, er, csr, off, gatb, emb_b, NN, p, 0, 0, 0);
      g2pool_kernel<<<NBG2 + BG, 256, 0, stream>>>(
          emb_b, W1_t, semb1, semW2, wpart, glist, gcnt2, pool, NN, p, 1, 0);
    }
  }

  final_kernel<<<BG, 256, 0, stream>>>(pool, wpart, gcnt2, clsW, clsb, out, NN);
}